// Round 3
// baseline (3487.269 us; speedup 1.0000x reference)
//
#include <hip/hip_runtime.h>
#include <stdint.h>
#include <math.h>

#define B_    8
#define S_    1024
#define D_    576
#define H_    9
#define HD_   64
#define LAT_  144
#define FF_   1536
#define NE_   7
#define NT_   8192
#define NPAIR_ 16384
#define NACT_  24576

typedef unsigned short u16;
typedef __attribute__((ext_vector_type(8))) short bf16x8;
typedef __attribute__((ext_vector_type(4))) float f32x4;
typedef __attribute__((ext_vector_type(4))) unsigned short us4;

__device__ __forceinline__ u16 f2b(float f){
  union{float f;uint32_t u;} v; v.f=f;
  uint32_t u=v.u;
  return (u16)((u + 0x7fffu + ((u>>16)&1u))>>16);
}
__device__ __forceinline__ float b2f(u16 h){
  union{uint32_t u;float f;} v; v.u=((uint32_t)h)<<16; return v.f;
}

#define MFMA16(a,b,c) __builtin_amdgcn_mfma_f32_16x16x32_bf16((a),(b),(c),0,0,0)

typedef __attribute__((address_space(1))) const unsigned char g_u8;
typedef __attribute__((address_space(3))) unsigned char s_u8;
__device__ __forceinline__ void gll16(const void* g, void* l){
  __builtin_amdgcn_global_load_lds((g_u8*)g, (s_u8*)l, 16, 0, 0);
}

// ---------------- MoE weight conversion fp32->bf16 ----------------
struct CvtSegs {
  const float* src[6];
  u16* dst[6];
  int start4[7];
};
__global__ void k_cvt(CvtSegs cs){
  int tot = cs.start4[6];
  for(int i = blockIdx.x*blockDim.x + threadIdx.x; i < tot; i += gridDim.x*blockDim.x){
    int s=0;
    #pragma unroll
    for(int j=0;j<6;j++) if(i >= cs.start4[j+1]) s=j+1;
    int loc = i - cs.start4[s];
    float4 v = ((const float4*)cs.src[s])[loc];
    us4 o; o[0]=f2b(v.x); o[1]=f2b(v.y); o[2]=f2b(v.z); o[3]=f2b(v.w);
    ((us4*)cs.dst[s])[loc] = o;
  }
}

// ---------------- RoPE tables (match numpy: 1/powf then fp32 multiply) ----
__global__ void k_rope_tab(float* __restrict__ cost, float* __restrict__ sint){
  int i = blockIdx.x*256+threadIdx.x; if(i>=S_*32) return;
  int s=i>>5, d=i&31;
  float pw = (float)pow(10000.0, (double)d/32.0);
  float inv = 1.0f/pw;
  float ang = (float)s*inv;
  cost[i]=cosf(ang); sint[i]=sinf(ang);
}

// ---------------- fp32 rmsnorm (+optional bf16 copy) ----------------
__global__ __launch_bounds__(64) void k_rms(const float* __restrict__ x, const float* __restrict__ w,
                      float* __restrict__ hf, u16* __restrict__ hb){
  int t = blockIdx.x; int lane = threadIdx.x;
  const float* xr = x + (size_t)t*D_;
  float v[9]; float ss=0.f;
  #pragma unroll
  for(int j=0;j<9;j++){ v[j]=xr[lane+64*j]; ss += v[j]*v[j]; }
  #pragma unroll
  for(int m=1;m<64;m<<=1) ss += __shfl_xor(ss,m,64);
  float sc = 1.0f/sqrtf(ss/(float)D_ + 1e-5f);
  #pragma unroll
  for(int j=0;j<9;j++){
    float y = v[j]*sc*w[lane+64*j];
    hf[(size_t)t*D_+lane+64*j] = y;
    if(hb) hb[(size_t)t*D_+lane+64*j] = f2b(y);
  }
}

// ---------------- fp32 tiled GEMM: C(M,N) = A(M,K)·B(N,K)^T (+resid) -----
template<bool CONCATB, bool RESID>
__global__ __launch_bounds__(256) void k_sgemm(
    const float* __restrict__ A, int lda,
    const float* __restrict__ Bm, const float* __restrict__ B2, int ldb,
    int N, int kchunks,
    float* __restrict__ C, int ldc, const float* __restrict__ resid)
{
  __shared__ float At[16][68], Bt[16][68];
  int tid=threadIdx.x;
  int tm=tid&15, tn=tid>>4;
  int m0=blockIdx.x*64, n0=blockIdx.y*64;
  int sr=tid>>2, kq=(tid&3)*4;
  float acc[4][4]={};
  for(int kt=0;kt<kchunks;kt++){
    int k0=kt*16;
    float4 a4 = *(const float4*)&A[(long)(m0+sr)*lda + k0+kq];
    int rb = n0+sr; if(rb>N-1) rb=N-1;
    const float* bp;
    if(CONCATB) bp = (rb<144)? (Bm + (long)rb*ldb) : (B2 + (long)(rb-144)*ldb);
    else bp = Bm + (long)rb*ldb;
    float4 b4 = *(const float4*)&bp[k0+kq];
    __syncthreads();
    At[kq+0][sr]=a4.x; At[kq+1][sr]=a4.y; At[kq+2][sr]=a4.z; At[kq+3][sr]=a4.w;
    Bt[kq+0][sr]=b4.x; Bt[kq+1][sr]=b4.y; Bt[kq+2][sr]=b4.z; Bt[kq+3][sr]=b4.w;
    __syncthreads();
    #pragma unroll
    for(int k=0;k<16;k++){
      float4 av=*(const float4*)&At[k][tm*4];
      float4 bv=*(const float4*)&Bt[k][tn*4];
      acc[0][0]+=av.x*bv.x; acc[0][1]+=av.x*bv.y; acc[0][2]+=av.x*bv.z; acc[0][3]+=av.x*bv.w;
      acc[1][0]+=av.y*bv.x; acc[1][1]+=av.y*bv.y; acc[1][2]+=av.y*bv.z; acc[1][3]+=av.y*bv.w;
      acc[2][0]+=av.z*bv.x; acc[2][1]+=av.z*bv.y; acc[2][2]+=av.z*bv.z; acc[2][3]+=av.z*bv.w;
      acc[3][0]+=av.w*bv.x; acc[3][1]+=av.w*bv.y; acc[3][2]+=av.w*bv.z; acc[3][3]+=av.w*bv.w;
    }
  }
  #pragma unroll
  for(int i=0;i<4;i++){
    int row=m0+tm*4+i;
    #pragma unroll
    for(int j=0;j<4;j++){
      int col=n0+tn*4+j;
      if(col<N){
        float v=acc[i][j];
        if(RESID) v += resid[(long)row*ldc+col];
        C[(long)row*ldc+col]=v;
      }
    }
  }
}

// ---------------- fp32 RoPE repack ----------------
__global__ void k_rope(const float* __restrict__ QR, const float* __restrict__ KR,
                       const float* __restrict__ cost, const float* __restrict__ sint,
                       float* __restrict__ QF, float* __restrict__ KF){
  int i = blockIdx.x*256+threadIdx.x;
  if(i >= NT_*H_*32) return;
  int d = i&31; int h=(i>>5)%H_; int t = i/(H_*32);
  int s = t & (S_-1); int b = t >> 10;
  float c = cost[s*32+d], sn = sint[s*32+d];
  long qi = (long)t*D_ + h*HD_ + d;
  float q1=QR[qi], q2=QR[qi+32];
  float k1=KR[qi], k2=KR[qi+32];
  long ob = ((long)(b*H_+h)*S_ + s)*HD_ + d;
  QF[ob]    = (q1*c - q2*sn)*0.125f;
  QF[ob+32] = (q2*c + q1*sn)*0.125f;
  KF[ob]    = k1*c - k2*sn;
  KF[ob+32] = k2*c + k1*sn;
}

// ---------------- fp32 flash attention (causal) ----------------
// block = 256 (4 waves); each wave owns 16 q rows; lane owns one key (score
// phase, K row in regs) and one output dim d=lane (PV phase, V col in regs).
__global__ __launch_bounds__(256) void k_attn_f32(const float* __restrict__ QF,
                        const float* __restrict__ KF,
                        const float* __restrict__ VR, float* __restrict__ OBF){
  __shared__ float q_lds[64][64];
  __shared__ float p_lds[4][16][64];
  int tid=threadIdx.x;
  int bh=blockIdx.y; int b=bh/H_, h=bh-b*H_;
  int s0=blockIdx.x*64;
  #pragma unroll
  for(int j=0;j<16;j++){
    int idx=j*256+tid; int r=idx>>6, d=idx&63;
    q_lds[r][d]=QF[((long)bh*S_+s0+r)*64+d];
  }
  __syncthreads();
  int wid=tid>>6, lane=tid&63;
  int q0w=s0+wid*16;
  float m_[16], l_[16], o_[16], sc_[16];
  #pragma unroll
  for(int r=0;r<16;r++){ m_[r]=-3e38f; l_[r]=0.f; o_[r]=0.f; sc_[r]=0.f; }
  for(int kv=0; kv<=q0w+15; kv+=64){
    int key=kv+lane;
    float kvreg[64];
    {
      const float* kr = KF + ((long)bh*S_+key)*64;
      #pragma unroll
      for(int j4=0;j4<16;j4++){
        float4 t=*(const float4*)&kr[j4*4];
        kvreg[j4*4]=t.x; kvreg[j4*4+1]=t.y; kvreg[j4*4+2]=t.z; kvreg[j4*4+3]=t.w;
      }
    }
    #pragma unroll
    for(int r=0;r<16;r++){
      float s=0.f;
      #pragma unroll
      for(int j4=0;j4<16;j4++){
        float4 qv=*(const float4*)&q_lds[wid*16+r][j4*4];
        s += qv.x*kvreg[j4*4] + qv.y*kvreg[j4*4+1] + qv.z*kvreg[j4*4+2] + qv.w*kvreg[j4*4+3];
      }
      if(key > q0w+r) s=-3e38f;
      float tmx=s;
      #pragma unroll
      for(int mm=1;mm<64;mm<<=1) tmx=fmaxf(tmx,__shfl_xor(tmx,mm,64));
      float mn=fmaxf(m_[r],tmx);
      float scr=expf(m_[r]-mn);
      float p=expf(s-mn);
      float ps=p;
      #pragma unroll
      for(int mm=1;mm<64;mm<<=1) ps+=__shfl_xor(ps,mm,64);
      l_[r]=l_[r]*scr+ps;
      m_[r]=mn; sc_[r]=scr;
      p_lds[wid][r][lane]=p;
    }
    // V phase: reuse kvreg for V column d=lane
    {
      const float* vb = VR + ((long)b*S_+kv)*D_ + h*HD_ + lane;
      #pragma unroll
      for(int j=0;j<64;j++) kvreg[j]=vb[(long)j*D_];
    }
    #pragma unroll
    for(int r=0;r<16;r++){
      float acc=0.f;
      #pragma unroll
      for(int j4=0;j4<16;j4++){
        float4 pv=*(const float4*)&p_lds[wid][r][j4*4];
        acc += pv.x*kvreg[j4*4]+pv.y*kvreg[j4*4+1]+pv.z*kvreg[j4*4+2]+pv.w*kvreg[j4*4+3];
      }
      o_[r]=o_[r]*sc_[r]+acc;
    }
  }
  #pragma unroll
  for(int r=0;r<16;r++){
    OBF[((long)b*S_+q0w+r)*D_ + h*HD_ + lane] = o_[r]/l_[r];
  }
}

// ---------------- router (fp32, accurate expf) ----------------
__global__ __launch_bounds__(64) void k_router(const float* __restrict__ h2f, const float* __restrict__ Wr,
                         const float* __restrict__ rb, int* __restrict__ idx2,
                         float* __restrict__ w2, int* __restrict__ counts){
  int t=blockIdx.x, lane=threadIdx.x;
  float hv[9];
  #pragma unroll
  for(int j=0;j<9;j++) hv[j]=h2f[(long)t*D_+lane+64*j];
  float pr[7];
  #pragma unroll
  for(int e=0;e<7;e++){
    float s=0.f;
    #pragma unroll
    for(int j=0;j<9;j++) s += hv[j]*Wr[e*D_+lane+64*j];
    #pragma unroll
    for(int mm=1;mm<64;mm<<=1) s+=__shfl_xor(s,mm,64);
    pr[e] = 1.f/(1.f+expf(-(s+rb[e])));
  }
  int e0=0; float b0=pr[0];
  #pragma unroll
  for(int e=1;e<7;e++) if(pr[e]>b0){b0=pr[e];e0=e;}
  int e1=-1; float b1=-1e30f;
  #pragma unroll
  for(int e=0;e<7;e++) if(e!=e0 && pr[e]>b1){b1=pr[e];e1=e;}
  if(lane==0){
    float s=b0+b1;
    idx2[2*t]=e0; idx2[2*t+1]=e1;
    w2[2*t]=b0/s; w2[2*t+1]=b1/s;
    atomicAdd(&counts[e0],1);
    atomicAdd(&counts[e1],1);
  }
}

__global__ void k_offsets(const int* __restrict__ counts, int* __restrict__ ofs, int* __restrict__ fill){
  if(threadIdx.x==0 && blockIdx.x==0){
    int a=0;
    for(int e=0;e<NE_;e++){ ofs[e]=a; fill[e]=a; a+=counts[e]; }
    ofs[NE_]=a;
  }
}

__global__ void k_scatter(const int* __restrict__ idx2, const float* __restrict__ w2, int* __restrict__ fill,
                          int* __restrict__ ltok, float* __restrict__ lw, int* __restrict__ ppos){
  int t = blockIdx.x*256+threadIdx.x; if(t>=NT_) return;
  #pragma unroll
  for(int j=0;j<2;j++){
    int e = idx2[2*t+j];
    int pos = atomicAdd(&fill[e],1);
    ltok[pos]=t; lw[pos]=w2[2*t+j]; ppos[2*t+j]=pos;
  }
}

// ---------------- grouped gate+up+SwiGLU (bf16 MFMA) ----------------
__global__ __launch_bounds__(256) void k_moe_gu(const u16* __restrict__ h2b, const u16* __restrict__ Gb,
                        const u16* __restrict__ Ub, const int* __restrict__ cnt,
                        const int* __restrict__ ofs, const int* __restrict__ ltok,
                        u16* __restrict__ act){
  int e = blockIdx.z;
  int nrows = (e<NE_)? cnt[e] : NT_;
  int base  = (e<NE_)? ofs[e] : 0;
  long arow0 = (e<NE_)? (long)base : (long)NPAIR_;
  int mt = blockIdx.x;
  if(mt*128 >= nrows) return;
  int f0 = blockIdx.y*64;
  __shared__ u16 As[128*32], Gs[64*32], Us[64*32];
  int tid=threadIdx.x, wid=tid>>6, lane=tid&63;
  int lq=lane&15, lg=lane>>4;
  int wr=wid>>1, wc=wid&1;
  f32x4 ag[4][2]={}, au[4][2]={};
  for(int kt=0;kt<18;kt++){
    #pragma unroll
    for(int is=0;is<2;is++){
      int ub = is*4096 + wid*1024;
      int o = ub + lane*16;
      int row = o>>6, cb=o&63;
      int ridx = mt*128+row; if(ridx>nrows-1) ridx=nrows-1;
      int tok = (e<NE_)? ltok[base+ridx] : ridx;
      const u16* ga = h2b + (long)tok*D_ + kt*32 + (cb>>1);
      gll16(ga, (char*)As+ub);
    }
    {
      int ub = wid*1024;
      int o = ub + lane*16;
      int row=o>>6, cb=o&63;
      long wrow = (long)e*FF_ + f0 + row;
      gll16(Gb + wrow*D_ + kt*32 + (cb>>1), (char*)Gs+ub);
      gll16(Ub + wrow*D_ + kt*32 + (cb>>1), (char*)Us+ub);
    }
    __syncthreads();
    bf16x8 af[4], gf[2], uf[2];
    #pragma unroll
    for(int m=0;m<4;m++) af[m]=*(const bf16x8*)&As[(wr*64+m*16+lq)*32+lg*8];
    #pragma unroll
    for(int n=0;n<2;n++){
      gf[n]=*(const bf16x8*)&Gs[(wc*32+n*16+lq)*32+lg*8];
      uf[n]=*(const bf16x8*)&Us[(wc*32+n*16+lq)*32+lg*8];
    }
    #pragma unroll
    for(int m=0;m<4;m++)
      #pragma unroll
      for(int n=0;n<2;n++){
        ag[m][n]=MFMA16(af[m],gf[n],ag[m][n]);
        au[m][n]=MFMA16(af[m],uf[n],au[m][n]);
      }
    __syncthreads();
  }
  #pragma unroll
  for(int m=0;m<4;m++){
    #pragma unroll
    for(int n=0;n<2;n++){
      int f = f0 + wc*32+n*16+lq;
      #pragma unroll
      for(int r=0;r<4;r++){
        int rl = wr*64+m*16+lg*4+r;
        int ridx = mt*128+rl;
        if(ridx<nrows){
          float g=ag[m][n][r], u=au[m][n][r];
          float sw = g/(1.f+__expf(-g))*u;
          act[(arow0+ridx)*FF_ + f] = f2b(sw);
        }
      }
    }
  }
}

// ---------------- grouped down-proj (bf16 MFMA, weight folded) ---------
__global__ __launch_bounds__(256) void k_moe_down(const u16* __restrict__ act, const u16* __restrict__ Db,
                          const int* __restrict__ cnt, const int* __restrict__ ofs,
                          const float* __restrict__ lw, u16* __restrict__ pd){
  int e=blockIdx.z;
  int nrows=(e<NE_)?cnt[e]:NT_;
  long arow0=(e<NE_)?(long)ofs[e]:(long)NPAIR_;
  int mt=blockIdx.x;
  if(mt*128>=nrows) return;
  int n0=blockIdx.y*64;
  __shared__ u16 As[128*32], Bs[64*32];
  int tid=threadIdx.x,wid=tid>>6,lane=tid&63;
  int lq=lane&15,lg=lane>>4;
  int wr=wid>>1,wc=wid&1;
  f32x4 acc[4][2]={};
  for(int kt=0;kt<48;kt++){
    #pragma unroll
    for(int is=0;is<2;is++){
      int ub=is*4096+wid*1024;
      int o=ub+lane*16;
      int row=o>>6, cb=o&63;
      const u16* ga = act + (arow0 + mt*128+row)*FF_ + kt*32 + (cb>>1);
      gll16(ga,(char*)As+ub);
    }
    {
      int ub=wid*1024; int o=ub+lane*16;
      int row=o>>6, cb=o&63;
      const u16* gb = Db + ((long)e*D_ + n0+row)*FF_ + kt*32 + (cb>>1);
      gll16(gb,(char*)Bs+ub);
    }
    __syncthreads();
    bf16x8 af[4],bf2[2];
    #pragma unroll
    for(int m=0;m<4;m++) af[m]=*(const bf16x8*)&As[(wr*64+m*16+lq)*32+lg*8];
    #pragma unroll
    for(int n=0;n<2;n++) bf2[n]=*(const bf16x8*)&Bs[(wc*32+n*16+lq)*32+lg*8];
    #pragma unroll
    for(int m=0;m<4;m++)
      #pragma unroll
      for(int n=0;n<2;n++)
        acc[m][n]=MFMA16(af[m],bf2[n],acc[m][n]);
    __syncthreads();
  }
  #pragma unroll
  for(int m=0;m<4;m++){
    #pragma unroll
    for(int n=0;n<2;n++){
      int col=n0+wc*32+n*16+lq;
      #pragma unroll
      for(int r=0;r<4;r++){
        int rl=wr*64+m*16+lg*4+r;
        int ridx=mt*128+rl;
        if(ridx<nrows){
          float w=1.f;
          if(e<NE_) w=lw[arow0+ridx];
          pd[(arow0+ridx)*D_ + col]=f2b(w*acc[m][n][r]);
        }
      }
    }
  }
}

// ---------------- final combine ----------------
__global__ void k_final(const float* __restrict__ x2, const u16* __restrict__ pd,
                        const int* __restrict__ ppos, float* __restrict__ out){
  int i=blockIdx.x*256+threadIdx.x;
  int tot = NT_*(D_/4);
  if(i>=tot) return;
  int t = i/(D_/4); int c = (i - t*(D_/4))*4;
  int p0=ppos[2*t], p1=ppos[2*t+1];
  const u16* a=pd+((long)NPAIR_+t)*D_+c;
  const u16* b=pd+(long)p0*D_+c;
  const u16* d=pd+(long)p1*D_+c;
  const float* xr = x2+(long)t*D_+c;
  float* o = out+(long)t*D_+c;
  #pragma unroll
  for(int j=0;j<4;j++) o[j]=xr[j]+b2f(a[j])+b2f(b[j])+b2f(d[j]);
}

extern "C" void kernel_launch(void* const* d_in, const int* in_sizes, int n_in,
                              void* d_out, int out_size, void* d_ws, size_t ws_size,
                              hipStream_t stream){
  const float* x    =(const float*)d_in[0];
  const float* ln1  =(const float*)d_in[1];
  const float* ln2  =(const float*)d_in[2];
  const float* Wqd  =(const float*)d_in[3];
  const float* Wkvd =(const float*)d_in[4];
  const float* Wqu  =(const float*)d_in[5];
  const float* Wku  =(const float*)d_in[6];
  const float* Wvu  =(const float*)d_in[7];
  const float* Wo   =(const float*)d_in[8];
  const float* sg   =(const float*)d_in[9];
  const float* su   =(const float*)d_in[10];
  const float* sd   =(const float*)d_in[11];
  const float* rg   =(const float*)d_in[12];
  const float* ru   =(const float*)d_in[13];
  const float* rd   =(const float*)d_in[14];
  const float* Wr   =(const float*)d_in[15];
  const float* rb   =(const float*)d_in[16];
  float* out=(float*)d_out;

  char* ws=(char*)d_ws;
  size_t off=0;
  auto alloc=[&](size_t bsz){ size_t r=off; off=(off+bsz+255)&~(size_t)255; return r; };
  // fixed region
  u16* GB   =(u16*)(ws+alloc(8L*FF_*D_*2));
  u16* UB   =(u16*)(ws+alloc(8L*FF_*D_*2));
  u16* DB   =(u16*)(ws+alloc(8L*D_*FF_*2));
  float* COS=(float*)(ws+alloc(S_*32*4));
  float* SIN=(float*)(ws+alloc(S_*32*4));
  float* X2 =(float*)(ws+alloc((long)NT_*D_*4));
  float* H2F=(float*)(ws+alloc((long)NT_*D_*4));
  u16* H2B  =(u16*)(ws+alloc((long)NT_*D_*2));
  int* IDX2 =(int*)(ws+alloc(NT_*2*4));
  float* W2 =(float*)(ws+alloc(NT_*2*4));
  int* PPOS =(int*)(ws+alloc(NT_*2*4));
  int* CNT  =(int*)(ws+alloc(64));
  int* OFS  =(int*)(ws+alloc(64));
  int* FILL =(int*)(ws+alloc(64));
  int* LTOK =(int*)(ws+alloc(NPAIR_*4));
  float* LW =(float*)(ws+alloc(NPAIR_*4));
  size_t scr0 = off;
  // phase A (attention)
  float* H1F=(float*)(ws+alloc((long)NT_*D_*4));
  float* LAT=(float*)(ws+alloc((long)NT_*288*4));
  float* QR =(float*)(ws+alloc((long)NT_*D_*4));
  float* KR =(float*)(ws+alloc((long)NT_*D_*4));
  float* VR =(float*)(ws+alloc((long)NT_*D_*4));
  float* QF =(float*)(ws+alloc((long)NT_*D_*4));
  float* KF =(float*)(ws+alloc((long)NT_*D_*4));
  float* OBF = QR;  // QR dead after k_rope; reuse for attention output
  // phase B (MoE) overlaps phase A
  off = scr0;
  u16* ACT =(u16*)(ws+alloc((long)NACT_*FF_*2));
  u16* PD  =(u16*)(ws+alloc((long)NACT_*D_*2));
  (void)ws_size;

  // MoE weight conversion
  CvtSegs cs;
  {
    const float* ss[6]={rg,sg,ru,su,rd,sd};
    u16* dd[6]={GB, GB+7L*FF_*D_, UB, UB+7L*FF_*D_, DB, DB+7L*D_*FF_};
    long nn[6]={7L*FF_*D_,(long)FF_*D_,7L*FF_*D_,(long)FF_*D_,7L*D_*FF_,(long)D_*FF_};
    cs.start4[0]=0;
    for(int j=0;j<6;j++){ cs.src[j]=ss[j]; cs.dst[j]=dd[j]; cs.start4[j+1]=cs.start4[j]+(int)(nn[j]/4); }
  }
  k_cvt<<<2048,256,0,stream>>>(cs);
  k_rope_tab<<<(S_*32+255)/256,256,0,stream>>>(COS,SIN);

  // attention block (all fp32)
  k_rms<<<NT_,64,0,stream>>>(x, ln1, H1F, (u16*)nullptr);
  k_sgemm<true ,false><<<dim3(128,5),256,0,stream>>>(H1F,D_, Wqd,Wkvd,D_, 288,36, LAT,288, nullptr);
  k_sgemm<false,false><<<dim3(128,9),256,0,stream>>>(LAT    ,288, Wqu,nullptr,LAT_, D_,9, QR,D_, nullptr);
  k_sgemm<false,false><<<dim3(128,9),256,0,stream>>>(LAT+144,288, Wku,nullptr,LAT_, D_,9, KR,D_, nullptr);
  k_sgemm<false,false><<<dim3(128,9),256,0,stream>>>(LAT+144,288, Wvu,nullptr,LAT_, D_,9, VR,D_, nullptr);
  k_rope<<<(NT_*H_*32+255)/256,256,0,stream>>>(QR,KR,COS,SIN,QF,KF);
  k_attn_f32<<<dim3(16,72),256,0,stream>>>(QF,KF,VR,OBF);
  k_sgemm<false,true ><<<dim3(128,9),256,0,stream>>>(OBF,D_, Wo,nullptr,D_, D_,36, X2,D_, x);

  // MoE block
  k_rms<<<NT_,64,0,stream>>>(X2, ln2, H2F, H2B);
  hipMemsetAsync(CNT,0,64,stream);
  k_router<<<NT_,64,0,stream>>>(H2F,Wr,rb,IDX2,W2,CNT);
  k_offsets<<<1,1,0,stream>>>(CNT,OFS,FILL);
  k_scatter<<<(NT_+255)/256,256,0,stream>>>(IDX2,W2,FILL,LTOK,LW,PPOS);
  k_moe_gu<<<dim3(64,24,8),256,0,stream>>>(H2B,GB,UB,CNT,OFS,LTOK,ACT);
  k_moe_down<<<dim3(64,9,8),256,0,stream>>>(ACT,DB,CNT,OFS,LW,PD);
  k_final<<<(NT_*(D_/4)+255)/256,256,0,stream>>>(X2,PD,PPOS,out);
}

// Round 4
// 1405.207 us; speedup vs baseline: 2.4817x; 2.4817x over previous
//
#include <hip/hip_runtime.h>
#include <stdint.h>
#include <math.h>

#define B_    8
#define S_    1024
#define D_    576
#define H_    9
#define HD_   64
#define LAT_  144
#define FF_   1536
#define NE_   7
#define NT_   8192
#define NPAIR_ 16384
#define NACT_  24576

typedef unsigned short u16;
typedef __attribute__((ext_vector_type(8))) short bf16x8;
typedef __attribute__((ext_vector_type(4))) float f32x4;
typedef __attribute__((ext_vector_type(4))) unsigned short us4;

__device__ __forceinline__ u16 f2b(float f){
  union{float f;uint32_t u;} v; v.f=f;
  uint32_t u=v.u;
  return (u16)((u + 0x7fffu + ((u>>16)&1u))>>16);
}
__device__ __forceinline__ float b2f(u16 h){
  union{uint32_t u;float f;} v; v.u=((uint32_t)h)<<16; return v.f;
}

#define MFMA16(a,b,c) __builtin_amdgcn_mfma_f32_16x16x32_bf16((a),(b),(c),0,0,0)

typedef __attribute__((address_space(1))) const unsigned char g_u8;
typedef __attribute__((address_space(3))) unsigned char s_u8;
__device__ __forceinline__ void gll16(const void* g, void* l){
  __builtin_amdgcn_global_load_lds((g_u8*)g, (s_u8*)l, 16, 0, 0);
}

// ---------------- MoE weight conversion fp32->bf16 ----------------
struct CvtSegs {
  const float* src[6];
  u16* dst[6];
  int start4[7];
};
__global__ void k_cvt(CvtSegs cs){
  int tot = cs.start4[6];
  for(int i = blockIdx.x*blockDim.x + threadIdx.x; i < tot; i += gridDim.x*blockDim.x){
    int s=0;
    #pragma unroll
    for(int j=0;j<6;j++) if(i >= cs.start4[j+1]) s=j+1;
    int loc = i - cs.start4[s];
    float4 v = ((const float4*)cs.src[s])[loc];
    us4 o; o[0]=f2b(v.x); o[1]=f2b(v.y); o[2]=f2b(v.z); o[3]=f2b(v.w);
    ((us4*)cs.dst[s])[loc] = o;
  }
}

// ---------------- RoPE tables (identical to passing round 3) ----------
__global__ void k_rope_tab(float* __restrict__ cost, float* __restrict__ sint){
  int i = blockIdx.x*256+threadIdx.x; if(i>=S_*32) return;
  int s=i>>5, d=i&31;
  float pw = (float)pow(10000.0, (double)d/32.0);
  float inv = 1.0f/pw;
  float ang = (float)s*inv;
  cost[i]=cosf(ang); sint[i]=sinf(ang);
}

// ---------------- fp32 rmsnorm (+optional bf16 copy) ----------------
__global__ __launch_bounds__(64) void k_rms(const float* __restrict__ x, const float* __restrict__ w,
                      float* __restrict__ hf, u16* __restrict__ hb){
  int t = blockIdx.x; int lane = threadIdx.x;
  const float* xr = x + (size_t)t*D_;
  float v[9]; float ss=0.f;
  #pragma unroll
  for(int j=0;j<9;j++){ v[j]=xr[lane+64*j]; ss += v[j]*v[j]; }
  #pragma unroll
  for(int m=1;m<64;m<<=1) ss += __shfl_xor(ss,m,64);
  float sc = 1.0f/sqrtf(ss/(float)D_ + 1e-5f);
  #pragma unroll
  for(int j=0;j<9;j++){
    float y = v[j]*sc*w[lane+64*j];
    hf[(size_t)t*D_+lane+64*j] = y;
    if(hb) hb[(size_t)t*D_+lane+64*j] = f2b(y);
  }
}

// ---------------- fp32 tiled GEMM: C(M,N) = A(M,K)·B(N,K)^T (+resid) -----
template<bool CONCATB, bool RESID>
__global__ __launch_bounds__(256) void k_sgemm(
    const float* __restrict__ A, int lda,
    const float* __restrict__ Bm, const float* __restrict__ B2, int ldb,
    int N, int kchunks,
    float* __restrict__ C, int ldc, const float* __restrict__ resid)
{
  __shared__ float At[16][68], Bt[16][68];
  int tid=threadIdx.x;
  int tm=tid&15, tn=tid>>4;
  int m0=blockIdx.x*64, n0=blockIdx.y*64;
  int sr=tid>>2, kq=(tid&3)*4;
  float acc[4][4]={};
  for(int kt=0;kt<kchunks;kt++){
    int k0=kt*16;
    float4 a4 = *(const float4*)&A[(long)(m0+sr)*lda + k0+kq];
    int rb = n0+sr; if(rb>N-1) rb=N-1;
    const float* bp;
    if(CONCATB) bp = (rb<144)? (Bm + (long)rb*ldb) : (B2 + (long)(rb-144)*ldb);
    else bp = Bm + (long)rb*ldb;
    float4 b4 = *(const float4*)&bp[k0+kq];
    __syncthreads();
    At[kq+0][sr]=a4.x; At[kq+1][sr]=a4.y; At[kq+2][sr]=a4.z; At[kq+3][sr]=a4.w;
    Bt[kq+0][sr]=b4.x; Bt[kq+1][sr]=b4.y; Bt[kq+2][sr]=b4.z; Bt[kq+3][sr]=b4.w;
    __syncthreads();
    #pragma unroll
    for(int k=0;k<16;k++){
      float4 av=*(const float4*)&At[k][tm*4];
      float4 bv=*(const float4*)&Bt[k][tn*4];
      acc[0][0]+=av.x*bv.x; acc[0][1]+=av.x*bv.y; acc[0][2]+=av.x*bv.z; acc[0][3]+=av.x*bv.w;
      acc[1][0]+=av.y*bv.x; acc[1][1]+=av.y*bv.y; acc[1][2]+=av.y*bv.z; acc[1][3]+=av.y*bv.w;
      acc[2][0]+=av.z*bv.x; acc[2][1]+=av.z*bv.y; acc[2][2]+=av.z*bv.z; acc[2][3]+=av.z*bv.w;
      acc[3][0]+=av.w*bv.x; acc[3][1]+=av.w*bv.y; acc[3][2]+=av.w*bv.z; acc[3][3]+=av.w*bv.w;
    }
  }
  #pragma unroll
  for(int i=0;i<4;i++){
    int row=m0+tm*4+i;
    #pragma unroll
    for(int j=0;j<4;j++){
      int col=n0+tn*4+j;
      if(col<N){
        float v=acc[i][j];
        if(RESID) v += resid[(long)row*ldc+col];
        C[(long)row*ldc+col]=v;
      }
    }
  }
}

// ---------------- RoPE + hi/lo split repack ----------------
__global__ void k_ropesplit(const float* __restrict__ QR, const float* __restrict__ KR,
                            const float* __restrict__ cost, const float* __restrict__ sint,
                            u16* __restrict__ QHI, u16* __restrict__ QLO,
                            u16* __restrict__ KHI, u16* __restrict__ KLO){
  int i = blockIdx.x*256+threadIdx.x;
  if(i >= NT_*H_*32) return;
  int d = i&31; int h=(i>>5)%H_; int t = i/(H_*32);
  int s = t & (S_-1); int b = t >> 10;
  float c = cost[s*32+d], sn = sint[s*32+d];
  long qi = (long)t*D_ + h*HD_ + d;
  float q1=QR[qi], q2=QR[qi+32];
  float k1=KR[qi], k2=KR[qi+32];
  long ob = ((long)(b*H_+h)*S_ + s)*HD_ + d;
  float qa=(q1*c - q2*sn)*0.125f, qb2=(q2*c + q1*sn)*0.125f;
  float ka=k1*c - k2*sn,          kb2=k2*c + k1*sn;
  u16 hh;
  hh=f2b(qa);  QHI[ob]=hh;    QLO[ob]   =f2b(qa -b2f(hh));
  hh=f2b(qb2); QHI[ob+32]=hh; QLO[ob+32]=f2b(qb2-b2f(hh));
  hh=f2b(ka);  KHI[ob]=hh;    KLO[ob]   =f2b(ka -b2f(hh));
  hh=f2b(kb2); KHI[ob+32]=hh; KLO[ob+32]=f2b(kb2-b2f(hh));
}

// ---------------- V transpose + hi/lo split: [b][s][576] -> [bh][64][S] --
__global__ __launch_bounds__(256) void k_vsplit(const float* __restrict__ VR,
                       u16* __restrict__ VHI, u16* __restrict__ VLO){
  __shared__ float ls[64][65];
  int s0 = blockIdx.x*64; int bh = blockIdx.y;
  int b = bh/H_, h = bh - b*H_;
  int tid=threadIdx.x;
  #pragma unroll
  for(int i=0;i<16;i++){
    int idx = tid + i*256;
    int si = idx>>6, dj = idx&63;
    ls[si][dj] = VR[((long)(b*S_+s0+si))*D_ + h*HD_ + dj];
  }
  __syncthreads();
  #pragma unroll
  for(int i=0;i<16;i++){
    int idx = tid + i*256;
    int di = idx>>6, sj = idx&63;
    float v = ls[sj][di];
    u16 hh = f2b(v);
    long o = ((long)bh*HD_+di)*S_ + s0+sj;
    VHI[o]=hh; VLO[o]=f2b(v-b2f(hh));
  }
}

// ---------------- split-bf16 MFMA flash attention (causal) -------------
// 4 waves/block, 16 q rows per wave. QK^T and PV each via 3-term hi/lo
// MFMA expansion (error ~2^-16, fp32-class -> router-safe).
__global__ __launch_bounds__(256) void k_attn_split(
    const u16* __restrict__ QHI, const u16* __restrict__ QLO,
    const u16* __restrict__ KHI, const u16* __restrict__ KLO,
    const u16* __restrict__ VHI, const u16* __restrict__ VLO,
    float* __restrict__ OBF){
  int tid=threadIdx.x, wid=tid>>6, lane=tid&63;
  int bh=blockIdx.y; int b=bh/H_, h=bh-b*H_;
  int q0=blockIdx.x*64 + wid*16;
  int lq=lane&15, lg=lane>>4;
  long qoff = ((long)bh*S_ + q0+lq)*HD_;
  bf16x8 qh0 = *(const bf16x8*)(QHI+qoff+lg*8);
  bf16x8 qh1 = *(const bf16x8*)(QHI+qoff+32+lg*8);
  bf16x8 ql0 = *(const bf16x8*)(QLO+qoff+lg*8);
  bf16x8 ql1 = *(const bf16x8*)(QLO+qoff+32+lg*8);
  float m=-1e30f, l=0.f;
  f32x4 ot[4]={};
  int q_lane = q0 + lq;
  for(int kv=0; kv<=q0+15; kv+=32){
    float p[8];
    float tmax=-1e30f;
    #pragma unroll
    for(int sub=0;sub<2;sub++){
      int krow = kv + sub*16 + lq; if(krow>S_-1) krow=S_-1;
      long koff = ((long)bh*S_+krow)*HD_;
      bf16x8 kh0=*(const bf16x8*)(KHI+koff+lg*8);
      bf16x8 kh1=*(const bf16x8*)(KHI+koff+32+lg*8);
      bf16x8 kl0=*(const bf16x8*)(KLO+koff+lg*8);
      bf16x8 kl1=*(const bf16x8*)(KLO+koff+32+lg*8);
      f32x4 st={0.f,0.f,0.f,0.f};
      st=MFMA16(kh0,qh0,st); st=MFMA16(kh1,qh1,st);
      st=MFMA16(kl0,qh0,st); st=MFMA16(kl1,qh1,st);
      st=MFMA16(kh0,ql0,st); st=MFMA16(kh1,ql1,st);
      #pragma unroll
      for(int r=0;r<4;r++){
        int key = kv + sub*16 + lg*4 + r;
        float sv = (key <= q_lane)? st[r] : -1e30f;
        p[sub*4+r]=sv;
        tmax = fmaxf(tmax, sv);
      }
    }
    tmax = fmaxf(tmax, __shfl_xor(tmax,16,64));
    tmax = fmaxf(tmax, __shfl_xor(tmax,32,64));
    float mn = fmaxf(m, tmax);
    float sc = expf(m - mn);
    l *= sc;
    #pragma unroll
    for(int t2=0;t2<4;t2++)
      #pragma unroll
      for(int r=0;r<4;r++) ot[t2][r]*=sc;
    float ps=0.f;
    #pragma unroll
    for(int j=0;j<8;j++){ p[j]=expf(p[j]-mn); ps+=p[j]; }
    l+=ps; m=mn;
    bf16x8 ph, pl;
    #pragma unroll
    for(int j=0;j<8;j++){
      u16 hb2=f2b(p[j]);
      ph[j]=(short)hb2;
      pl[j]=(short)f2b(p[j]-b2f(hb2));
    }
    int k1o = kv + 4*lg;      if(k1o > S_-4) k1o = S_-4;  // masked tail: finite values, p==0
    int k2o = kv + 16 + 4*lg; if(k2o > S_-4) k2o = S_-4;
    #pragma unroll
    for(int t2=0;t2<4;t2++){
      long vro = ((long)bh*HD_ + t2*16 + lq)*S_;
      us4 vh0=*(const us4*)(VHI+vro+k1o);
      us4 vh1=*(const us4*)(VHI+vro+k2o);
      us4 vl0=*(const us4*)(VLO+vro+k1o);
      us4 vl1=*(const us4*)(VLO+vro+k2o);
      bf16x8 vh, vl;
      #pragma unroll
      for(int j=0;j<4;j++){
        vh[j]=(short)vh0[j]; vh[4+j]=(short)vh1[j];
        vl[j]=(short)vl0[j]; vl[4+j]=(short)vl1[j];
      }
      ot[t2]=MFMA16(vh,ph,ot[t2]);
      ot[t2]=MFMA16(vl,ph,ot[t2]);
      ot[t2]=MFMA16(vh,pl,ot[t2]);
    }
  }
  float l1 = l + __shfl_xor(l,16,64);
  float lt = l1 + __shfl_xor(l1,32,64);
  float inv = 1.f/lt;
  long orow = ((long)b*S_ + q_lane)*D_ + h*HD_;
  #pragma unroll
  for(int t2=0;t2<4;t2++){
    float4 o4;
    o4.x=ot[t2][0]*inv; o4.y=ot[t2][1]*inv; o4.z=ot[t2][2]*inv; o4.w=ot[t2][3]*inv;
    *(float4*)(OBF + orow + t2*16 + 4*lg) = o4;
  }
}

// ---------------- router (fp32, accurate expf) ----------------
__global__ __launch_bounds__(64) void k_router(const float* __restrict__ h2f, const float* __restrict__ Wr,
                         const float* __restrict__ rb, int* __restrict__ idx2,
                         float* __restrict__ w2, int* __restrict__ counts){
  int t=blockIdx.x, lane=threadIdx.x;
  float hv[9];
  #pragma unroll
  for(int j=0;j<9;j++) hv[j]=h2f[(long)t*D_+lane+64*j];
  float pr[7];
  #pragma unroll
  for(int e=0;e<7;e++){
    float s=0.f;
    #pragma unroll
    for(int j=0;j<9;j++) s += hv[j]*Wr[e*D_+lane+64*j];
    #pragma unroll
    for(int mm=1;mm<64;mm<<=1) s+=__shfl_xor(s,mm,64);
    pr[e] = 1.f/(1.f+expf(-(s+rb[e])));
  }
  int e0=0; float b0=pr[0];
  #pragma unroll
  for(int e=1;e<7;e++) if(pr[e]>b0){b0=pr[e];e0=e;}
  int e1=-1; float b1=-1e30f;
  #pragma unroll
  for(int e=0;e<7;e++) if(e!=e0 && pr[e]>b1){b1=pr[e];e1=e;}
  if(lane==0){
    float s=b0+b1;
    idx2[2*t]=e0; idx2[2*t+1]=e1;
    w2[2*t]=b0/s; w2[2*t+1]=b1/s;
    atomicAdd(&counts[e0],1);
    atomicAdd(&counts[e1],1);
  }
}

__global__ void k_offsets(const int* __restrict__ counts, int* __restrict__ ofs, int* __restrict__ fill){
  if(threadIdx.x==0 && blockIdx.x==0){
    int a=0;
    for(int e=0;e<NE_;e++){ ofs[e]=a; fill[e]=a; a+=counts[e]; }
    ofs[NE_]=a;
  }
}

__global__ void k_scatter(const int* __restrict__ idx2, const float* __restrict__ w2, int* __restrict__ fill,
                          int* __restrict__ ltok, float* __restrict__ lw, int* __restrict__ ppos){
  int t = blockIdx.x*256+threadIdx.x; if(t>=NT_) return;
  #pragma unroll
  for(int j=0;j<2;j++){
    int e = idx2[2*t+j];
    int pos = atomicAdd(&fill[e],1);
    ltok[pos]=t; lw[pos]=w2[2*t+j]; ppos[2*t+j]=pos;
  }
}

// ---------------- grouped gate+up+SwiGLU (bf16 MFMA) ----------------
__global__ __launch_bounds__(256) void k_moe_gu(const u16* __restrict__ h2b, const u16* __restrict__ Gb,
                        const u16* __restrict__ Ub, const int* __restrict__ cnt,
                        const int* __restrict__ ofs, const int* __restrict__ ltok,
                        u16* __restrict__ act){
  int e = blockIdx.z;
  int nrows = (e<NE_)? cnt[e] : NT_;
  int base  = (e<NE_)? ofs[e] : 0;
  long arow0 = (e<NE_)? (long)base : (long)NPAIR_;
  int mt = blockIdx.x;
  if(mt*128 >= nrows) return;
  int f0 = blockIdx.y*64;
  __shared__ u16 As[128*32], Gs[64*32], Us[64*32];
  int tid=threadIdx.x, wid=tid>>6, lane=tid&63;
  int lq=lane&15, lg=lane>>4;
  int wr=wid>>1, wc=wid&1;
  f32x4 ag[4][2]={}, au[4][2]={};
  for(int kt=0;kt<18;kt++){
    #pragma unroll
    for(int is=0;is<2;is++){
      int ub = is*4096 + wid*1024;
      int o = ub + lane*16;
      int row = o>>6, cb=o&63;
      int ridx = mt*128+row; if(ridx>nrows-1) ridx=nrows-1;
      int tok = (e<NE_)? ltok[base+ridx] : ridx;
      const u16* ga = h2b + (long)tok*D_ + kt*32 + (cb>>1);
      gll16(ga, (char*)As+ub);
    }
    {
      int ub = wid*1024;
      int o = ub + lane*16;
      int row=o>>6, cb=o&63;
      long wrow = (long)e*FF_ + f0 + row;
      gll16(Gb + wrow*D_ + kt*32 + (cb>>1), (char*)Gs+ub);
      gll16(Ub + wrow*D_ + kt*32 + (cb>>1), (char*)Us+ub);
    }
    __syncthreads();
    bf16x8 af[4], gf[2], uf[2];
    #pragma unroll
    for(int m=0;m<4;m++) af[m]=*(const bf16x8*)&As[(wr*64+m*16+lq)*32+lg*8];
    #pragma unroll
    for(int n=0;n<2;n++){
      gf[n]=*(const bf16x8*)&Gs[(wc*32+n*16+lq)*32+lg*8];
      uf[n]=*(const bf16x8*)&Us[(wc*32+n*16+lq)*32+lg*8];
    }
    #pragma unroll
    for(int m=0;m<4;m++)
      #pragma unroll
      for(int n=0;n<2;n++){
        ag[m][n]=MFMA16(af[m],gf[n],ag[m][n]);
        au[m][n]=MFMA16(af[m],uf[n],au[m][n]);
      }
    __syncthreads();
  }
  #pragma unroll
  for(int m=0;m<4;m++){
    #pragma unroll
    for(int n=0;n<2;n++){
      int f = f0 + wc*32+n*16+lq;
      #pragma unroll
      for(int r=0;r<4;r++){
        int rl = wr*64+m*16+lg*4+r;
        int ridx = mt*128+rl;
        if(ridx<nrows){
          float g=ag[m][n][r], u=au[m][n][r];
          float sw = g/(1.f+__expf(-g))*u;
          act[(arow0+ridx)*FF_ + f] = f2b(sw);
        }
      }
    }
  }
}

// ---------------- grouped down-proj (bf16 MFMA, weight folded) ---------
__global__ __launch_bounds__(256) void k_moe_down(const u16* __restrict__ act, const u16* __restrict__ Db,
                          const int* __restrict__ cnt, const int* __restrict__ ofs,
                          const float* __restrict__ lw, u16* __restrict__ pd){
  int e=blockIdx.z;
  int nrows=(e<NE_)?cnt[e]:NT_;
  long arow0=(e<NE_)?(long)ofs[e]:(long)NPAIR_;
  int mt=blockIdx.x;
  if(mt*128>=nrows) return;
  int n0=blockIdx.y*64;
  __shared__ u16 As[128*32], Bs[64*32];
  int tid=threadIdx.x,wid=tid>>6,lane=tid&63;
  int lq=lane&15,lg=lane>>4;
  int wr=wid>>1,wc=wid&1;
  f32x4 acc[4][2]={};
  for(int kt=0;kt<48;kt++){
    #pragma unroll
    for(int is=0;is<2;is++){
      int ub=is*4096+wid*1024;
      int o=ub+lane*16;
      int row=o>>6, cb=o&63;
      const u16* ga = act + (arow0 + mt*128+row)*FF_ + kt*32 + (cb>>1);
      gll16(ga,(char*)As+ub);
    }
    {
      int ub=wid*1024; int o=ub+lane*16;
      int row=o>>6, cb=o&63;
      const u16* gb = Db + ((long)e*D_ + n0+row)*FF_ + kt*32 + (cb>>1);
      gll16(gb,(char*)Bs+ub);
    }
    __syncthreads();
    bf16x8 af[4],bf2[2];
    #pragma unroll
    for(int m=0;m<4;m++) af[m]=*(const bf16x8*)&As[(wr*64+m*16+lq)*32+lg*8];
    #pragma unroll
    for(int n=0;n<2;n++) bf2[n]=*(const bf16x8*)&Bs[(wc*32+n*16+lq)*32+lg*8];
    #pragma unroll
    for(int m=0;m<4;m++)
      #pragma unroll
      for(int n=0;n<2;n++)
        acc[m][n]=MFMA16(af[m],bf2[n],acc[m][n]);
    __syncthreads();
  }
  #pragma unroll
  for(int m=0;m<4;m++){
    #pragma unroll
    for(int n=0;n<2;n++){
      int col=n0+wc*32+n*16+lq;
      #pragma unroll
      for(int r=0;r<4;r++){
        int rl=wr*64+m*16+lg*4+r;
        int ridx=mt*128+rl;
        if(ridx<nrows){
          float w=1.f;
          if(e<NE_) w=lw[arow0+ridx];
          pd[(arow0+ridx)*D_ + col]=f2b(w*acc[m][n][r]);
        }
      }
    }
  }
}

// ---------------- final combine ----------------
__global__ void k_final(const float* __restrict__ x2, const u16* __restrict__ pd,
                        const int* __restrict__ ppos, float* __restrict__ out){
  int i=blockIdx.x*256+threadIdx.x;
  int tot = NT_*(D_/4);
  if(i>=tot) return;
  int t = i/(D_/4); int c = (i - t*(D_/4))*4;
  int p0=ppos[2*t], p1=ppos[2*t+1];
  const u16* a=pd+((long)NPAIR_+t)*D_+c;
  const u16* b=pd+(long)p0*D_+c;
  const u16* d=pd+(long)p1*D_+c;
  const float* xr = x2+(long)t*D_+c;
  float* o = out+(long)t*D_+c;
  #pragma unroll
  for(int j=0;j<4;j++) o[j]=xr[j]+b2f(a[j])+b2f(b[j])+b2f(d[j]);
}

extern "C" void kernel_launch(void* const* d_in, const int* in_sizes, int n_in,
                              void* d_out, int out_size, void* d_ws, size_t ws_size,
                              hipStream_t stream){
  const float* x    =(const float*)d_in[0];
  const float* ln1  =(const float*)d_in[1];
  const float* ln2  =(const float*)d_in[2];
  const float* Wqd  =(const float*)d_in[3];
  const float* Wkvd =(const float*)d_in[4];
  const float* Wqu  =(const float*)d_in[5];
  const float* Wku  =(const float*)d_in[6];
  const float* Wvu  =(const float*)d_in[7];
  const float* Wo   =(const float*)d_in[8];
  const float* sg   =(const float*)d_in[9];
  const float* su   =(const float*)d_in[10];
  const float* sd   =(const float*)d_in[11];
  const float* rg   =(const float*)d_in[12];
  const float* ru   =(const float*)d_in[13];
  const float* rd   =(const float*)d_in[14];
  const float* Wr   =(const float*)d_in[15];
  const float* rb   =(const float*)d_in[16];
  float* out=(float*)d_out;

  char* ws=(char*)d_ws;
  size_t off=0;
  auto alloc=[&](size_t bsz){ size_t r=off; off=(off+bsz+255)&~(size_t)255; return r; };
  // fixed region
  u16* GB   =(u16*)(ws+alloc(8L*FF_*D_*2));
  u16* UB   =(u16*)(ws+alloc(8L*FF_*D_*2));
  u16* DB   =(u16*)(ws+alloc(8L*D_*FF_*2));
  float* COS=(float*)(ws+alloc(S_*32*4));
  float* SIN=(float*)(ws+alloc(S_*32*4));
  float* X2 =(float*)(ws+alloc((long)NT_*D_*4));
  float* H2F=(float*)(ws+alloc((long)NT_*D_*4));
  u16* H2B  =(u16*)(ws+alloc((long)NT_*D_*2));
  int* IDX2 =(int*)(ws+alloc(NT_*2*4));
  float* W2 =(float*)(ws+alloc(NT_*2*4));
  int* PPOS =(int*)(ws+alloc(NT_*2*4));
  int* CNT  =(int*)(ws+alloc(64));
  int* OFS  =(int*)(ws+alloc(64));
  int* FILL =(int*)(ws+alloc(64));
  int* LTOK =(int*)(ws+alloc(NPAIR_*4));
  float* LW =(float*)(ws+alloc(NPAIR_*4));
  size_t scr0 = off;
  // phase A (attention)
  const long NQ = (long)B_*H_*S_*HD_;   // 4.72M elems
  float* H1F=(float*)(ws+alloc((long)NT_*D_*4));
  float* LAT=(float*)(ws+alloc((long)NT_*288*4));
  float* QR =(float*)(ws+alloc((long)NT_*D_*4));
  float* KR =(float*)(ws+alloc((long)NT_*D_*4));
  float* VR =(float*)(ws+alloc((long)NT_*D_*4));
  u16* QHI =(u16*)(ws+alloc(NQ*2));
  u16* QLO =(u16*)(ws+alloc(NQ*2));
  u16* KHI =(u16*)(ws+alloc(NQ*2));
  u16* KLO =(u16*)(ws+alloc(NQ*2));
  u16* VHI =(u16*)(ws+alloc(NQ*2));
  u16* VLO =(u16*)(ws+alloc(NQ*2));
  float* OBF = QR;  // QR dead after k_ropesplit; reuse for attention output
  // phase B (MoE) overlaps phase A
  off = scr0;
  u16* ACT =(u16*)(ws+alloc((long)NACT_*FF_*2));
  u16* PD  =(u16*)(ws+alloc((long)NACT_*D_*2));
  (void)ws_size;

  // MoE weight conversion
  CvtSegs cs;
  {
    const float* ss[6]={rg,sg,ru,su,rd,sd};
    u16* dd[6]={GB, GB+7L*FF_*D_, UB, UB+7L*FF_*D_, DB, DB+7L*D_*FF_};
    long nn[6]={7L*FF_*D_,(long)FF_*D_,7L*FF_*D_,(long)FF_*D_,7L*D_*FF_,(long)D_*FF_};
    cs.start4[0]=0;
    for(int j=0;j<6;j++){ cs.src[j]=ss[j]; cs.dst[j]=dd[j]; cs.start4[j+1]=cs.start4[j]+(int)(nn[j]/4); }
  }
  k_cvt<<<2048,256,0,stream>>>(cs);
  k_rope_tab<<<(S_*32+255)/256,256,0,stream>>>(COS,SIN);

  // attention block (fp32 GEMMs + split-bf16 MFMA attention)
  k_rms<<<NT_,64,0,stream>>>(x, ln1, H1F, (u16*)nullptr);
  k_sgemm<true ,false><<<dim3(128,5),256,0,stream>>>(H1F,D_, Wqd,Wkvd,D_, 288,36, LAT,288, nullptr);
  k_sgemm<false,false><<<dim3(128,9),256,0,stream>>>(LAT    ,288, Wqu,nullptr,LAT_, D_,9, QR,D_, nullptr);
  k_sgemm<false,false><<<dim3(128,9),256,0,stream>>>(LAT+144,288, Wku,nullptr,LAT_, D_,9, KR,D_, nullptr);
  k_sgemm<false,false><<<dim3(128,9),256,0,stream>>>(LAT+144,288, Wvu,nullptr,LAT_, D_,9, VR,D_, nullptr);
  k_ropesplit<<<(NT_*H_*32+255)/256,256,0,stream>>>(QR,KR,COS,SIN,QHI,QLO,KHI,KLO);
  k_vsplit<<<dim3(16,72),256,0,stream>>>(VR,VHI,VLO);
  k_attn_split<<<dim3(16,72),256,0,stream>>>(QHI,QLO,KHI,KLO,VHI,VLO,OBF);
  k_sgemm<false,true ><<<dim3(128,9),256,0,stream>>>(OBF,D_, Wo,nullptr,D_, D_,36, X2,D_, x);

  // MoE block
  k_rms<<<NT_,64,0,stream>>>(X2, ln2, H2F, H2B);
  hipMemsetAsync(CNT,0,64,stream);
  k_router<<<NT_,64,0,stream>>>(H2F,Wr,rb,IDX2,W2,CNT);
  k_offsets<<<1,1,0,stream>>>(CNT,OFS,FILL);
  k_scatter<<<(NT_+255)/256,256,0,stream>>>(IDX2,W2,FILL,LTOK,LW,PPOS);
  k_moe_gu<<<dim3(64,24,8),256,0,stream>>>(H2B,GB,UB,CNT,OFS,LTOK,ACT);
  k_moe_down<<<dim3(64,9,8),256,0,stream>>>(ACT,DB,CNT,OFS,LW,PD);
  k_final<<<(NT_*(D_/4)+255)/256,256,0,stream>>>(X2,PD,PPOS,out);
}

// Round 5
// 1131.307 us; speedup vs baseline: 3.0825x; 1.2421x over previous
//
#include <hip/hip_runtime.h>
#include <stdint.h>
#include <math.h>

#define B_    8
#define S_    1024
#define D_    576
#define H_    9
#define HD_   64
#define LAT_  144
#define FF_   1536
#define NE_   7
#define NT_   8192
#define NPAIR_ 16384
#define NACT_  24576

typedef unsigned short u16;
typedef __attribute__((ext_vector_type(8))) short bf16x8;
typedef __attribute__((ext_vector_type(4))) float f32x4;
typedef __attribute__((ext_vector_type(4))) unsigned short us4;

__device__ __forceinline__ u16 f2b(float f){
  union{float f;uint32_t u;} v; v.f=f;
  uint32_t u=v.u;
  return (u16)((u + 0x7fffu + ((u>>16)&1u))>>16);
}
__device__ __forceinline__ float b2f(u16 h){
  union{uint32_t u;float f;} v; v.u=((uint32_t)h)<<16; return v.f;
}

#define MFMA16(a,b,c) __builtin_amdgcn_mfma_f32_16x16x32_bf16((a),(b),(c),0,0,0)

typedef __attribute__((address_space(1))) const unsigned char g_u8;
typedef __attribute__((address_space(3))) unsigned char s_u8;
__device__ __forceinline__ void gll16(const void* g, void* l){
  __builtin_amdgcn_global_load_lds((g_u8*)g, (s_u8*)l, 16, 0, 0);
}

// ---------------- MoE weight conversion fp32->bf16 ----------------
struct CvtSegs {
  const float* src[6];
  u16* dst[6];
  int start4[7];
};
__global__ void k_cvt(CvtSegs cs){
  int tot = cs.start4[6];
  for(int i = blockIdx.x*blockDim.x + threadIdx.x; i < tot; i += gridDim.x*blockDim.x){
    int s=0;
    #pragma unroll
    for(int j=0;j<6;j++) if(i >= cs.start4[j+1]) s=j+1;
    int loc = i - cs.start4[s];
    float4 v = ((const float4*)cs.src[s])[loc];
    us4 o; o[0]=f2b(v.x); o[1]=f2b(v.y); o[2]=f2b(v.z); o[3]=f2b(v.w);
    ((us4*)cs.dst[s])[loc] = o;
  }
}

// ---------------- attention weight conversion fp32 -> hi/lo bf16 -------
struct CvtSegs2 {
  const float* src[3];
  u16* dhi[3]; u16* dlo[3];
  int start4[4];
};
__global__ void k_cvt_split(CvtSegs2 cs){
  int tot = cs.start4[3];
  for(int i = blockIdx.x*blockDim.x + threadIdx.x; i < tot; i += gridDim.x*blockDim.x){
    int s=0;
    #pragma unroll
    for(int j=0;j<3;j++) if(i >= cs.start4[j+1]) s=j+1;
    int loc = i - cs.start4[s];
    float4 v = ((const float4*)cs.src[s])[loc];
    us4 oh, ol;
    float vv[4]={v.x,v.y,v.z,v.w};
    #pragma unroll
    for(int j=0;j<4;j++){ u16 hh=f2b(vv[j]); oh[j]=hh; ol[j]=f2b(vv[j]-b2f(hh)); }
    ((us4*)cs.dhi[s])[loc]=oh;
    ((us4*)cs.dlo[s])[loc]=ol;
  }
}

// up-proj weights [3][576][144] -> padded [3][576][160] hi/lo
__global__ void k_cvt_pad_split(const float* __restrict__ Wqu, const float* __restrict__ Wku,
                                const float* __restrict__ Wvu,
                                u16* __restrict__ dhi, u16* __restrict__ dlo){
  int i = blockIdx.x*256 + threadIdx.x;
  if(i >= 3*D_*160) return;
  int z = i/(D_*160); int rem = i - z*D_*160;
  int row = rem/160, col = rem - row*160;
  const float* s = (z==0)?Wqu:((z==1)?Wku:Wvu);
  float v = (col<LAT_)? s[row*LAT_+col] : 0.f;
  u16 hh=f2b(v);
  dhi[i]=hh; dlo[i]=f2b(v-b2f(hh));
}

// ---------------- RoPE tables ----------------
__global__ void k_rope_tab(float* __restrict__ cost, float* __restrict__ sint){
  int i = blockIdx.x*256+threadIdx.x; if(i>=S_*32) return;
  int s=i>>5, d=i&31;
  float pw = (float)pow(10000.0, (double)d/32.0);
  float inv = 1.0f/pw;
  float ang = (float)s*inv;
  cost[i]=cosf(ang); sint[i]=sinf(ang);
}

// ---------------- fp32 rmsnorm, multi-format output ----------------
__global__ __launch_bounds__(64) void k_rms(const float* __restrict__ x, const float* __restrict__ w,
                      float* __restrict__ hf, u16* __restrict__ hhi, u16* __restrict__ hlo,
                      u16* __restrict__ hb){
  int t = blockIdx.x; int lane = threadIdx.x;
  const float* xr = x + (size_t)t*D_;
  float v[9]; float ss=0.f;
  #pragma unroll
  for(int j=0;j<9;j++){ v[j]=xr[lane+64*j]; ss += v[j]*v[j]; }
  #pragma unroll
  for(int m=1;m<64;m<<=1) ss += __shfl_xor(ss,m,64);
  float sc = 1.0f/sqrtf(ss/(float)D_ + 1e-5f);
  #pragma unroll
  for(int j=0;j<9;j++){
    float y = v[j]*sc*w[lane+64*j];
    size_t o=(size_t)t*D_+lane+64*j;
    if(hf) hf[o]=y;
    if(hhi){ u16 hh=f2b(y); hhi[o]=hh; hlo[o]=f2b(y-b2f(hh)); }
    if(hb) hb[o]=f2b(y);
  }
}

// ---------------- split-bf16 128x128 MFMA GEMM: C = A(M,K)·B(N,K)^T ----
// 3-term expansion: Ah·Bh + Ah·Bl + Al·Bh  (error ~2^-17, fp32-class)
// EPI 0: hi/lo bf16 store with latent col remap (col<144 ? col : col+16)
// EPI 1: fp32 store (z-offset C)
// EPI 2: fp32 store = resid + acc
template<int EPI>
__global__ __launch_bounds__(256) void k_gemm2(
    const u16* __restrict__ Ahi, const u16* __restrict__ Alo, int lda, int aofs_z,
    const u16* __restrict__ Bhi, const u16* __restrict__ Blo, int ldb, long bStrideZ,
    int N, int ksteps,
    u16* __restrict__ Chi, u16* __restrict__ Clo, int ldc,
    float* __restrict__ C32, long cStrideZ, const float* __restrict__ resid)
{
  __shared__ u16 Ahs[128*32], Als[128*32], Bhs[128*32], Bls[128*32];
  int tid=threadIdx.x, wid=tid>>6, lane=tid&63;
  int m0=blockIdx.x*128, n0=blockIdx.y*128, z=blockIdx.z;
  const u16* Abh = Ahi + ((z>0)?aofs_z:0);
  const u16* Abl = Alo + ((z>0)?aofs_z:0);
  const u16* Bbh = Bhi + (long)z*bStrideZ;
  const u16* Bbl = Blo + (long)z*bStrideZ;
  int lq=lane&15, lg=lane>>4;
  int wr=wid>>1, wc=wid&1;
  f32x4 acc[4][4]={};
  for(int kt=0;kt<ksteps;kt++){
    #pragma unroll
    for(int is=0;is<2;is++){
      int ub = is*4096 + wid*1024;
      int o = ub + lane*16;
      int row = o>>6, cb = o&63;
      long aoff = (long)(m0+row)*lda + kt*32 + (cb>>1);
      gll16(Abh+aoff, (char*)Ahs+ub);
      gll16(Abl+aoff, (char*)Als+ub);
      int rowb = n0+row; rowb = rowb<N?rowb:(N-1);
      long boff = (long)rowb*ldb + kt*32 + (cb>>1);
      gll16(Bbh+boff, (char*)Bhs+ub);
      gll16(Bbl+boff, (char*)Bls+ub);
    }
    __syncthreads();
    bf16x8 ah[4], al[4], bh[4], bl[4];
    #pragma unroll
    for(int m=0;m<4;m++){
      ah[m]=*(const bf16x8*)&Ahs[(wr*64+m*16+lq)*32+lg*8];
      al[m]=*(const bf16x8*)&Als[(wr*64+m*16+lq)*32+lg*8];
    }
    #pragma unroll
    for(int n=0;n<4;n++){
      bh[n]=*(const bf16x8*)&Bhs[(wc*64+n*16+lq)*32+lg*8];
      bl[n]=*(const bf16x8*)&Bls[(wc*64+n*16+lq)*32+lg*8];
    }
    #pragma unroll
    for(int m=0;m<4;m++)
      #pragma unroll
      for(int n=0;n<4;n++){
        acc[m][n]=MFMA16(ah[m],bh[n],acc[m][n]);
        acc[m][n]=MFMA16(ah[m],bl[n],acc[m][n]);
        acc[m][n]=MFMA16(al[m],bh[n],acc[m][n]);
      }
    __syncthreads();
  }
  #pragma unroll
  for(int m=0;m<4;m++){
    #pragma unroll
    for(int n=0;n<4;n++){
      int col = n0 + wc*64 + n*16 + lq;
      if(col<N){
        #pragma unroll
        for(int r=0;r<4;r++){
          int row = m0 + wr*64 + m*16 + lg*4 + r;
          float val = acc[m][n][r];
          if(EPI==0){
            int dc = (col<144)? col : col+16;
            u16 hh=f2b(val);
            Chi[(long)row*ldc + dc] = hh;
            Clo[(long)row*ldc + dc] = f2b(val-b2f(hh));
          } else if(EPI==1){
            (C32 + (long)z*cStrideZ)[(long)row*ldc + col] = val;
          } else {
            C32[(long)row*ldc+col] = resid[(long)row*ldc+col] + val;
          }
        }
      }
    }
  }
}

// ---------------- RoPE + hi/lo split repack ----------------
__global__ void k_ropesplit(const float* __restrict__ QR, const float* __restrict__ KR,
                            const float* __restrict__ cost, const float* __restrict__ sint,
                            u16* __restrict__ QHI, u16* __restrict__ QLO,
                            u16* __restrict__ KHI, u16* __restrict__ KLO){
  int i = blockIdx.x*256+threadIdx.x;
  if(i >= NT_*H_*32) return;
  int d = i&31; int h=(i>>5)%H_; int t = i/(H_*32);
  int s = t & (S_-1); int b = t >> 10;
  float c = cost[s*32+d], sn = sint[s*32+d];
  long qi = (long)t*D_ + h*HD_ + d;
  float q1=QR[qi], q2=QR[qi+32];
  float k1=KR[qi], k2=KR[qi+32];
  long ob = ((long)(b*H_+h)*S_ + s)*HD_ + d;
  float qa=(q1*c - q2*sn)*0.125f, qb2=(q2*c + q1*sn)*0.125f;
  float ka=k1*c - k2*sn,          kb2=k2*c + k1*sn;
  u16 hh;
  hh=f2b(qa);  QHI[ob]=hh;    QLO[ob]   =f2b(qa -b2f(hh));
  hh=f2b(qb2); QHI[ob+32]=hh; QLO[ob+32]=f2b(qb2-b2f(hh));
  hh=f2b(ka);  KHI[ob]=hh;    KLO[ob]   =f2b(ka -b2f(hh));
  hh=f2b(kb2); KHI[ob+32]=hh; KLO[ob+32]=f2b(kb2-b2f(hh));
}

// ---------------- V transpose + hi/lo split: [b][s][576] -> [bh][64][S] --
__global__ __launch_bounds__(256) void k_vsplit(const float* __restrict__ VR,
                       u16* __restrict__ VHI, u16* __restrict__ VLO){
  __shared__ float ls[64][65];
  int s0 = blockIdx.x*64; int bh = blockIdx.y;
  int b = bh/H_, h = bh - b*H_;
  int tid=threadIdx.x;
  #pragma unroll
  for(int i=0;i<16;i++){
    int idx = tid + i*256;
    int si = idx>>6, dj = idx&63;
    ls[si][dj] = VR[((long)(b*S_+s0+si))*D_ + h*HD_ + dj];
  }
  __syncthreads();
  #pragma unroll
  for(int i=0;i<16;i++){
    int idx = tid + i*256;
    int di = idx>>6, sj = idx&63;
    float v = ls[sj][di];
    u16 hh = f2b(v);
    long o = ((long)bh*HD_+di)*S_ + s0+sj;
    VHI[o]=hh; VLO[o]=f2b(v-b2f(hh));
  }
}

// ---------------- split-bf16 MFMA flash attention (causal) -------------
// grid (8,72): block jb handles q-tiles {jb, 15-jb} -> constant work/block.
// 4 waves/block, 16 q rows per wave per tile. Output: hi/lo bf16.
__global__ __launch_bounds__(256) void k_attn_split(
    const u16* __restrict__ QHI, const u16* __restrict__ QLO,
    const u16* __restrict__ KHI, const u16* __restrict__ KLO,
    const u16* __restrict__ VHI, const u16* __restrict__ VLO,
    u16* __restrict__ OHI, u16* __restrict__ OLO){
  int tid=threadIdx.x, wid=tid>>6, lane=tid&63;
  int bh=blockIdx.y; int b=bh/H_, h=bh-b*H_;
  int jb=blockIdx.x;
  int lq=lane&15, lg=lane>>4;
  for(int pass=0;pass<2;pass++){
    int tile = pass? (15-jb) : jb;
    int q0 = tile*64 + wid*16;
    long qoff = ((long)bh*S_ + q0+lq)*HD_;
    bf16x8 qh0 = *(const bf16x8*)(QHI+qoff+lg*8);
    bf16x8 qh1 = *(const bf16x8*)(QHI+qoff+32+lg*8);
    bf16x8 ql0 = *(const bf16x8*)(QLO+qoff+lg*8);
    bf16x8 ql1 = *(const bf16x8*)(QLO+qoff+32+lg*8);
    float m=-1e30f, l=0.f;
    f32x4 ot[4]={};
    int q_lane = q0 + lq;
    for(int kv=0; kv<=q0+15; kv+=32){
      float p[8];
      float tmax=-1e30f;
      #pragma unroll
      for(int sub=0;sub<2;sub++){
        int krow = kv + sub*16 + lq; if(krow>S_-1) krow=S_-1;
        long koff = ((long)bh*S_+krow)*HD_;
        bf16x8 kh0=*(const bf16x8*)(KHI+koff+lg*8);
        bf16x8 kh1=*(const bf16x8*)(KHI+koff+32+lg*8);
        bf16x8 kl0=*(const bf16x8*)(KLO+koff+lg*8);
        bf16x8 kl1=*(const bf16x8*)(KLO+koff+32+lg*8);
        f32x4 st={0.f,0.f,0.f,0.f};
        st=MFMA16(kh0,qh0,st); st=MFMA16(kh1,qh1,st);
        st=MFMA16(kl0,qh0,st); st=MFMA16(kl1,qh1,st);
        st=MFMA16(kh0,ql0,st); st=MFMA16(kh1,ql1,st);
        #pragma unroll
        for(int r=0;r<4;r++){
          int key = kv + sub*16 + lg*4 + r;
          float sv = (key <= q_lane)? st[r] : -1e30f;
          p[sub*4+r]=sv;
          tmax = fmaxf(tmax, sv);
        }
      }
      tmax = fmaxf(tmax, __shfl_xor(tmax,16,64));
      tmax = fmaxf(tmax, __shfl_xor(tmax,32,64));
      float mn = fmaxf(m, tmax);
      float sc = __expf(m - mn);
      l *= sc;
      #pragma unroll
      for(int t2=0;t2<4;t2++)
        #pragma unroll
        for(int r=0;r<4;r++) ot[t2][r]*=sc;
      float ps=0.f;
      #pragma unroll
      for(int j=0;j<8;j++){ p[j]=__expf(p[j]-mn); ps+=p[j]; }
      l+=ps; m=mn;
      bf16x8 ph, pl;
      #pragma unroll
      for(int j=0;j<8;j++){
        u16 hb2=f2b(p[j]);
        ph[j]=(short)hb2;
        pl[j]=(short)f2b(p[j]-b2f(hb2));
      }
      int k1o = kv + 4*lg;      if(k1o > S_-4) k1o = S_-4;  // masked tail (p==0)
      int k2o = kv + 16 + 4*lg; if(k2o > S_-4) k2o = S_-4;
      #pragma unroll
      for(int t2=0;t2<4;t2++){
        long vro = ((long)bh*HD_ + t2*16 + lq)*S_;
        us4 vh0=*(const us4*)(VHI+vro+k1o);
        us4 vh1=*(const us4*)(VHI+vro+k2o);
        us4 vl0=*(const us4*)(VLO+vro+k1o);
        us4 vl1=*(const us4*)(VLO+vro+k2o);
        bf16x8 vh, vl;
        #pragma unroll
        for(int j=0;j<4;j++){
          vh[j]=(short)vh0[j]; vh[4+j]=(short)vh1[j];
          vl[j]=(short)vl0[j]; vl[4+j]=(short)vl1[j];
        }
        ot[t2]=MFMA16(vh,ph,ot[t2]);
        ot[t2]=MFMA16(vl,ph,ot[t2]);
        ot[t2]=MFMA16(vh,pl,ot[t2]);
      }
    }
    float l1 = l + __shfl_xor(l,16,64);
    float lt = l1 + __shfl_xor(l1,32,64);
    float inv = 1.f/lt;
    long orow = ((long)b*S_ + q_lane)*D_ + h*HD_;
    #pragma unroll
    for(int t2=0;t2<4;t2++){
      us4 oh4, ol4;
      #pragma unroll
      for(int r=0;r<4;r++){
        float v=ot[t2][r]*inv;
        u16 hh=f2b(v);
        oh4[r]=hh; ol4[r]=f2b(v-b2f(hh));
      }
      *(us4*)(OHI + orow + t2*16 + 4*lg) = oh4;
      *(us4*)(OLO + orow + t2*16 + 4*lg) = ol4;
    }
  }
}

// ---------------- router (fp32, accurate expf) ----------------
__global__ __launch_bounds__(64) void k_router(const float* __restrict__ h2f, const float* __restrict__ Wr,
                         const float* __restrict__ rb, int* __restrict__ idx2,
                         float* __restrict__ w2, int* __restrict__ counts){
  int t=blockIdx.x, lane=threadIdx.x;
  float hv[9];
  #pragma unroll
  for(int j=0;j<9;j++) hv[j]=h2f[(long)t*D_+lane+64*j];
  float pr[7];
  #pragma unroll
  for(int e=0;e<7;e++){
    float s=0.f;
    #pragma unroll
    for(int j=0;j<9;j++) s += hv[j]*Wr[e*D_+lane+64*j];
    #pragma unroll
    for(int mm=1;mm<64;mm<<=1) s+=__shfl_xor(s,mm,64);
    pr[e] = 1.f/(1.f+expf(-(s+rb[e])));
  }
  int e0=0; float b0=pr[0];
  #pragma unroll
  for(int e=1;e<7;e++) if(pr[e]>b0){b0=pr[e];e0=e;}
  int e1=-1; float b1=-1e30f;
  #pragma unroll
  for(int e=0;e<7;e++) if(e!=e0 && pr[e]>b1){b1=pr[e];e1=e;}
  if(lane==0){
    float s=b0+b1;
    idx2[2*t]=e0; idx2[2*t+1]=e1;
    w2[2*t]=b0/s; w2[2*t+1]=b1/s;
    atomicAdd(&counts[e0],1);
    atomicAdd(&counts[e1],1);
  }
}

__global__ void k_offsets(const int* __restrict__ counts, int* __restrict__ ofs, int* __restrict__ fill){
  if(threadIdx.x==0 && blockIdx.x==0){
    int a=0;
    for(int e=0;e<NE_;e++){ ofs[e]=a; fill[e]=a; a+=counts[e]; }
    ofs[NE_]=a;
  }
}

__global__ void k_scatter(const int* __restrict__ idx2, const float* __restrict__ w2, int* __restrict__ fill,
                          int* __restrict__ ltok, float* __restrict__ lw, int* __restrict__ ppos){
  int t = blockIdx.x*256+threadIdx.x; if(t>=NT_) return;
  #pragma unroll
  for(int j=0;j<2;j++){
    int e = idx2[2*t+j];
    int pos = atomicAdd(&fill[e],1);
    ltok[pos]=t; lw[pos]=w2[2*t+j]; ppos[2*t+j]=pos;
  }
}

// ---------------- grouped gate+up+SwiGLU (bf16 MFMA) ----------------
__global__ __launch_bounds__(256) void k_moe_gu(const u16* __restrict__ h2b, const u16* __restrict__ Gb,
                        const u16* __restrict__ Ub, const int* __restrict__ cnt,
                        const int* __restrict__ ofs, const int* __restrict__ ltok,
                        u16* __restrict__ act){
  int e = blockIdx.z;
  int nrows = (e<NE_)? cnt[e] : NT_;
  int base  = (e<NE_)? ofs[e] : 0;
  long arow0 = (e<NE_)? (long)base : (long)NPAIR_;
  int mt = blockIdx.x;
  if(mt*128 >= nrows) return;
  int f0 = blockIdx.y*64;
  __shared__ u16 As[128*32], Gs[64*32], Us[64*32];
  int tid=threadIdx.x, wid=tid>>6, lane=tid&63;
  int lq=lane&15, lg=lane>>4;
  int wr=wid>>1, wc=wid&1;
  f32x4 ag[4][2]={}, au[4][2]={};
  for(int kt=0;kt<18;kt++){
    #pragma unroll
    for(int is=0;is<2;is++){
      int ub = is*4096 + wid*1024;
      int o = ub + lane*16;
      int row = o>>6, cb=o&63;
      int ridx = mt*128+row; if(ridx>nrows-1) ridx=nrows-1;
      int tok = (e<NE_)? ltok[base+ridx] : ridx;
      const u16* ga = h2b + (long)tok*D_ + kt*32 + (cb>>1);
      gll16(ga, (char*)As+ub);
    }
    {
      int ub = wid*1024;
      int o = ub + lane*16;
      int row=o>>6, cb=o&63;
      long wrow = (long)e*FF_ + f0 + row;
      gll16(Gb + wrow*D_ + kt*32 + (cb>>1), (char*)Gs+ub);
      gll16(Ub + wrow*D_ + kt*32 + (cb>>1), (char*)Us+ub);
    }
    __syncthreads();
    bf16x8 af[4], gf[2], uf[2];
    #pragma unroll
    for(int m=0;m<4;m++) af[m]=*(const bf16x8*)&As[(wr*64+m*16+lq)*32+lg*8];
    #pragma unroll
    for(int n=0;n<2;n++){
      gf[n]=*(const bf16x8*)&Gs[(wc*32+n*16+lq)*32+lg*8];
      uf[n]=*(const bf16x8*)&Us[(wc*32+n*16+lq)*32+lg*8];
    }
    #pragma unroll
    for(int m=0;m<4;m++)
      #pragma unroll
      for(int n=0;n<2;n++){
        ag[m][n]=MFMA16(af[m],gf[n],ag[m][n]);
        au[m][n]=MFMA16(af[m],uf[n],au[m][n]);
      }
    __syncthreads();
  }
  #pragma unroll
  for(int m=0;m<4;m++){
    #pragma unroll
    for(int n=0;n<2;n++){
      int f = f0 + wc*32+n*16+lq;
      #pragma unroll
      for(int r=0;r<4;r++){
        int rl = wr*64+m*16+lg*4+r;
        int ridx = mt*128+rl;
        if(ridx<nrows){
          float g=ag[m][n][r], u=au[m][n][r];
          float sw = g/(1.f+__expf(-g))*u;
          act[(arow0+ridx)*FF_ + f] = f2b(sw);
        }
      }
    }
  }
}

// ---------------- grouped down-proj (bf16 MFMA, weight folded) ---------
__global__ __launch_bounds__(256) void k_moe_down(const u16* __restrict__ act, const u16* __restrict__ Db,
                          const int* __restrict__ cnt, const int* __restrict__ ofs,
                          const float* __restrict__ lw, u16* __restrict__ pd){
  int e=blockIdx.z;
  int nrows=(e<NE_)?cnt[e]:NT_;
  long arow0=(e<NE_)?(long)ofs[e]:(long)NPAIR_;
  int mt=blockIdx.x;
  if(mt*128>=nrows) return;
  int n0=blockIdx.y*64;
  __shared__ u16 As[128*32], Bs[64*32];
  int tid=threadIdx.x,wid=tid>>6,lane=tid&63;
  int lq=lane&15,lg=lane>>4;
  int wr=wid>>1,wc=wid&1;
  f32x4 acc[4][2]={};
  for(int kt=0;kt<48;kt++){
    #pragma unroll
    for(int is=0;is<2;is++){
      int ub=is*4096+wid*1024;
      int o=ub+lane*16;
      int row=o>>6, cb=o&63;
      const u16* ga = act + (arow0 + mt*128+row)*FF_ + kt*32 + (cb>>1);
      gll16(ga,(char*)As+ub);
    }
    {
      int ub=wid*1024; int o=ub+lane*16;
      int row=o>>6, cb=o&63;
      const u16* gb = Db + ((long)e*D_ + n0+row)*FF_ + kt*32 + (cb>>1);
      gll16(gb,(char*)Bs+ub);
    }
    __syncthreads();
    bf16x8 af[4],bf2[2];
    #pragma unroll
    for(int m=0;m<4;m++) af[m]=*(const bf16x8*)&As[(wr*64+m*16+lq)*32+lg*8];
    #pragma unroll
    for(int n=0;n<2;n++) bf2[n]=*(const bf16x8*)&Bs[(wc*32+n*16+lq)*32+lg*8];
    #pragma unroll
    for(int m=0;m<4;m++)
      #pragma unroll
      for(int n=0;n<2;n++)
        acc[m][n]=MFMA16(af[m],bf2[n],acc[m][n]);
    __syncthreads();
  }
  #pragma unroll
  for(int m=0;m<4;m++){
    #pragma unroll
    for(int n=0;n<2;n++){
      int col=n0+wc*32+n*16+lq;
      #pragma unroll
      for(int r=0;r<4;r++){
        int rl=wr*64+m*16+lg*4+r;
        int ridx=mt*128+rl;
        if(ridx<nrows){
          float w=1.f;
          if(e<NE_) w=lw[arow0+ridx];
          pd[(arow0+ridx)*D_ + col]=f2b(w*acc[m][n][r]);
        }
      }
    }
  }
}

// ---------------- final combine ----------------
__global__ void k_final(const float* __restrict__ x2, const u16* __restrict__ pd,
                        const int* __restrict__ ppos, float* __restrict__ out){
  int i=blockIdx.x*256+threadIdx.x;
  int tot = NT_*(D_/4);
  if(i>=tot) return;
  int t = i/(D_/4); int c = (i - t*(D_/4))*4;
  int p0=ppos[2*t], p1=ppos[2*t+1];
  const u16* a=pd+((long)NPAIR_+t)*D_+c;
  const u16* b=pd+(long)p0*D_+c;
  const u16* d=pd+(long)p1*D_+c;
  const float* xr = x2+(long)t*D_+c;
  float* o = out+(long)t*D_+c;
  #pragma unroll
  for(int j=0;j<4;j++) o[j]=xr[j]+b2f(a[j])+b2f(b[j])+b2f(d[j]);
}

extern "C" void kernel_launch(void* const* d_in, const int* in_sizes, int n_in,
                              void* d_out, int out_size, void* d_ws, size_t ws_size,
                              hipStream_t stream){
  const float* x    =(const float*)d_in[0];
  const float* ln1  =(const float*)d_in[1];
  const float* ln2  =(const float*)d_in[2];
  const float* Wqd  =(const float*)d_in[3];
  const float* Wkvd =(const float*)d_in[4];
  const float* Wqu  =(const float*)d_in[5];
  const float* Wku  =(const float*)d_in[6];
  const float* Wvu  =(const float*)d_in[7];
  const float* Wo   =(const float*)d_in[8];
  const float* sg   =(const float*)d_in[9];
  const float* su   =(const float*)d_in[10];
  const float* sd   =(const float*)d_in[11];
  const float* rg   =(const float*)d_in[12];
  const float* ru   =(const float*)d_in[13];
  const float* rd   =(const float*)d_in[14];
  const float* Wr   =(const float*)d_in[15];
  const float* rb   =(const float*)d_in[16];
  float* out=(float*)d_out;

  char* ws=(char*)d_ws;
  size_t off=0;
  auto alloc=[&](size_t bsz){ size_t r=off; off=(off+bsz+255)&~(size_t)255; return r; };
  // fixed region
  u16* GB   =(u16*)(ws+alloc(8L*FF_*D_*2));
  u16* UB   =(u16*)(ws+alloc(8L*FF_*D_*2));
  u16* DB   =(u16*)(ws+alloc(8L*D_*FF_*2));
  float* COS=(float*)(ws+alloc(S_*32*4));
  float* SIN=(float*)(ws+alloc(S_*32*4));
  float* X2 =(float*)(ws+alloc((long)NT_*D_*4));
  float* H2F=(float*)(ws+alloc((long)NT_*D_*4));
  u16* H2B  =(u16*)(ws+alloc((long)NT_*D_*2));
  int* IDX2 =(int*)(ws+alloc(NT_*2*4));
  float* W2 =(float*)(ws+alloc(NT_*2*4));
  int* PPOS =(int*)(ws+alloc(NT_*2*4));
  int* CNT  =(int*)(ws+alloc(64));
  int* OFS  =(int*)(ws+alloc(64));
  int* FILL =(int*)(ws+alloc(64));
  int* LTOK =(int*)(ws+alloc(NPAIR_*4));
  float* LW =(float*)(ws+alloc(NPAIR_*4));
  size_t scr0 = off;
  // phase A (attention)
  const long NQ = (long)B_*H_*S_*HD_;   // 4.72M elems
  u16* H1HI=(u16*)(ws+alloc((long)NT_*D_*2));
  u16* H1LO=(u16*)(ws+alloc((long)NT_*D_*2));
  u16* LATHI=(u16*)(ws+alloc((long)NT_*320*2));
  u16* LATLO=(u16*)(ws+alloc((long)NT_*320*2));
  float* QR =(float*)(ws+alloc((long)NT_*D_*4));
  float* KR =(float*)(ws+alloc((long)NT_*D_*4));
  float* VR =(float*)(ws+alloc((long)NT_*D_*4));
  u16* QHI =(u16*)(ws+alloc(NQ*2));
  u16* QLO =(u16*)(ws+alloc(NQ*2));
  u16* KHI =(u16*)(ws+alloc(NQ*2));
  u16* KLO =(u16*)(ws+alloc(NQ*2));
  u16* WDHI=(u16*)(ws+alloc(288L*D_*2));
  u16* WDLO=(u16*)(ws+alloc(288L*D_*2));
  u16* WUPHI=(u16*)(ws+alloc(3L*D_*160*2));
  u16* WUPLO=(u16*)(ws+alloc(3L*D_*160*2));
  u16* WOHI=(u16*)(ws+alloc((long)D_*D_*2));
  u16* WOLO=(u16*)(ws+alloc((long)D_*D_*2));
  // overlays: V splits land in QR/KR region (dead after k_ropesplit);
  // O splits land in H1 region (dead after down-proj GEMM).
  u16* VHI = (u16*)QR;
  u16* VLO = (u16*)QR + NQ;
  u16* OHI = H1HI;
  u16* OLO = H1LO;
  // phase B (MoE) overlaps phase A
  off = scr0;
  u16* ACT =(u16*)(ws+alloc((long)NACT_*FF_*2));
  u16* PD  =(u16*)(ws+alloc((long)NACT_*D_*2));
  (void)ws_size;

  // MoE weight conversion (plain bf16)
  CvtSegs cs;
  {
    const float* ss[6]={rg,sg,ru,su,rd,sd};
    u16* dd[6]={GB, GB+7L*FF_*D_, UB, UB+7L*FF_*D_, DB, DB+7L*D_*FF_};
    long nn[6]={7L*FF_*D_,(long)FF_*D_,7L*FF_*D_,(long)FF_*D_,7L*D_*FF_,(long)D_*FF_};
    cs.start4[0]=0;
    for(int j=0;j<6;j++){ cs.src[j]=ss[j]; cs.dst[j]=dd[j]; cs.start4[j+1]=cs.start4[j]+(int)(nn[j]/4); }
  }
  k_cvt<<<2048,256,0,stream>>>(cs);
  // attention weight conversion (hi/lo split)
  CvtSegs2 c2;
  {
    const float* ss[3]={Wqd, Wkvd, Wo};
    u16* dh[3]={WDHI, WDHI+144L*D_, WOHI};
    u16* dl[3]={WDLO, WDLO+144L*D_, WOLO};
    long nn[3]={144L*D_, 144L*D_, (long)D_*D_};
    c2.start4[0]=0;
    for(int j=0;j<3;j++){ c2.src[j]=ss[j]; c2.dhi[j]=dh[j]; c2.dlo[j]=dl[j]; c2.start4[j+1]=c2.start4[j]+(int)(nn[j]/4); }
  }
  k_cvt_split<<<512,256,0,stream>>>(c2);
  k_cvt_pad_split<<<(3*D_*160+255)/256,256,0,stream>>>(Wqu,Wku,Wvu,WUPHI,WUPLO);
  k_rope_tab<<<(S_*32+255)/256,256,0,stream>>>(COS,SIN);

  // attention block (split-bf16 MFMA throughout)
  k_rms<<<NT_,64,0,stream>>>(x, ln1, (float*)nullptr, H1HI, H1LO, (u16*)nullptr);
  hipMemsetAsync(LATHI, 0, (size_t)NT_*320*2, stream);
  hipMemsetAsync(LATLO, 0, (size_t)NT_*320*2, stream);
  k_gemm2<0><<<dim3(64,3,1),256,0,stream>>>(H1HI,H1LO,D_,0, WDHI,WDLO,D_,0, 288,18, LATHI,LATLO,320, nullptr,0,nullptr);
  k_gemm2<1><<<dim3(64,5,3),256,0,stream>>>(LATHI,LATLO,320,160, WUPHI,WUPLO,160,(long)D_*160, D_,5, nullptr,nullptr,D_, QR,(long)NT_*D_, nullptr);
  k_ropesplit<<<(NT_*H_*32+255)/256,256,0,stream>>>(QR,KR,COS,SIN,QHI,QLO,KHI,KLO);
  k_vsplit<<<dim3(16,72),256,0,stream>>>(VR,VHI,VLO);
  k_attn_split<<<dim3(8,72),256,0,stream>>>(QHI,QLO,KHI,KLO,VHI,VLO,OHI,OLO);
  k_gemm2<2><<<dim3(64,5,1),256,0,stream>>>(OHI,OLO,D_,0, WOHI,WOLO,D_,0, D_,18, nullptr,nullptr,D_, X2,0, x);

  // MoE block
  k_rms<<<NT_,64,0,stream>>>(X2, ln2, H2F, (u16*)nullptr, (u16*)nullptr, H2B);
  hipMemsetAsync(CNT,0,64,stream);
  k_router<<<NT_,64,0,stream>>>(H2F,Wr,rb,IDX2,W2,CNT);
  k_offsets<<<1,1,0,stream>>>(CNT,OFS,FILL);
  k_scatter<<<(NT_+255)/256,256,0,stream>>>(IDX2,W2,FILL,LTOK,LW,PPOS);
  k_moe_gu<<<dim3(64,24,8),256,0,stream>>>(H2B,GB,UB,CNT,OFS,LTOK,ACT);
  k_moe_down<<<dim3(64,9,8),256,0,stream>>>(ACT,DB,CNT,OFS,LW,PD);
  k_final<<<(NT_*(D_/4)+255)/256,256,0,stream>>>(X2,PD,PPOS,out);
}

// Round 6
// 943.536 us; speedup vs baseline: 3.6960x; 1.1990x over previous
//
#include <hip/hip_runtime.h>
#include <stdint.h>
#include <math.h>

#define B_    8
#define S_    1024
#define D_    576
#define H_    9
#define HD_   64
#define LAT_  144
#define FF_   1536
#define NE_   7
#define NT_   8192
#define NPAIR_ 16384
#define NACT_  24576

typedef unsigned short u16;
typedef __attribute__((ext_vector_type(8))) short bf16x8;
typedef __attribute__((ext_vector_type(4))) float f32x4;
typedef __attribute__((ext_vector_type(4))) unsigned short us4;

__device__ __forceinline__ u16 f2b(float f){
  union{float f;uint32_t u;} v; v.f=f;
  uint32_t u=v.u;
  return (u16)((u + 0x7fffu + ((u>>16)&1u))>>16);
}
__device__ __forceinline__ float b2f(u16 h){
  union{uint32_t u;float f;} v; v.u=((uint32_t)h)<<16; return v.f;
}

#define MFMA16(a,b,c) __builtin_amdgcn_mfma_f32_16x16x32_bf16((a),(b),(c),0,0,0)

typedef __attribute__((address_space(1))) const unsigned char g_u8;
typedef __attribute__((address_space(3))) unsigned char s_u8;
__device__ __forceinline__ void gll16(const void* g, void* l){
  __builtin_amdgcn_global_load_lds((g_u8*)g, (s_u8*)l, 16, 0, 0);
}

// ---------------- MoE weight conversion fp32->bf16 ----------------
struct CvtSegs {
  const float* src[6];
  u16* dst[6];
  int start4[7];
};
__global__ void k_cvt(CvtSegs cs){
  int tot = cs.start4[6];
  for(int i = blockIdx.x*blockDim.x + threadIdx.x; i < tot; i += gridDim.x*blockDim.x){
    int s=0;
    #pragma unroll
    for(int j=0;j<6;j++) if(i >= cs.start4[j+1]) s=j+1;
    int loc = i - cs.start4[s];
    float4 v = ((const float4*)cs.src[s])[loc];
    us4 o; o[0]=f2b(v.x); o[1]=f2b(v.y); o[2]=f2b(v.z); o[3]=f2b(v.w);
    ((us4*)cs.dst[s])[loc] = o;
  }
}

// ---------------- attention weight conversion fp32 -> hi/lo bf16 -------
struct CvtSegs2 {
  const float* src[3];
  u16* dhi[3]; u16* dlo[3];
  int start4[4];
};
__global__ void k_cvt_split(CvtSegs2 cs){
  int tot = cs.start4[3];
  for(int i = blockIdx.x*blockDim.x + threadIdx.x; i < tot; i += gridDim.x*blockDim.x){
    int s=0;
    #pragma unroll
    for(int j=0;j<3;j++) if(i >= cs.start4[j+1]) s=j+1;
    int loc = i - cs.start4[s];
    float4 v = ((const float4*)cs.src[s])[loc];
    us4 oh, ol;
    float vv[4]={v.x,v.y,v.z,v.w};
    #pragma unroll
    for(int j=0;j<4;j++){ u16 hh=f2b(vv[j]); oh[j]=hh; ol[j]=f2b(vv[j]-b2f(hh)); }
    ((us4*)cs.dhi[s])[loc]=oh;
    ((us4*)cs.dlo[s])[loc]=ol;
  }
}

// up-proj weights [3][576][144] -> padded [3][576][160] hi/lo
__global__ void k_cvt_pad_split(const float* __restrict__ Wqu, const float* __restrict__ Wku,
                                const float* __restrict__ Wvu,
                                u16* __restrict__ dhi, u16* __restrict__ dlo){
  int i = blockIdx.x*256 + threadIdx.x;
  if(i >= 3*D_*160) return;
  int z = i/(D_*160); int rem = i - z*D_*160;
  int row = rem/160, col = rem - row*160;
  const float* s = (z==0)?Wqu:((z==1)?Wku:Wvu);
  float v = (col<LAT_)? s[row*LAT_+col] : 0.f;
  u16 hh=f2b(v);
  dhi[i]=hh; dlo[i]=f2b(v-b2f(hh));
}

// ---------------- RoPE tables ----------------
__global__ void k_rope_tab(float* __restrict__ cost, float* __restrict__ sint){
  int i = blockIdx.x*256+threadIdx.x; if(i>=S_*32) return;
  int s=i>>5, d=i&31;
  float pw = (float)pow(10000.0, (double)d/32.0);
  float inv = 1.0f/pw;
  float ang = (float)s*inv;
  cost[i]=cosf(ang); sint[i]=sinf(ang);
}

// ---------------- fp32 rmsnorm, multi-format output ----------------
__global__ __launch_bounds__(64) void k_rms(const float* __restrict__ x, const float* __restrict__ w,
                      float* __restrict__ hf, u16* __restrict__ hhi, u16* __restrict__ hlo,
                      u16* __restrict__ hb){
  int t = blockIdx.x; int lane = threadIdx.x;
  const float* xr = x + (size_t)t*D_;
  float v[9]; float ss=0.f;
  #pragma unroll
  for(int j=0;j<9;j++){ v[j]=xr[lane+64*j]; ss += v[j]*v[j]; }
  #pragma unroll
  for(int m=1;m<64;m<<=1) ss += __shfl_xor(ss,m,64);
  float sc = 1.0f/sqrtf(ss/(float)D_ + 1e-5f);
  #pragma unroll
  for(int j=0;j<9;j++){
    float y = v[j]*sc*w[lane+64*j];
    size_t o=(size_t)t*D_+lane+64*j;
    if(hf) hf[o]=y;
    if(hhi){ u16 hh=f2b(y); hhi[o]=hh; hlo[o]=f2b(y-b2f(hh)); }
    if(hb) hb[o]=f2b(y);
  }
}

// ---------------- split-bf16 128x128 MFMA GEMM: C = A(M,K)·B(N,K)^T ----
// 3-term expansion: Ah·Bh + Ah·Bl + Al·Bh  (error ~2^-17, fp32-class)
// EPI 0: hi/lo bf16 store with latent col remap (col<144 ? col : col+16)
// EPI 1: fp32 store (z-offset C)
// EPI 2: fp32 store = resid + acc
template<int EPI>
__global__ __launch_bounds__(256) void k_gemm2(
    const u16* __restrict__ Ahi, const u16* __restrict__ Alo, int lda, int aofs_z,
    const u16* __restrict__ Bhi, const u16* __restrict__ Blo, int ldb, long bStrideZ,
    int N, int ksteps,
    u16* __restrict__ Chi, u16* __restrict__ Clo, int ldc,
    float* __restrict__ C32, long cStrideZ, const float* __restrict__ resid)
{
  __shared__ u16 Ahs[128*32], Als[128*32], Bhs[128*32], Bls[128*32];
  int tid=threadIdx.x, wid=tid>>6, lane=tid&63;
  int m0=blockIdx.x*128, n0=blockIdx.y*128, z=blockIdx.z;
  const u16* Abh = Ahi + ((z>0)?aofs_z:0);
  const u16* Abl = Alo + ((z>0)?aofs_z:0);
  const u16* Bbh = Bhi + (long)z*bStrideZ;
  const u16* Bbl = Blo + (long)z*bStrideZ;
  int lq=lane&15, lg=lane>>4;
  int wr=wid>>1, wc=wid&1;
  f32x4 acc[4][4]={};
  for(int kt=0;kt<ksteps;kt++){
    #pragma unroll
    for(int is=0;is<2;is++){
      int ub = is*4096 + wid*1024;
      int o = ub + lane*16;
      int row = o>>6, cb = o&63;
      long aoff = (long)(m0+row)*lda + kt*32 + (cb>>1);
      gll16(Abh+aoff, (char*)Ahs+ub);
      gll16(Abl+aoff, (char*)Als+ub);
      int rowb = n0+row; rowb = rowb<N?rowb:(N-1);
      long boff = (long)rowb*ldb + kt*32 + (cb>>1);
      gll16(Bbh+boff, (char*)Bhs+ub);
      gll16(Bbl+boff, (char*)Bls+ub);
    }
    __syncthreads();
    bf16x8 ah[4], al[4], bh[4], bl[4];
    #pragma unroll
    for(int m=0;m<4;m++){
      ah[m]=*(const bf16x8*)&Ahs[(wr*64+m*16+lq)*32+lg*8];
      al[m]=*(const bf16x8*)&Als[(wr*64+m*16+lq)*32+lg*8];
    }
    #pragma unroll
    for(int n=0;n<4;n++){
      bh[n]=*(const bf16x8*)&Bhs[(wc*64+n*16+lq)*32+lg*8];
      bl[n]=*(const bf16x8*)&Bls[(wc*64+n*16+lq)*32+lg*8];
    }
    #pragma unroll
    for(int m=0;m<4;m++)
      #pragma unroll
      for(int n=0;n<4;n++){
        acc[m][n]=MFMA16(ah[m],bh[n],acc[m][n]);
        acc[m][n]=MFMA16(ah[m],bl[n],acc[m][n]);
        acc[m][n]=MFMA16(al[m],bh[n],acc[m][n]);
      }
    __syncthreads();
  }
  #pragma unroll
  for(int m=0;m<4;m++){
    #pragma unroll
    for(int n=0;n<4;n++){
      int col = n0 + wc*64 + n*16 + lq;
      if(col<N){
        #pragma unroll
        for(int r=0;r<4;r++){
          int row = m0 + wr*64 + m*16 + lg*4 + r;
          float val = acc[m][n][r];
          if(EPI==0){
            int dc = (col<144)? col : col+16;
            u16 hh=f2b(val);
            Chi[(long)row*ldc + dc] = hh;
            Clo[(long)row*ldc + dc] = f2b(val-b2f(hh));
          } else if(EPI==1){
            (C32 + (long)z*cStrideZ)[(long)row*ldc + col] = val;
          } else {
            C32[(long)row*ldc+col] = resid[(long)row*ldc+col] + val;
          }
        }
      }
    }
  }
}

// ---------------- RoPE + hi/lo split repack ----------------
__global__ void k_ropesplit(const float* __restrict__ QR, const float* __restrict__ KR,
                            const float* __restrict__ cost, const float* __restrict__ sint,
                            u16* __restrict__ QHI, u16* __restrict__ QLO,
                            u16* __restrict__ KHI, u16* __restrict__ KLO){
  int i = blockIdx.x*256+threadIdx.x;
  if(i >= NT_*H_*32) return;
  int d = i&31; int h=(i>>5)%H_; int t = i/(H_*32);
  int s = t & (S_-1); int b = t >> 10;
  float c = cost[s*32+d], sn = sint[s*32+d];
  long qi = (long)t*D_ + h*HD_ + d;
  float q1=QR[qi], q2=QR[qi+32];
  float k1=KR[qi], k2=KR[qi+32];
  long ob = ((long)(b*H_+h)*S_ + s)*HD_ + d;
  float qa=(q1*c - q2*sn)*0.125f, qb2=(q2*c + q1*sn)*0.125f;
  float ka=k1*c - k2*sn,          kb2=k2*c + k1*sn;
  u16 hh;
  hh=f2b(qa);  QHI[ob]=hh;    QLO[ob]   =f2b(qa -b2f(hh));
  hh=f2b(qb2); QHI[ob+32]=hh; QLO[ob+32]=f2b(qb2-b2f(hh));
  hh=f2b(ka);  KHI[ob]=hh;    KLO[ob]   =f2b(ka -b2f(hh));
  hh=f2b(kb2); KHI[ob+32]=hh; KLO[ob+32]=f2b(kb2-b2f(hh));
}

// ---------------- V transpose + hi/lo split: [b][s][576] -> [bh][64][S] --
__global__ __launch_bounds__(256) void k_vsplit(const float* __restrict__ VR,
                       u16* __restrict__ VHI, u16* __restrict__ VLO){
  __shared__ float ls[64][65];
  int s0 = blockIdx.x*64; int bh = blockIdx.y;
  int b = bh/H_, h = bh - b*H_;
  int tid=threadIdx.x;
  #pragma unroll
  for(int i=0;i<16;i++){
    int idx = tid + i*256;
    int si = idx>>6, dj = idx&63;
    ls[si][dj] = VR[((long)(b*S_+s0+si))*D_ + h*HD_ + dj];
  }
  __syncthreads();
  #pragma unroll
  for(int i=0;i<16;i++){
    int idx = tid + i*256;
    int di = idx>>6, sj = idx&63;
    float v = ls[sj][di];
    u16 hh = f2b(v);
    long o = ((long)bh*HD_+di)*S_ + s0+sj;
    VHI[o]=hh; VLO[o]=f2b(v-b2f(hh));
  }
}

// ---------------- split-bf16 MFMA flash attention v3 -------------------
// grid (72, 8): x=bh (XCD-local K/V), y=jb; block handles q-tiles {jb,15-jb}.
// K/V tiles staged in LDS (XOR-swizzled via pre-swizzled global src),
// double-buffered 2-phase pipeline; shared by all 4 waves.
__global__ __launch_bounds__(256) void k_attn_split(
    const u16* __restrict__ QHI, const u16* __restrict__ QLO,
    const u16* __restrict__ KHI, const u16* __restrict__ KLO,
    const u16* __restrict__ VHI, const u16* __restrict__ VLO,
    u16* __restrict__ OHI, u16* __restrict__ OLO){
  __shared__ u16 lds[2][4][64*64];   // [buf][Khi,Klo,Vhi,Vlo][row*64]
  int tid=threadIdx.x, wid=tid>>6, lane=tid&63;
  int bh=blockIdx.x; int b=bh/H_, h=bh-b*H_;
  int jb=blockIdx.y;
  int lq=lane&15, lg=lane>>4;
  int jslot=lane&7, rloc=lane>>3;

  for(int pass=0;pass<2;pass++){
    int tile = pass? (15-jb) : jb;
    int ntile = tile+1;
    int q0 = tile*64 + wid*16;
    long qoff = ((long)bh*S_ + q0+lq)*HD_;
    bf16x8 qh0 = *(const bf16x8*)(QHI+qoff+lg*8);
    bf16x8 qh1 = *(const bf16x8*)(QHI+qoff+32+lg*8);
    bf16x8 ql0 = *(const bf16x8*)(QLO+qoff+lg*8);
    bf16x8 ql1 = *(const bf16x8*)(QLO+qoff+32+lg*8);
    float m=-1e30f, l=0.f;
    f32x4 ot[4]={};
    int q_lane = q0 + lq;

    // stage helper expanded inline (wave stages rows wid*16..+15 of each buf)
    #define STAGE(bufi, kv0_) do{                                          \
      int _kv0=(kv0_);                                                     \
      _Pragma("unroll")                                                    \
      for(int c=0;c<2;c++){                                                \
        int r = wid*16 + c*8 + rloc;                                       \
        int col = 8*(jslot ^ (r&7));                                       \
        long kg = ((long)bh*S_ + _kv0 + r)*64 + col;                       \
        long vg = ((long)bh*64 + r)*S_ + _kv0 + col;                       \
        int lb = (wid*16 + c*8)*64;                                        \
        gll16(KHI+kg, &lds[bufi][0][lb]);                                  \
        gll16(KLO+kg, &lds[bufi][1][lb]);                                  \
        gll16(VHI+vg, &lds[bufi][2][lb]);                                  \
        gll16(VLO+vg, &lds[bufi][3][lb]);                                  \
      } }while(0)

    STAGE(0, 0);
    __syncthreads();
    for(int t=0;t<ntile;t++){
      if(t+1<ntile) STAGE((t+1)&1, (t+1)*64);
      int bufc = t&1;
      int kv0 = t*64;
      bool last = (t==ntile-1);
      const char* Khs=(const char*)lds[bufc][0];
      const char* Kls=(const char*)lds[bufc][1];
      const char* Vhs=(const char*)lds[bufc][2];
      const char* Vls=(const char*)lds[bufc][3];
      #pragma unroll
      for(int kvh=0;kvh<64;kvh+=32){
        float p[8];
        float tmax=-1e30f;
        #pragma unroll
        for(int sub=0;sub<2;sub++){
          int r = kvh + sub*16 + lq;
          int sw = (r&7)<<4;
          bf16x8 kh0=*(const bf16x8*)(Khs + r*128 + ((lg*16) ^ sw));
          bf16x8 kh1=*(const bf16x8*)(Khs + r*128 + ((64+lg*16) ^ sw));
          bf16x8 kl0=*(const bf16x8*)(Kls + r*128 + ((lg*16) ^ sw));
          bf16x8 kl1=*(const bf16x8*)(Kls + r*128 + ((64+lg*16) ^ sw));
          f32x4 st={0.f,0.f,0.f,0.f};
          st=MFMA16(kh0,qh0,st); st=MFMA16(kh1,qh1,st);
          st=MFMA16(kl0,qh0,st); st=MFMA16(kl1,qh1,st);
          st=MFMA16(kh0,ql0,st); st=MFMA16(kh1,ql1,st);
          #pragma unroll
          for(int r2=0;r2<4;r2++){
            int key = kv0 + kvh + sub*16 + lg*4 + r2;
            float sv = (!last || key <= q_lane)? st[r2] : -1e30f;
            p[sub*4+r2]=sv;
            tmax = fmaxf(tmax, sv);
          }
        }
        tmax = fmaxf(tmax, __shfl_xor(tmax,16,64));
        tmax = fmaxf(tmax, __shfl_xor(tmax,32,64));
        float mn = fmaxf(m, tmax);
        float sc = __expf(m - mn);
        l *= sc;
        #pragma unroll
        for(int t2=0;t2<4;t2++)
          #pragma unroll
          for(int r2=0;r2<4;r2++) ot[t2][r2]*=sc;
        float ps=0.f;
        #pragma unroll
        for(int j=0;j<8;j++){ p[j]=__expf(p[j]-mn); ps+=p[j]; }
        l+=ps; m=mn;
        bf16x8 ph, pl;
        #pragma unroll
        for(int j=0;j<8;j++){
          u16 hb2=f2b(p[j]);
          ph[j]=(short)hb2;
          pl[j]=(short)f2b(p[j]-b2f(hb2));
        }
        #pragma unroll
        for(int t2=0;t2<4;t2++){
          int d = t2*16+lq;
          int swd = (d&7)<<4;
          int b1 = (2*(kvh+4*lg)) ^ swd;
          int b2v = (2*(kvh+16+4*lg)) ^ swd;
          us4 vh0=*(const us4*)(Vhs + d*128 + b1);
          us4 vh1=*(const us4*)(Vhs + d*128 + b2v);
          us4 vl0=*(const us4*)(Vls + d*128 + b1);
          us4 vl1=*(const us4*)(Vls + d*128 + b2v);
          bf16x8 vh, vl;
          #pragma unroll
          for(int j=0;j<4;j++){
            vh[j]=(short)vh0[j]; vh[4+j]=(short)vh1[j];
            vl[j]=(short)vl0[j]; vl[4+j]=(short)vl1[j];
          }
          ot[t2]=MFMA16(vh,ph,ot[t2]);
          ot[t2]=MFMA16(vl,ph,ot[t2]);
          ot[t2]=MFMA16(vh,pl,ot[t2]);
        }
      }
      __syncthreads();
    }
    #undef STAGE
    float l1 = l + __shfl_xor(l,16,64);
    float lt = l1 + __shfl_xor(l1,32,64);
    float inv = 1.f/lt;
    long orow = ((long)b*S_ + q_lane)*D_ + h*HD_;
    #pragma unroll
    for(int t2=0;t2<4;t2++){
      us4 oh4, ol4;
      #pragma unroll
      for(int r2=0;r2<4;r2++){
        float v=ot[t2][r2]*inv;
        u16 hh=f2b(v);
        oh4[r2]=hh; ol4[r2]=f2b(v-b2f(hh));
      }
      *(us4*)(OHI + orow + t2*16 + 4*lg) = oh4;
      *(us4*)(OLO + orow + t2*16 + 4*lg) = ol4;
    }
  }
}

// ---------------- router (fp32, accurate expf) ----------------
__global__ __launch_bounds__(64) void k_router(const float* __restrict__ h2f, const float* __restrict__ Wr,
                         const float* __restrict__ rb, int* __restrict__ idx2,
                         float* __restrict__ w2, int* __restrict__ counts){
  int t=blockIdx.x, lane=threadIdx.x;
  float hv[9];
  #pragma unroll
  for(int j=0;j<9;j++) hv[j]=h2f[(long)t*D_+lane+64*j];
  float pr[7];
  #pragma unroll
  for(int e=0;e<7;e++){
    float s=0.f;
    #pragma unroll
    for(int j=0;j<9;j++) s += hv[j]*Wr[e*D_+lane+64*j];
    #pragma unroll
    for(int mm=1;mm<64;mm<<=1) s+=__shfl_xor(s,mm,64);
    pr[e] = 1.f/(1.f+expf(-(s+rb[e])));
  }
  int e0=0; float b0=pr[0];
  #pragma unroll
  for(int e=1;e<7;e++) if(pr[e]>b0){b0=pr[e];e0=e;}
  int e1=-1; float b1=-1e30f;
  #pragma unroll
  for(int e=0;e<7;e++) if(e!=e0 && pr[e]>b1){b1=pr[e];e1=e;}
  if(lane==0){
    float s=b0+b1;
    idx2[2*t]=e0; idx2[2*t+1]=e1;
    w2[2*t]=b0/s; w2[2*t+1]=b1/s;
    atomicAdd(&counts[e0],1);
    atomicAdd(&counts[e1],1);
  }
}

__global__ void k_offsets(const int* __restrict__ counts, int* __restrict__ ofs, int* __restrict__ fill){
  if(threadIdx.x==0 && blockIdx.x==0){
    int a=0;
    for(int e=0;e<NE_;e++){ ofs[e]=a; fill[e]=a; a+=counts[e]; }
    ofs[NE_]=a;
  }
}

__global__ void k_scatter(const int* __restrict__ idx2, const float* __restrict__ w2, int* __restrict__ fill,
                          int* __restrict__ ltok, float* __restrict__ lw, int* __restrict__ ppos){
  int t = blockIdx.x*256+threadIdx.x; if(t>=NT_) return;
  #pragma unroll
  for(int j=0;j<2;j++){
    int e = idx2[2*t+j];
    int pos = atomicAdd(&fill[e],1);
    ltok[pos]=t; lw[pos]=w2[2*t+j]; ppos[2*t+j]=pos;
  }
}

// ---------------- token gather: AG[row] = H2B[ltok[row]] (rows NPAIR..: identity)
__global__ void k_gather(const int* __restrict__ ltok, const u16* __restrict__ h2b,
                         u16* __restrict__ ag){
  long i = (long)blockIdx.x*256+threadIdx.x;
  const int CPR = D_*2/16;   // 72 16B-chunks per row
  if(i >= (long)NACT_*CPR) return;
  int row = (int)(i/CPR), c = (int)(i - (long)row*CPR);
  int tok = (row<NPAIR_)? ltok[row] : (row-NPAIR_);
  ((ulonglong2*)ag)[(long)row*CPR + c] = ((const ulonglong2*)(h2b + (long)tok*D_))[c];
}

// ---------------- grouped gate+up+SwiGLU (bf16 MFMA) ----------------
__global__ __launch_bounds__(256) void k_moe_gu(const u16* __restrict__ ag, const u16* __restrict__ Gb,
                        const u16* __restrict__ Ub, const int* __restrict__ cnt,
                        const int* __restrict__ ofs, u16* __restrict__ act){
  int e = blockIdx.z;
  int nrows = (e<NE_)? cnt[e] : NT_;
  long arow0 = (e<NE_)? (long)ofs[e] : (long)NPAIR_;
  int mt = blockIdx.x;
  if(mt*128 >= nrows) return;
  int f0 = blockIdx.y*64;
  __shared__ u16 As[128*32], Gs[64*32], Us[64*32];
  int tid=threadIdx.x, wid=tid>>6, lane=tid&63;
  int lq=lane&15, lg=lane>>4;
  int wr=wid>>1, wc=wid&1;
  f32x4 ag_[4][2]={}, au_[4][2]={};
  for(int kt=0;kt<18;kt++){
    #pragma unroll
    for(int is=0;is<2;is++){
      int ub = is*4096 + wid*1024;
      int o = ub + lane*16;
      int row = o>>6, cb=o&63;
      int ridx = mt*128+row; if(ridx>nrows-1) ridx=nrows-1;
      const u16* gaa = ag + (arow0+ridx)*D_ + kt*32 + (cb>>1);
      gll16(gaa, (char*)As+ub);
    }
    {
      int ub = wid*1024;
      int o = ub + lane*16;
      int row=o>>6, cb=o&63;
      long wrow = (long)e*FF_ + f0 + row;
      gll16(Gb + wrow*D_ + kt*32 + (cb>>1), (char*)Gs+ub);
      gll16(Ub + wrow*D_ + kt*32 + (cb>>1), (char*)Us+ub);
    }
    __syncthreads();
    bf16x8 af[4], gf[2], uf[2];
    #pragma unroll
    for(int m=0;m<4;m++) af[m]=*(const bf16x8*)&As[(wr*64+m*16+lq)*32+lg*8];
    #pragma unroll
    for(int n=0;n<2;n++){
      gf[n]=*(const bf16x8*)&Gs[(wc*32+n*16+lq)*32+lg*8];
      uf[n]=*(const bf16x8*)&Us[(wc*32+n*16+lq)*32+lg*8];
    }
    #pragma unroll
    for(int m=0;m<4;m++)
      #pragma unroll
      for(int n=0;n<2;n++){
        ag_[m][n]=MFMA16(af[m],gf[n],ag_[m][n]);
        au_[m][n]=MFMA16(af[m],uf[n],au_[m][n]);
      }
    __syncthreads();
  }
  #pragma unroll
  for(int m=0;m<4;m++){
    #pragma unroll
    for(int n=0;n<2;n++){
      int f = f0 + wc*32+n*16+lq;
      #pragma unroll
      for(int r=0;r<4;r++){
        int rl = wr*64+m*16+lg*4+r;
        int ridx = mt*128+rl;
        if(ridx<nrows){
          float g=ag_[m][n][r], u=au_[m][n][r];
          float sw = g/(1.f+__expf(-g))*u;
          act[(arow0+ridx)*FF_ + f] = f2b(sw);
        }
      }
    }
  }
}

// ---------------- grouped down-proj (bf16 MFMA, weight folded) ---------
__global__ __launch_bounds__(256) void k_moe_down(const u16* __restrict__ act, const u16* __restrict__ Db,
                          const int* __restrict__ cnt, const int* __restrict__ ofs,
                          const float* __restrict__ lw, u16* __restrict__ pd){
  int e=blockIdx.z;
  int nrows=(e<NE_)?cnt[e]:NT_;
  long arow0=(e<NE_)?(long)ofs[e]:(long)NPAIR_;
  int mt=blockIdx.x;
  if(mt*128>=nrows) return;
  int n0=blockIdx.y*64;
  __shared__ u16 As[128*32], Bs[64*32];
  int tid=threadIdx.x,wid=tid>>6,lane=tid&63;
  int lq=lane&15,lg=lane>>4;
  int wr=wid>>1,wc=wid&1;
  f32x4 acc[4][2]={};
  for(int kt=0;kt<48;kt++){
    #pragma unroll
    for(int is=0;is<2;is++){
      int ub=is*4096+wid*1024;
      int o=ub+lane*16;
      int row=o>>6, cb=o&63;
      const u16* ga = act + (arow0 + mt*128+row)*FF_ + kt*32 + (cb>>1);
      gll16(ga,(char*)As+ub);
    }
    {
      int ub=wid*1024; int o=ub+lane*16;
      int row=o>>6, cb=o&63;
      const u16* gb = Db + ((long)e*D_ + n0+row)*FF_ + kt*32 + (cb>>1);
      gll16(gb,(char*)Bs+ub);
    }
    __syncthreads();
    bf16x8 af[4],bf2[2];
    #pragma unroll
    for(int m=0;m<4;m++) af[m]=*(const bf16x8*)&As[(wr*64+m*16+lq)*32+lg*8];
    #pragma unroll
    for(int n=0;n<2;n++) bf2[n]=*(const bf16x8*)&Bs[(wc*32+n*16+lq)*32+lg*8];
    #pragma unroll
    for(int m=0;m<4;m++)
      #pragma unroll
      for(int n=0;n<2;n++)
        acc[m][n]=MFMA16(af[m],bf2[n],acc[m][n]);
    __syncthreads();
  }
  #pragma unroll
  for(int m=0;m<4;m++){
    #pragma unroll
    for(int n=0;n<2;n++){
      int col=n0+wc*32+n*16+lq;
      #pragma unroll
      for(int r=0;r<4;r++){
        int rl=wr*64+m*16+lg*4+r;
        int ridx=mt*128+rl;
        if(ridx<nrows){
          float w=1.f;
          if(e<NE_) w=lw[arow0+ridx];
          pd[(arow0+ridx)*D_ + col]=f2b(w*acc[m][n][r]);
        }
      }
    }
  }
}

// ---------------- final combine ----------------
__global__ void k_final(const float* __restrict__ x2, const u16* __restrict__ pd,
                        const int* __restrict__ ppos, float* __restrict__ out){
  int i=blockIdx.x*256+threadIdx.x;
  int tot = NT_*(D_/4);
  if(i>=tot) return;
  int t = i/(D_/4); int c = (i - t*(D_/4))*4;
  int p0=ppos[2*t], p1=ppos[2*t+1];
  const u16* a=pd+((long)NPAIR_+t)*D_+c;
  const u16* b=pd+(long)p0*D_+c;
  const u16* d=pd+(long)p1*D_+c;
  const float* xr = x2+(long)t*D_+c;
  float* o = out+(long)t*D_+c;
  #pragma unroll
  for(int j=0;j<4;j++) o[j]=xr[j]+b2f(a[j])+b2f(b[j])+b2f(d[j]);
}

extern "C" void kernel_launch(void* const* d_in, const int* in_sizes, int n_in,
                              void* d_out, int out_size, void* d_ws, size_t ws_size,
                              hipStream_t stream){
  const float* x    =(const float*)d_in[0];
  const float* ln1  =(const float*)d_in[1];
  const float* ln2  =(const float*)d_in[2];
  const float* Wqd  =(const float*)d_in[3];
  const float* Wkvd =(const float*)d_in[4];
  const float* Wqu  =(const float*)d_in[5];
  const float* Wku  =(const float*)d_in[6];
  const float* Wvu  =(const float*)d_in[7];
  const float* Wo   =(const float*)d_in[8];
  const float* sg   =(const float*)d_in[9];
  const float* su   =(const float*)d_in[10];
  const float* sd   =(const float*)d_in[11];
  const float* rg   =(const float*)d_in[12];
  const float* ru   =(const float*)d_in[13];
  const float* rd   =(const float*)d_in[14];
  const float* Wr   =(const float*)d_in[15];
  const float* rb   =(const float*)d_in[16];
  float* out=(float*)d_out;

  char* ws=(char*)d_ws;
  size_t off=0;
  auto alloc=[&](size_t bsz){ size_t r=off; off=(off+bsz+255)&~(size_t)255; return r; };
  // fixed region
  u16* GB   =(u16*)(ws+alloc(8L*FF_*D_*2));
  u16* UB   =(u16*)(ws+alloc(8L*FF_*D_*2));
  u16* DB   =(u16*)(ws+alloc(8L*D_*FF_*2));
  float* COS=(float*)(ws+alloc(S_*32*4));
  float* SIN=(float*)(ws+alloc(S_*32*4));
  float* X2 =(float*)(ws+alloc((long)NT_*D_*4));
  float* H2F=(float*)(ws+alloc((long)NT_*D_*4));
  u16* H2B  =(u16*)(ws+alloc((long)NT_*D_*2));
  int* IDX2 =(int*)(ws+alloc(NT_*2*4));
  float* W2 =(float*)(ws+alloc(NT_*2*4));
  int* PPOS =(int*)(ws+alloc(NT_*2*4));
  int* CNT  =(int*)(ws+alloc(64));
  int* OFS  =(int*)(ws+alloc(64));
  int* FILL =(int*)(ws+alloc(64));
  int* LTOK =(int*)(ws+alloc(NPAIR_*4));
  float* LW =(float*)(ws+alloc(NPAIR_*4));
  size_t scr0 = off;
  // phase A (attention)
  const long NQ = (long)B_*H_*S_*HD_;   // 4.72M elems
  u16* H1HI=(u16*)(ws+alloc((long)NT_*D_*2));
  u16* H1LO=(u16*)(ws+alloc((long)NT_*D_*2));
  u16* LATHI=(u16*)(ws+alloc((long)NT_*320*2));
  u16* LATLO=(u16*)(ws+alloc((long)NT_*320*2));
  float* QR =(float*)(ws+alloc((long)NT_*D_*4));
  float* KR =(float*)(ws+alloc((long)NT_*D_*4));
  float* VR =(float*)(ws+alloc((long)NT_*D_*4));
  u16* QHI =(u16*)(ws+alloc(NQ*2));
  u16* QLO =(u16*)(ws+alloc(NQ*2));
  u16* KHI =(u16*)(ws+alloc(NQ*2));
  u16* KLO =(u16*)(ws+alloc(NQ*2));
  u16* WDHI=(u16*)(ws+alloc(288L*D_*2));
  u16* WDLO=(u16*)(ws+alloc(288L*D_*2));
  u16* WUPHI=(u16*)(ws+alloc(3L*D_*160*2));
  u16* WUPLO=(u16*)(ws+alloc(3L*D_*160*2));
  u16* WOHI=(u16*)(ws+alloc((long)D_*D_*2));
  u16* WOLO=(u16*)(ws+alloc((long)D_*D_*2));
  // overlays: V splits land in QR/KR region (dead after k_ropesplit);
  // O splits land in H1 region (dead after Wo GEMM).
  u16* VHI = (u16*)QR;
  u16* VLO = (u16*)QR + NQ;
  u16* OHI = H1HI;
  u16* OLO = H1LO;
  // phase B (MoE) overlaps phase A
  off = scr0;
  u16* ACT =(u16*)(ws+alloc((long)NACT_*FF_*2));
  u16* PD  =(u16*)(ws+alloc((long)NACT_*D_*2));
  u16* AG  =(u16*)(ws+alloc((long)NACT_*D_*2));
  (void)ws_size;

  // MoE weight conversion (plain bf16)
  CvtSegs cs;
  {
    const float* ss[6]={rg,sg,ru,su,rd,sd};
    u16* dd[6]={GB, GB+7L*FF_*D_, UB, UB+7L*FF_*D_, DB, DB+7L*D_*FF_};
    long nn[6]={7L*FF_*D_,(long)FF_*D_,7L*FF_*D_,(long)FF_*D_,7L*D_*FF_,(long)D_*FF_};
    cs.start4[0]=0;
    for(int j=0;j<6;j++){ cs.src[j]=ss[j]; cs.dst[j]=dd[j]; cs.start4[j+1]=cs.start4[j]+(int)(nn[j]/4); }
  }
  k_cvt<<<2048,256,0,stream>>>(cs);
  // attention weight conversion (hi/lo split)
  CvtSegs2 c2;
  {
    const float* ss[3]={Wqd, Wkvd, Wo};
    u16* dh[3]={WDHI, WDHI+144L*D_, WOHI};
    u16* dl[3]={WDLO, WDLO+144L*D_, WOLO};
    long nn[3]={144L*D_, 144L*D_, (long)D_*D_};
    c2.start4[0]=0;
    for(int j=0;j<3;j++){ c2.src[j]=ss[j]; c2.dhi[j]=dh[j]; c2.dlo[j]=dl[j]; c2.start4[j+1]=c2.start4[j]+(int)(nn[j]/4); }
  }
  k_cvt_split<<<512,256,0,stream>>>(c2);
  k_cvt_pad_split<<<(3*D_*160+255)/256,256,0,stream>>>(Wqu,Wku,Wvu,WUPHI,WUPLO);
  k_rope_tab<<<(S_*32+255)/256,256,0,stream>>>(COS,SIN);

  // attention block (split-bf16 MFMA throughout)
  k_rms<<<NT_,64,0,stream>>>(x, ln1, (float*)nullptr, H1HI, H1LO, (u16*)nullptr);
  hipMemsetAsync(LATHI, 0, (size_t)NT_*320*2, stream);
  hipMemsetAsync(LATLO, 0, (size_t)NT_*320*2, stream);
  k_gemm2<0><<<dim3(64,3,1),256,0,stream>>>(H1HI,H1LO,D_,0, WDHI,WDLO,D_,0, 288,18, LATHI,LATLO,320, nullptr,0,nullptr);
  k_gemm2<1><<<dim3(64,5,3),256,0,stream>>>(LATHI,LATLO,320,160, WUPHI,WUPLO,160,(long)D_*160, D_,5, nullptr,nullptr,D_, QR,(long)NT_*D_, nullptr);
  k_ropesplit<<<(NT_*H_*32+255)/256,256,0,stream>>>(QR,KR,COS,SIN,QHI,QLO,KHI,KLO);
  k_vsplit<<<dim3(16,72),256,0,stream>>>(VR,VHI,VLO);
  k_attn_split<<<dim3(72,8),256,0,stream>>>(QHI,QLO,KHI,KLO,VHI,VLO,OHI,OLO);
  k_gemm2<2><<<dim3(64,5,1),256,0,stream>>>(OHI,OLO,D_,0, WOHI,WOLO,D_,0, D_,18, nullptr,nullptr,D_, X2,0, x);

  // MoE block
  k_rms<<<NT_,64,0,stream>>>(X2, ln2, H2F, (u16*)nullptr, (u16*)nullptr, H2B);
  hipMemsetAsync(CNT,0,64,stream);
  k_router<<<NT_,64,0,stream>>>(H2F,Wr,rb,IDX2,W2,CNT);
  k_offsets<<<1,1,0,stream>>>(CNT,OFS,FILL);
  k_scatter<<<(NT_+255)/256,256,0,stream>>>(IDX2,W2,FILL,LTOK,LW,PPOS);
  {
    long tot = (long)NACT_*(D_*2/16);
    k_gather<<<(int)((tot+255)/256),256,0,stream>>>(LTOK,H2B,AG);
  }
  k_moe_gu<<<dim3(64,24,8),256,0,stream>>>(AG,GB,UB,CNT,OFS,ACT);
  k_moe_down<<<dim3(64,9,8),256,0,stream>>>(ACT,DB,CNT,OFS,LW,PD);
  k_final<<<(NT_*(D_/4)+255)/256,256,0,stream>>>(X2,PD,PPOS,out);
}

// Round 7
// 842.540 us; speedup vs baseline: 4.1390x; 1.1199x over previous
//
#include <hip/hip_runtime.h>
#include <stdint.h>
#include <math.h>

#define B_    8
#define S_    1024
#define D_    576
#define H_    9
#define HD_   64
#define LAT_  144
#define FF_   1536
#define NE_   7
#define NT_   8192
#define NPAIR_ 16384
#define NACT_  24576

typedef unsigned short u16;
typedef __attribute__((ext_vector_type(8))) short bf16x8;
typedef __attribute__((ext_vector_type(4))) float f32x4;
typedef __attribute__((ext_vector_type(4))) unsigned short us4;

__device__ __forceinline__ u16 f2b(float f){
  union{float f;uint32_t u;} v; v.f=f;
  uint32_t u=v.u;
  return (u16)((u + 0x7fffu + ((u>>16)&1u))>>16);
}
__device__ __forceinline__ float b2f(u16 h){
  union{uint32_t u;float f;} v; v.u=((uint32_t)h)<<16; return v.f;
}

#define MFMA16(a,b,c) __builtin_amdgcn_mfma_f32_16x16x32_bf16((a),(b),(c),0,0,0)

typedef __attribute__((address_space(1))) const unsigned char g_u8;
typedef __attribute__((address_space(3))) unsigned char s_u8;
__device__ __forceinline__ void gll16(const void* g, void* l){
  __builtin_amdgcn_global_load_lds((g_u8*)g, (s_u8*)l, 16, 0, 0);
}

// ---------------- MoE weight conversion fp32->bf16 ----------------
struct CvtSegs {
  const float* src[6];
  u16* dst[6];
  int start4[7];
};
__global__ void k_cvt(CvtSegs cs){
  int tot = cs.start4[6];
  for(int i = blockIdx.x*blockDim.x + threadIdx.x; i < tot; i += gridDim.x*blockDim.x){
    int s=0;
    #pragma unroll
    for(int j=0;j<6;j++) if(i >= cs.start4[j+1]) s=j+1;
    int loc = i - cs.start4[s];
    float4 v = ((const float4*)cs.src[s])[loc];
    us4 o; o[0]=f2b(v.x); o[1]=f2b(v.y); o[2]=f2b(v.z); o[3]=f2b(v.w);
    ((us4*)cs.dst[s])[loc] = o;
  }
}

// ---------------- attention weight conversion fp32 -> hi/lo bf16 -------
struct CvtSegs2 {
  const float* src[3];
  u16* dhi[3]; u16* dlo[3];
  int start4[4];
};
__global__ void k_cvt_split(CvtSegs2 cs){
  int tot = cs.start4[3];
  for(int i = blockIdx.x*blockDim.x + threadIdx.x; i < tot; i += gridDim.x*blockDim.x){
    int s=0;
    #pragma unroll
    for(int j=0;j<3;j++) if(i >= cs.start4[j+1]) s=j+1;
    int loc = i - cs.start4[s];
    float4 v = ((const float4*)cs.src[s])[loc];
    us4 oh, ol;
    float vv[4]={v.x,v.y,v.z,v.w};
    #pragma unroll
    for(int j=0;j<4;j++){ u16 hh=f2b(vv[j]); oh[j]=hh; ol[j]=f2b(vv[j]-b2f(hh)); }
    ((us4*)cs.dhi[s])[loc]=oh;
    ((us4*)cs.dlo[s])[loc]=ol;
  }
}

// up-proj weights [3][576][144] -> padded [3][576][160] hi/lo
__global__ void k_cvt_pad_split(const float* __restrict__ Wqu, const float* __restrict__ Wku,
                                const float* __restrict__ Wvu,
                                u16* __restrict__ dhi, u16* __restrict__ dlo){
  int i = blockIdx.x*256 + threadIdx.x;
  if(i >= 3*D_*160) return;
  int z = i/(D_*160); int rem = i - z*D_*160;
  int row = rem/160, col = rem - row*160;
  const float* s = (z==0)?Wqu:((z==1)?Wku:Wvu);
  float v = (col<LAT_)? s[row*LAT_+col] : 0.f;
  u16 hh=f2b(v);
  dhi[i]=hh; dlo[i]=f2b(v-b2f(hh));
}

// ---------------- RoPE tables ----------------
__global__ void k_rope_tab(float* __restrict__ cost, float* __restrict__ sint){
  int i = blockIdx.x*256+threadIdx.x; if(i>=S_*32) return;
  int s=i>>5, d=i&31;
  float pw = (float)pow(10000.0, (double)d/32.0);
  float inv = 1.0f/pw;
  float ang = (float)s*inv;
  cost[i]=cosf(ang); sint[i]=sinf(ang);
}

// ---------------- fp32 rmsnorm, multi-format output ----------------
__global__ __launch_bounds__(64) void k_rms(const float* __restrict__ x, const float* __restrict__ w,
                      float* __restrict__ hf, u16* __restrict__ hhi, u16* __restrict__ hlo,
                      u16* __restrict__ hb){
  int t = blockIdx.x; int lane = threadIdx.x;
  const float* xr = x + (size_t)t*D_;
  float v[9]; float ss=0.f;
  #pragma unroll
  for(int j=0;j<9;j++){ v[j]=xr[lane+64*j]; ss += v[j]*v[j]; }
  #pragma unroll
  for(int m=1;m<64;m<<=1) ss += __shfl_xor(ss,m,64);
  float sc = 1.0f/sqrtf(ss/(float)D_ + 1e-5f);
  #pragma unroll
  for(int j=0;j<9;j++){
    float y = v[j]*sc*w[lane+64*j];
    size_t o=(size_t)t*D_+lane+64*j;
    if(hf) hf[o]=y;
    if(hhi){ u16 hh=f2b(y); hhi[o]=hh; hlo[o]=f2b(y-b2f(hh)); }
    if(hb) hb[o]=f2b(y);
  }
}

// ---------------- split-bf16 128x128 MFMA GEMM: C = A(M,K)·B(N,K)^T ----
template<int EPI>
__global__ __launch_bounds__(256) void k_gemm2(
    const u16* __restrict__ Ahi, const u16* __restrict__ Alo, int lda, int aofs_z,
    const u16* __restrict__ Bhi, const u16* __restrict__ Blo, int ldb, long bStrideZ,
    int N, int ksteps,
    u16* __restrict__ Chi, u16* __restrict__ Clo, int ldc,
    float* __restrict__ C32, long cStrideZ, const float* __restrict__ resid)
{
  __shared__ u16 Ahs[128*32], Als[128*32], Bhs[128*32], Bls[128*32];
  int tid=threadIdx.x, wid=tid>>6, lane=tid&63;
  int m0=blockIdx.x*128, n0=blockIdx.y*128, z=blockIdx.z;
  const u16* Abh = Ahi + ((z>0)?aofs_z:0);
  const u16* Abl = Alo + ((z>0)?aofs_z:0);
  const u16* Bbh = Bhi + (long)z*bStrideZ;
  const u16* Bbl = Blo + (long)z*bStrideZ;
  int lq=lane&15, lg=lane>>4;
  int wr=wid>>1, wc=wid&1;
  f32x4 acc[4][4]={};
  for(int kt=0;kt<ksteps;kt++){
    #pragma unroll
    for(int is=0;is<2;is++){
      int ub = is*4096 + wid*1024;
      int o = ub + lane*16;
      int row = o>>6, cb = o&63;
      long aoff = (long)(m0+row)*lda + kt*32 + (cb>>1);
      gll16(Abh+aoff, (char*)Ahs+ub);
      gll16(Abl+aoff, (char*)Als+ub);
      int rowb = n0+row; rowb = rowb<N?rowb:(N-1);
      long boff = (long)rowb*ldb + kt*32 + (cb>>1);
      gll16(Bbh+boff, (char*)Bhs+ub);
      gll16(Bbl+boff, (char*)Bls+ub);
    }
    __syncthreads();
    bf16x8 ah[4], al[4], bh[4], bl[4];
    #pragma unroll
    for(int m=0;m<4;m++){
      ah[m]=*(const bf16x8*)&Ahs[(wr*64+m*16+lq)*32+lg*8];
      al[m]=*(const bf16x8*)&Als[(wr*64+m*16+lq)*32+lg*8];
    }
    #pragma unroll
    for(int n=0;n<4;n++){
      bh[n]=*(const bf16x8*)&Bhs[(wc*64+n*16+lq)*32+lg*8];
      bl[n]=*(const bf16x8*)&Bls[(wc*64+n*16+lq)*32+lg*8];
    }
    #pragma unroll
    for(int m=0;m<4;m++)
      #pragma unroll
      for(int n=0;n<4;n++){
        acc[m][n]=MFMA16(ah[m],bh[n],acc[m][n]);
        acc[m][n]=MFMA16(ah[m],bl[n],acc[m][n]);
        acc[m][n]=MFMA16(al[m],bh[n],acc[m][n]);
      }
    __syncthreads();
  }
  #pragma unroll
  for(int m=0;m<4;m++){
    #pragma unroll
    for(int n=0;n<4;n++){
      int col = n0 + wc*64 + n*16 + lq;
      if(col<N){
        #pragma unroll
        for(int r=0;r<4;r++){
          int row = m0 + wr*64 + m*16 + lg*4 + r;
          float val = acc[m][n][r];
          if(EPI==0){
            int dc = (col<144)? col : col+16;
            u16 hh=f2b(val);
            Chi[(long)row*ldc + dc] = hh;
            Clo[(long)row*ldc + dc] = f2b(val-b2f(hh));
          } else if(EPI==1){
            (C32 + (long)z*cStrideZ)[(long)row*ldc + col] = val;
          } else {
            C32[(long)row*ldc+col] = resid[(long)row*ldc+col] + val;
          }
        }
      }
    }
  }
}

// ---------------- RoPE + hi/lo split repack ----------------
__global__ void k_ropesplit(const float* __restrict__ QR, const float* __restrict__ KR,
                            const float* __restrict__ cost, const float* __restrict__ sint,
                            u16* __restrict__ QHI, u16* __restrict__ QLO,
                            u16* __restrict__ KHI, u16* __restrict__ KLO){
  int i = blockIdx.x*256+threadIdx.x;
  if(i >= NT_*H_*32) return;
  int d = i&31; int h=(i>>5)%H_; int t = i/(H_*32);
  int s = t & (S_-1); int b = t >> 10;
  float c = cost[s*32+d], sn = sint[s*32+d];
  long qi = (long)t*D_ + h*HD_ + d;
  float q1=QR[qi], q2=QR[qi+32];
  float k1=KR[qi], k2=KR[qi+32];
  long ob = ((long)(b*H_+h)*S_ + s)*HD_ + d;
  float qa=(q1*c - q2*sn)*0.125f, qb2=(q2*c + q1*sn)*0.125f;
  float ka=k1*c - k2*sn,          kb2=k2*c + k1*sn;
  u16 hh;
  hh=f2b(qa);  QHI[ob]=hh;    QLO[ob]   =f2b(qa -b2f(hh));
  hh=f2b(qb2); QHI[ob+32]=hh; QLO[ob+32]=f2b(qb2-b2f(hh));
  hh=f2b(ka);  KHI[ob]=hh;    KLO[ob]   =f2b(ka -b2f(hh));
  hh=f2b(kb2); KHI[ob+32]=hh; KLO[ob+32]=f2b(kb2-b2f(hh));
}

// ---------------- V transpose + hi/lo split: [b][s][576] -> [bh][64][S] --
__global__ __launch_bounds__(256) void k_vsplit(const float* __restrict__ VR,
                       u16* __restrict__ VHI, u16* __restrict__ VLO){
  __shared__ float ls[64][65];
  int s0 = blockIdx.x*64; int bh = blockIdx.y;
  int b = bh/H_, h = bh - b*H_;
  int tid=threadIdx.x;
  #pragma unroll
  for(int i=0;i<16;i++){
    int idx = tid + i*256;
    int si = idx>>6, dj = idx&63;
    ls[si][dj] = VR[((long)(b*S_+s0+si))*D_ + h*HD_ + dj];
  }
  __syncthreads();
  #pragma unroll
  for(int i=0;i<16;i++){
    int idx = tid + i*256;
    int di = idx>>6, sj = idx&63;
    float v = ls[sj][di];
    u16 hh = f2b(v);
    long o = ((long)bh*HD_+di)*S_ + s0+sj;
    VHI[o]=hh; VLO[o]=f2b(v-b2f(hh));
  }
}

// ---------------- split-bf16 MFMA flash attention v3 -------------------
__global__ __launch_bounds__(256) void k_attn_split(
    const u16* __restrict__ QHI, const u16* __restrict__ QLO,
    const u16* __restrict__ KHI, const u16* __restrict__ KLO,
    const u16* __restrict__ VHI, const u16* __restrict__ VLO,
    u16* __restrict__ OHI, u16* __restrict__ OLO){
  __shared__ u16 lds[2][4][64*64];   // [buf][Khi,Klo,Vhi,Vlo][row*64]
  int tid=threadIdx.x, wid=tid>>6, lane=tid&63;
  int bh=blockIdx.x; int b=bh/H_, h=bh-b*H_;
  int jb=blockIdx.y;
  int lq=lane&15, lg=lane>>4;
  int jslot=lane&7, rloc=lane>>3;

  for(int pass=0;pass<2;pass++){
    int tile = pass? (15-jb) : jb;
    int ntile = tile+1;
    int q0 = tile*64 + wid*16;
    long qoff = ((long)bh*S_ + q0+lq)*HD_;
    bf16x8 qh0 = *(const bf16x8*)(QHI+qoff+lg*8);
    bf16x8 qh1 = *(const bf16x8*)(QHI+qoff+32+lg*8);
    bf16x8 ql0 = *(const bf16x8*)(QLO+qoff+lg*8);
    bf16x8 ql1 = *(const bf16x8*)(QLO+qoff+32+lg*8);
    float m=-1e30f, l=0.f;
    f32x4 ot[4]={};
    int q_lane = q0 + lq;

    #define STAGE(bufi, kv0_) do{                                          \
      int _kv0=(kv0_);                                                     \
      _Pragma("unroll")                                                    \
      for(int c=0;c<2;c++){                                                \
        int r = wid*16 + c*8 + rloc;                                       \
        int col = 8*(jslot ^ (r&7));                                       \
        long kg = ((long)bh*S_ + _kv0 + r)*64 + col;                       \
        long vg = ((long)bh*64 + r)*S_ + _kv0 + col;                       \
        int lb = (wid*16 + c*8)*64;                                        \
        gll16(KHI+kg, &lds[bufi][0][lb]);                                  \
        gll16(KLO+kg, &lds[bufi][1][lb]);                                  \
        gll16(VHI+vg, &lds[bufi][2][lb]);                                  \
        gll16(VLO+vg, &lds[bufi][3][lb]);                                  \
      } }while(0)

    STAGE(0, 0);
    __syncthreads();
    for(int t=0;t<ntile;t++){
      if(t+1<ntile) STAGE((t+1)&1, (t+1)*64);
      int bufc = t&1;
      int kv0 = t*64;
      bool last = (t==ntile-1);
      const char* Khs=(const char*)lds[bufc][0];
      const char* Kls=(const char*)lds[bufc][1];
      const char* Vhs=(const char*)lds[bufc][2];
      const char* Vls=(const char*)lds[bufc][3];
      #pragma unroll
      for(int kvh=0;kvh<64;kvh+=32){
        float p[8];
        float tmax=-1e30f;
        #pragma unroll
        for(int sub=0;sub<2;sub++){
          int r = kvh + sub*16 + lq;
          int sw = (r&7)<<4;
          bf16x8 kh0=*(const bf16x8*)(Khs + r*128 + ((lg*16) ^ sw));
          bf16x8 kh1=*(const bf16x8*)(Khs + r*128 + ((64+lg*16) ^ sw));
          bf16x8 kl0=*(const bf16x8*)(Kls + r*128 + ((lg*16) ^ sw));
          bf16x8 kl1=*(const bf16x8*)(Kls + r*128 + ((64+lg*16) ^ sw));
          f32x4 st={0.f,0.f,0.f,0.f};
          st=MFMA16(kh0,qh0,st); st=MFMA16(kh1,qh1,st);
          st=MFMA16(kl0,qh0,st); st=MFMA16(kl1,qh1,st);
          st=MFMA16(kh0,ql0,st); st=MFMA16(kh1,ql1,st);
          #pragma unroll
          for(int r2=0;r2<4;r2++){
            int key = kv0 + kvh + sub*16 + lg*4 + r2;
            float sv = (!last || key <= q_lane)? st[r2] : -1e30f;
            p[sub*4+r2]=sv;
            tmax = fmaxf(tmax, sv);
          }
        }
        tmax = fmaxf(tmax, __shfl_xor(tmax,16,64));
        tmax = fmaxf(tmax, __shfl_xor(tmax,32,64));
        float mn = fmaxf(m, tmax);
        float sc = __expf(m - mn);
        l *= sc;
        #pragma unroll
        for(int t2=0;t2<4;t2++)
          #pragma unroll
          for(int r2=0;r2<4;r2++) ot[t2][r2]*=sc;
        float ps=0.f;
        #pragma unroll
        for(int j=0;j<8;j++){ p[j]=__expf(p[j]-mn); ps+=p[j]; }
        l+=ps; m=mn;
        bf16x8 ph, pl;
        #pragma unroll
        for(int j=0;j<8;j++){
          u16 hb2=f2b(p[j]);
          ph[j]=(short)hb2;
          pl[j]=(short)f2b(p[j]-b2f(hb2));
        }
        #pragma unroll
        for(int t2=0;t2<4;t2++){
          int d = t2*16+lq;
          int swd = (d&7)<<4;
          int b1 = (2*(kvh+4*lg)) ^ swd;
          int b2v = (2*(kvh+16+4*lg)) ^ swd;
          us4 vh0=*(const us4*)(Vhs + d*128 + b1);
          us4 vh1=*(const us4*)(Vhs + d*128 + b2v);
          us4 vl0=*(const us4*)(Vls + d*128 + b1);
          us4 vl1=*(const us4*)(Vls + d*128 + b2v);
          bf16x8 vh, vl;
          #pragma unroll
          for(int j=0;j<4;j++){
            vh[j]=(short)vh0[j]; vh[4+j]=(short)vh1[j];
            vl[j]=(short)vl0[j]; vl[4+j]=(short)vl1[j];
          }
          ot[t2]=MFMA16(vh,ph,ot[t2]);
          ot[t2]=MFMA16(vl,ph,ot[t2]);
          ot[t2]=MFMA16(vh,pl,ot[t2]);
        }
      }
      __syncthreads();
    }
    #undef STAGE
    float l1 = l + __shfl_xor(l,16,64);
    float lt = l1 + __shfl_xor(l1,32,64);
    float inv = 1.f/lt;
    long orow = ((long)b*S_ + q_lane)*D_ + h*HD_;
    #pragma unroll
    for(int t2=0;t2<4;t2++){
      us4 oh4, ol4;
      #pragma unroll
      for(int r2=0;r2<4;r2++){
        float v=ot[t2][r2]*inv;
        u16 hh=f2b(v);
        oh4[r2]=hh; ol4[r2]=f2b(v-b2f(hh));
      }
      *(us4*)(OHI + orow + t2*16 + 4*lg) = oh4;
      *(us4*)(OLO + orow + t2*16 + 4*lg) = ol4;
    }
  }
}

// ---------------- router (fp32, accurate expf; NO atomics) -------------
__global__ __launch_bounds__(256) void k_router(const float* __restrict__ h2f, const float* __restrict__ Wr,
                         const float* __restrict__ rb, int* __restrict__ idx2,
                         float* __restrict__ w2){
  int tid=threadIdx.x, wid=tid>>6, lane=tid&63;
  int t=blockIdx.x*4 + wid;
  float hv[9];
  #pragma unroll
  for(int j=0;j<9;j++) hv[j]=h2f[(long)t*D_+lane+64*j];
  float pr[7];
  #pragma unroll
  for(int e=0;e<7;e++){
    float s=0.f;
    #pragma unroll
    for(int j=0;j<9;j++) s += hv[j]*Wr[e*D_+lane+64*j];
    #pragma unroll
    for(int mm=1;mm<64;mm<<=1) s+=__shfl_xor(s,mm,64);
    pr[e] = 1.f/(1.f+expf(-(s+rb[e])));
  }
  int e0=0; float b0=pr[0];
  #pragma unroll
  for(int e=1;e<7;e++) if(pr[e]>b0){b0=pr[e];e0=e;}
  int e1=-1; float b1=-1e30f;
  #pragma unroll
  for(int e=0;e<7;e++) if(e!=e0 && pr[e]>b1){b1=pr[e];e1=e;}
  if(lane==0){
    float s=b0+b1;
    idx2[2*t]=e0; idx2[2*t+1]=e1;
    w2[2*t]=b0/s; w2[2*t+1]=b1/s;
  }
}

// ---------------- expert histogram (LDS, 7 global atomics/block) -------
__global__ __launch_bounds__(256) void k_count(const int* __restrict__ idx2, int* __restrict__ counts){
  __shared__ int hist[NE_];
  int tid=threadIdx.x;
  if(tid<NE_) hist[tid]=0;
  __syncthreads();
  int i = blockIdx.x*256+tid;
  atomicAdd(&hist[idx2[i]],1);
  __syncthreads();
  if(tid<NE_) atomicAdd(&counts[tid], hist[tid]);
}

__global__ void k_offsets(const int* __restrict__ counts, int* __restrict__ ofs, int* __restrict__ fill){
  if(threadIdx.x==0 && blockIdx.x==0){
    int a=0;
    for(int e=0;e<NE_;e++){ ofs[e]=a; fill[e]=a; a+=counts[e]; }
    ofs[NE_]=a;
  }
}

// ---------------- ballot-scan scatter (1 atomic/expert/block) ----------
__global__ __launch_bounds__(256) void k_scatter2(const int* __restrict__ idx2, const float* __restrict__ w2,
                          int* __restrict__ fill, int* __restrict__ ltok,
                          float* __restrict__ lw, int* __restrict__ ppos){
  __shared__ int wcnt[4][8];
  __shared__ int wpre[4][8];
  __shared__ int base[8];
  int tid=threadIdx.x, wid=tid>>6, lane=tid&63;
  int slot = blockIdx.x*256 + wid*64 + lane;
  int id = idx2[slot];
  unsigned long long ltm = (1ull<<lane)-1ull;
  int myrank=0;
  #pragma unroll
  for(int e=0;e<7;e++){
    unsigned long long mask = __ballot(id==e);
    if(id==e) myrank = __popcll(mask & ltm);
    if(lane==0) wcnt[wid][e] = __popcll(mask);
  }
  __syncthreads();
  if(wid==0 && lane<7){
    int e=lane;
    int s0=wcnt[0][e], s1=wcnt[1][e], s2=wcnt[2][e], s3=wcnt[3][e];
    wpre[0][e]=0; wpre[1][e]=s0; wpre[2][e]=s0+s1; wpre[3][e]=s0+s1+s2;
    base[e] = atomicAdd(&fill[e], s0+s1+s2+s3);
  }
  __syncthreads();
  int pos = base[id] + wpre[wid][id] + myrank;
  ltok[pos] = slot>>1;
  lw[pos] = w2[slot];
  ppos[slot] = pos;
}

// ---------------- token gather: AG[row] = H2B[ltok[row]] ----------------
__global__ void k_gather(const int* __restrict__ ltok, const u16* __restrict__ h2b,
                         u16* __restrict__ ag){
  long i = (long)blockIdx.x*256+threadIdx.x;
  const int CPR = D_*2/16;   // 72 16B-chunks per row
  if(i >= (long)NACT_*CPR) return;
  int row = (int)(i/CPR), c = (int)(i - (long)row*CPR);
  int tok = (row<NPAIR_)? ltok[row] : (row-NPAIR_);
  ((ulonglong2*)ag)[(long)row*CPR + c] = ((const ulonglong2*)(h2b + (long)tok*D_))[c];
}

// ---------------- grouped gate+up+SwiGLU (bf16 MFMA, 128x128) ----------
__global__ __launch_bounds__(256) void k_moe_gu(const u16* __restrict__ ag, const u16* __restrict__ Gb,
                        const u16* __restrict__ Ub, const int* __restrict__ cnt,
                        const int* __restrict__ ofs, u16* __restrict__ act){
  int e = blockIdx.z;
  int nrows = (e<NE_)? cnt[e] : NT_;
  long arow0 = (e<NE_)? (long)ofs[e] : (long)NPAIR_;
  int mt = blockIdx.x;
  if(mt*128 >= nrows) return;
  int f0 = blockIdx.y*128;
  __shared__ u16 As[128*32], Gs[128*32], Us[128*32];
  int tid=threadIdx.x, wid=tid>>6, lane=tid&63;
  int lq=lane&15, lg=lane>>4;
  int wr=wid>>1, wc=wid&1;
  f32x4 ag_[4][4]={}, au_[4][4]={};
  for(int kt=0;kt<18;kt++){
    #pragma unroll
    for(int is=0;is<2;is++){
      int ub = is*4096 + wid*1024;
      int o = ub + lane*16;
      int row = o>>6, cb=o&63;
      int ridx = mt*128+row; if(ridx>nrows-1) ridx=nrows-1;
      gll16(ag + (arow0+ridx)*D_ + kt*32 + (cb>>1), (char*)As+ub);
      long wrow = (long)e*FF_ + f0 + row;
      gll16(Gb + wrow*D_ + kt*32 + (cb>>1), (char*)Gs+ub);
      gll16(Ub + wrow*D_ + kt*32 + (cb>>1), (char*)Us+ub);
    }
    __syncthreads();
    bf16x8 af[4], gf[4], uf[4];
    #pragma unroll
    for(int m=0;m<4;m++) af[m]=*(const bf16x8*)&As[(wr*64+m*16+lq)*32+lg*8];
    #pragma unroll
    for(int n=0;n<4;n++){
      gf[n]=*(const bf16x8*)&Gs[(wc*64+n*16+lq)*32+lg*8];
      uf[n]=*(const bf16x8*)&Us[(wc*64+n*16+lq)*32+lg*8];
    }
    #pragma unroll
    for(int m=0;m<4;m++)
      #pragma unroll
      for(int n=0;n<4;n++){
        ag_[m][n]=MFMA16(af[m],gf[n],ag_[m][n]);
        au_[m][n]=MFMA16(af[m],uf[n],au_[m][n]);
      }
    __syncthreads();
  }
  #pragma unroll
  for(int m=0;m<4;m++){
    #pragma unroll
    for(int n=0;n<4;n++){
      int f = f0 + wc*64+n*16+lq;
      #pragma unroll
      for(int r=0;r<4;r++){
        int rl = wr*64+m*16+lg*4+r;
        int ridx = mt*128+rl;
        if(ridx<nrows){
          float g=ag_[m][n][r], u=au_[m][n][r];
          float sw = g/(1.f+__expf(-g))*u;
          act[(arow0+ridx)*FF_ + f] = f2b(sw);
        }
      }
    }
  }
}

// ---------------- grouped down-proj (bf16 MFMA, 128x128) ---------------
__global__ __launch_bounds__(256) void k_moe_down(const u16* __restrict__ act, const u16* __restrict__ Db,
                          const int* __restrict__ cnt, const int* __restrict__ ofs,
                          const float* __restrict__ lw, u16* __restrict__ pd){
  int e=blockIdx.z;
  int nrows=(e<NE_)?cnt[e]:NT_;
  long arow0=(e<NE_)?(long)ofs[e]:(long)NPAIR_;
  int mt=blockIdx.x;
  if(mt*128>=nrows) return;
  int n0=blockIdx.y*128;
  __shared__ u16 As[128*32], Bs[128*32];
  int tid=threadIdx.x,wid=tid>>6,lane=tid&63;
  int lq=lane&15,lg=lane>>4;
  int wr=wid>>1,wc=wid&1;
  f32x4 acc[4][4]={};
  for(int kt=0;kt<48;kt++){
    #pragma unroll
    for(int is=0;is<2;is++){
      int ub=is*4096+wid*1024;
      int o=ub+lane*16;
      int row=o>>6, cb=o&63;
      int ridx = mt*128+row; if(ridx>nrows-1) ridx=nrows-1;
      gll16(act + (arow0+ridx)*FF_ + kt*32 + (cb>>1), (char*)As+ub);
      int rowb = n0+row; if(rowb>D_-1) rowb=D_-1;
      gll16(Db + ((long)e*D_ + rowb)*FF_ + kt*32 + (cb>>1), (char*)Bs+ub);
    }
    __syncthreads();
    bf16x8 af[4],bf2[4];
    #pragma unroll
    for(int m=0;m<4;m++) af[m]=*(const bf16x8*)&As[(wr*64+m*16+lq)*32+lg*8];
    #pragma unroll
    for(int n=0;n<4;n++) bf2[n]=*(const bf16x8*)&Bs[(wc*64+n*16+lq)*32+lg*8];
    #pragma unroll
    for(int m=0;m<4;m++)
      #pragma unroll
      for(int n=0;n<4;n++)
        acc[m][n]=MFMA16(af[m],bf2[n],acc[m][n]);
    __syncthreads();
  }
  #pragma unroll
  for(int m=0;m<4;m++){
    #pragma unroll
    for(int n=0;n<4;n++){
      int col=n0+wc*64+n*16+lq;
      if(col<D_){
        #pragma unroll
        for(int r=0;r<4;r++){
          int rl=wr*64+m*16+lg*4+r;
          int ridx=mt*128+rl;
          if(ridx<nrows){
            float w=1.f;
            if(e<NE_) w=lw[arow0+ridx];
            pd[(arow0+ridx)*D_ + col]=f2b(w*acc[m][n][r]);
          }
        }
      }
    }
  }
}

// ---------------- final combine ----------------
__global__ void k_final(const float* __restrict__ x2, const u16* __restrict__ pd,
                        const int* __restrict__ ppos, float* __restrict__ out){
  int i=blockIdx.x*256+threadIdx.x;
  int tot = NT_*(D_/4);
  if(i>=tot) return;
  int t = i/(D_/4); int c = (i - t*(D_/4))*4;
  int p0=ppos[2*t], p1=ppos[2*t+1];
  const u16* a=pd+((long)NPAIR_+t)*D_+c;
  const u16* b=pd+(long)p0*D_+c;
  const u16* d=pd+(long)p1*D_+c;
  const float* xr = x2+(long)t*D_+c;
  float* o = out+(long)t*D_+c;
  #pragma unroll
  for(int j=0;j<4;j++) o[j]=xr[j]+b2f(a[j])+b2f(b[j])+b2f(d[j]);
}

extern "C" void kernel_launch(void* const* d_in, const int* in_sizes, int n_in,
                              void* d_out, int out_size, void* d_ws, size_t ws_size,
                              hipStream_t stream){
  const float* x    =(const float*)d_in[0];
  const float* ln1  =(const float*)d_in[1];
  const float* ln2  =(const float*)d_in[2];
  const float* Wqd  =(const float*)d_in[3];
  const float* Wkvd =(const float*)d_in[4];
  const float* Wqu  =(const float*)d_in[5];
  const float* Wku  =(const float*)d_in[6];
  const float* Wvu  =(const float*)d_in[7];
  const float* Wo   =(const float*)d_in[8];
  const float* sg   =(const float*)d_in[9];
  const float* su   =(const float*)d_in[10];
  const float* sd   =(const float*)d_in[11];
  const float* rg   =(const float*)d_in[12];
  const float* ru   =(const float*)d_in[13];
  const float* rd   =(const float*)d_in[14];
  const float* Wr   =(const float*)d_in[15];
  const float* rb   =(const float*)d_in[16];
  float* out=(float*)d_out;

  char* ws=(char*)d_ws;
  size_t off=0;
  auto alloc=[&](size_t bsz){ size_t r=off; off=(off+bsz+255)&~(size_t)255; return r; };
  // fixed region
  u16* GB   =(u16*)(ws+alloc(8L*FF_*D_*2));
  u16* UB   =(u16*)(ws+alloc(8L*FF_*D_*2));
  u16* DB   =(u16*)(ws+alloc(8L*D_*FF_*2));
  float* COS=(float*)(ws+alloc(S_*32*4));
  float* SIN=(float*)(ws+alloc(S_*32*4));
  float* X2 =(float*)(ws+alloc((long)NT_*D_*4));
  float* H2F=(float*)(ws+alloc((long)NT_*D_*4));
  u16* H2B  =(u16*)(ws+alloc((long)NT_*D_*2));
  int* IDX2 =(int*)(ws+alloc(NT_*2*4));
  float* W2 =(float*)(ws+alloc(NT_*2*4));
  int* PPOS =(int*)(ws+alloc(NT_*2*4));
  int* CNT  =(int*)(ws+alloc(64));
  int* OFS  =(int*)(ws+alloc(64));
  int* FILL =(int*)(ws+alloc(64));
  int* LTOK =(int*)(ws+alloc(NPAIR_*4));
  float* LW =(float*)(ws+alloc(NPAIR_*4));
  size_t scr0 = off;
  // phase A (attention)
  const long NQ = (long)B_*H_*S_*HD_;   // 4.72M elems
  u16* H1HI=(u16*)(ws+alloc((long)NT_*D_*2));
  u16* H1LO=(u16*)(ws+alloc((long)NT_*D_*2));
  u16* LATHI=(u16*)(ws+alloc((long)NT_*320*2));
  u16* LATLO=(u16*)(ws+alloc((long)NT_*320*2));
  float* QR =(float*)(ws+alloc((long)NT_*D_*4));
  float* KR =(float*)(ws+alloc((long)NT_*D_*4));
  float* VR =(float*)(ws+alloc((long)NT_*D_*4));
  u16* QHI =(u16*)(ws+alloc(NQ*2));
  u16* QLO =(u16*)(ws+alloc(NQ*2));
  u16* KHI =(u16*)(ws+alloc(NQ*2));
  u16* KLO =(u16*)(ws+alloc(NQ*2));
  u16* WDHI=(u16*)(ws+alloc(288L*D_*2));
  u16* WDLO=(u16*)(ws+alloc(288L*D_*2));
  u16* WUPHI=(u16*)(ws+alloc(3L*D_*160*2));
  u16* WUPLO=(u16*)(ws+alloc(3L*D_*160*2));
  u16* WOHI=(u16*)(ws+alloc((long)D_*D_*2));
  u16* WOLO=(u16*)(ws+alloc((long)D_*D_*2));
  u16* VHI = (u16*)QR;
  u16* VLO = (u16*)QR + NQ;
  u16* OHI = H1HI;
  u16* OLO = H1LO;
  // phase B (MoE) overlaps phase A
  off = scr0;
  u16* ACT =(u16*)(ws+alloc((long)NACT_*FF_*2));
  u16* PD  =(u16*)(ws+alloc((long)NACT_*D_*2));
  u16* AG  =(u16*)(ws+alloc((long)NACT_*D_*2));
  (void)ws_size;

  // MoE weight conversion (plain bf16)
  CvtSegs cs;
  {
    const float* ss[6]={rg,sg,ru,su,rd,sd};
    u16* dd[6]={GB, GB+7L*FF_*D_, UB, UB+7L*FF_*D_, DB, DB+7L*D_*FF_};
    long nn[6]={7L*FF_*D_,(long)FF_*D_,7L*FF_*D_,(long)FF_*D_,7L*D_*FF_,(long)D_*FF_};
    cs.start4[0]=0;
    for(int j=0;j<6;j++){ cs.src[j]=ss[j]; cs.dst[j]=dd[j]; cs.start4[j+1]=cs.start4[j]+(int)(nn[j]/4); }
  }
  k_cvt<<<2048,256,0,stream>>>(cs);
  // attention weight conversion (hi/lo split)
  CvtSegs2 c2;
  {
    const float* ss[3]={Wqd, Wkvd, Wo};
    u16* dh[3]={WDHI, WDHI+144L*D_, WOHI};
    u16* dl[3]={WDLO, WDLO+144L*D_, WOLO};
    long nn[3]={144L*D_, 144L*D_, (long)D_*D_};
    c2.start4[0]=0;
    for(int j=0;j<3;j++){ c2.src[j]=ss[j]; c2.dhi[j]=dh[j]; c2.dlo[j]=dl[j]; c2.start4[j+1]=c2.start4[j]+(int)(nn[j]/4); }
  }
  k_cvt_split<<<512,256,0,stream>>>(c2);
  k_cvt_pad_split<<<(3*D_*160+255)/256,256,0,stream>>>(Wqu,Wku,Wvu,WUPHI,WUPLO);
  k_rope_tab<<<(S_*32+255)/256,256,0,stream>>>(COS,SIN);

  // attention block (split-bf16 MFMA throughout)
  k_rms<<<NT_,64,0,stream>>>(x, ln1, (float*)nullptr, H1HI, H1LO, (u16*)nullptr);
  hipMemsetAsync(LATHI, 0, (size_t)NT_*320*2, stream);
  hipMemsetAsync(LATLO, 0, (size_t)NT_*320*2, stream);
  k_gemm2<0><<<dim3(64,3,1),256,0,stream>>>(H1HI,H1LO,D_,0, WDHI,WDLO,D_,0, 288,18, LATHI,LATLO,320, nullptr,0,nullptr);
  k_gemm2<1><<<dim3(64,5,3),256,0,stream>>>(LATHI,LATLO,320,160, WUPHI,WUPLO,160,(long)D_*160, D_,5, nullptr,nullptr,D_, QR,(long)NT_*D_, nullptr);
  k_ropesplit<<<(NT_*H_*32+255)/256,256,0,stream>>>(QR,KR,COS,SIN,QHI,QLO,KHI,KLO);
  k_vsplit<<<dim3(16,72),256,0,stream>>>(VR,VHI,VLO);
  k_attn_split<<<dim3(72,8),256,0,stream>>>(QHI,QLO,KHI,KLO,VHI,VLO,OHI,OLO);
  k_gemm2<2><<<dim3(64,5,1),256,0,stream>>>(OHI,OLO,D_,0, WOHI,WOLO,D_,0, D_,18, nullptr,nullptr,D_, X2,0, x);

  // MoE block
  k_rms<<<NT_,64,0,stream>>>(X2, ln2, H2F, (u16*)nullptr, (u16*)nullptr, H2B);
  hipMemsetAsync(CNT,0,64,stream);
  k_router<<<NT_/4,256,0,stream>>>(H2F,Wr,rb,IDX2,W2);
  k_count<<<NPAIR_/256,256,0,stream>>>(IDX2,CNT);
  k_offsets<<<1,1,0,stream>>>(CNT,OFS,FILL);
  k_scatter2<<<NPAIR_/256,256,0,stream>>>(IDX2,W2,FILL,LTOK,LW,PPOS);
  {
    long tot = (long)NACT_*(D_*2/16);
    k_gather<<<(int)((tot+255)/256),256,0,stream>>>(LTOK,H2B,AG);
  }
  k_moe_gu<<<dim3(64,12,8),256,0,stream>>>(AG,GB,UB,CNT,OFS,ACT);
  k_moe_down<<<dim3(64,5,8),256,0,stream>>>(ACT,DB,CNT,OFS,LW,PD);
  k_final<<<(NT_*(D_/4)+255)/256,256,0,stream>>>(X2,PD,PPOS,out);
}

// Round 8
// 707.832 us; speedup vs baseline: 4.9267x; 1.1903x over previous
//
#include <hip/hip_runtime.h>
#include <stdint.h>
#include <math.h>

#define B_    8
#define S_    1024
#define D_    576
#define H_    9
#define HD_   64
#define LAT_  144
#define FF_   1536
#define NE_   7
#define NT_   8192
#define NPAIR_ 16384
#define NACT_  24576
#define MAXT_ 200

typedef unsigned short u16;
typedef __attribute__((ext_vector_type(8))) short bf16x8;
typedef __attribute__((ext_vector_type(4))) float f32x4;
typedef __attribute__((ext_vector_type(4))) unsigned short us4;

__device__ __forceinline__ u16 f2b(float f){
  union{float f;uint32_t u;} v; v.f=f;
  uint32_t u=v.u;
  return (u16)((u + 0x7fffu + ((u>>16)&1u))>>16);
}
__device__ __forceinline__ float b2f(u16 h){
  union{uint32_t u;float f;} v; v.u=((uint32_t)h)<<16; return v.f;
}

#define MFMA16(a,b,c) __builtin_amdgcn_mfma_f32_16x16x32_bf16((a),(b),(c),0,0,0)

typedef __attribute__((address_space(1))) const unsigned char g_u8;
typedef __attribute__((address_space(3))) unsigned char s_u8;
__device__ __forceinline__ void gll16(const void* g, void* l){
  __builtin_amdgcn_global_load_lds((g_u8*)g, (s_u8*)l, 16, 0, 0);
}

// ---------------- MoE weight conversion fp32->bf16 ----------------
struct CvtSegs {
  const float* src[6];
  u16* dst[6];
  int start4[7];
};
__global__ void k_cvt(CvtSegs cs){
  int tot = cs.start4[6];
  for(int i = blockIdx.x*blockDim.x + threadIdx.x; i < tot; i += gridDim.x*blockDim.x){
    int s=0;
    #pragma unroll
    for(int j=0;j<6;j++) if(i >= cs.start4[j+1]) s=j+1;
    int loc = i - cs.start4[s];
    float4 v = ((const float4*)cs.src[s])[loc];
    us4 o; o[0]=f2b(v.x); o[1]=f2b(v.y); o[2]=f2b(v.z); o[3]=f2b(v.w);
    ((us4*)cs.dst[s])[loc] = o;
  }
}

// ---------------- attention weight conversion fp32 -> hi/lo bf16 -------
struct CvtSegs2 {
  const float* src[3];
  u16* dhi[3]; u16* dlo[3];
  int start4[4];
};
__global__ void k_cvt_split(CvtSegs2 cs){
  int tot = cs.start4[3];
  for(int i = blockIdx.x*blockDim.x + threadIdx.x; i < tot; i += gridDim.x*blockDim.x){
    int s=0;
    #pragma unroll
    for(int j=0;j<3;j++) if(i >= cs.start4[j+1]) s=j+1;
    int loc = i - cs.start4[s];
    float4 v = ((const float4*)cs.src[s])[loc];
    us4 oh, ol;
    float vv[4]={v.x,v.y,v.z,v.w};
    #pragma unroll
    for(int j=0;j<4;j++){ u16 hh=f2b(vv[j]); oh[j]=hh; ol[j]=f2b(vv[j]-b2f(hh)); }
    ((us4*)cs.dhi[s])[loc]=oh;
    ((us4*)cs.dlo[s])[loc]=ol;
  }
}

// up-proj weights [3][576][144] -> padded [3][576][160] hi/lo
__global__ void k_cvt_pad_split(const float* __restrict__ Wqu, const float* __restrict__ Wku,
                                const float* __restrict__ Wvu,
                                u16* __restrict__ dhi, u16* __restrict__ dlo){
  int i = blockIdx.x*256 + threadIdx.x;
  if(i >= 3*D_*160) return;
  int z = i/(D_*160); int rem = i - z*D_*160;
  int row = rem/160, col = rem - row*160;
  const float* s = (z==0)?Wqu:((z==1)?Wku:Wvu);
  float v = (col<LAT_)? s[row*LAT_+col] : 0.f;
  u16 hh=f2b(v);
  dhi[i]=hh; dlo[i]=f2b(v-b2f(hh));
}

// ---------------- RoPE tables ----------------
__global__ void k_rope_tab(float* __restrict__ cost, float* __restrict__ sint){
  int i = blockIdx.x*256+threadIdx.x; if(i>=S_*32) return;
  int s=i>>5, d=i&31;
  float pw = (float)pow(10000.0, (double)d/32.0);
  float inv = 1.0f/pw;
  float ang = (float)s*inv;
  cost[i]=cosf(ang); sint[i]=sinf(ang);
}

// ---------------- fp32 rmsnorm, multi-format output ----------------
__global__ __launch_bounds__(64) void k_rms(const float* __restrict__ x, const float* __restrict__ w,
                      u16* __restrict__ hhi, u16* __restrict__ hlo){
  int t = blockIdx.x; int lane = threadIdx.x;
  const float* xr = x + (size_t)t*D_;
  float v[9]; float ss=0.f;
  #pragma unroll
  for(int j=0;j<9;j++){ v[j]=xr[lane+64*j]; ss += v[j]*v[j]; }
  #pragma unroll
  for(int m=1;m<64;m<<=1) ss += __shfl_xor(ss,m,64);
  float sc = 1.0f/sqrtf(ss/(float)D_ + 1e-5f);
  #pragma unroll
  for(int j=0;j<9;j++){
    float y = v[j]*sc*w[lane+64*j];
    size_t o=(size_t)t*D_+lane+64*j;
    u16 hh=f2b(y); hhi[o]=hh; hlo[o]=f2b(y-b2f(hh));
  }
}

// ---------------- fused rmsnorm2 + router (fp32 exact) -----------------
__global__ __launch_bounds__(256) void k_rms_router(const float* __restrict__ x2, const float* __restrict__ w,
                        const float* __restrict__ Wr, const float* __restrict__ rb,
                        u16* __restrict__ hb, int* __restrict__ idx2, float* __restrict__ w2){
  int wid=threadIdx.x>>6, lane=threadIdx.x&63;
  int t = blockIdx.x*4 + wid;
  const float* xr = x2 + (size_t)t*D_;
  float v[9]; float ss=0.f;
  #pragma unroll
  for(int j=0;j<9;j++){ v[j]=xr[lane+64*j]; ss += v[j]*v[j]; }
  #pragma unroll
  for(int m=1;m<64;m<<=1) ss += __shfl_xor(ss,m,64);
  float sc = 1.0f/sqrtf(ss/(float)D_ + 1e-5f);
  float hv[9];
  #pragma unroll
  for(int j=0;j<9;j++){
    float y = v[j]*sc*w[lane+64*j];
    hv[j]=y;
    hb[(size_t)t*D_+lane+64*j]=f2b(y);
  }
  float pr[7];
  #pragma unroll
  for(int e=0;e<7;e++){
    float s=0.f;
    #pragma unroll
    for(int j=0;j<9;j++) s += hv[j]*Wr[e*D_+lane+64*j];
    #pragma unroll
    for(int mm=1;mm<64;mm<<=1) s+=__shfl_xor(s,mm,64);
    pr[e] = 1.f/(1.f+expf(-(s+rb[e])));
  }
  int e0=0; float b0=pr[0];
  #pragma unroll
  for(int e=1;e<7;e++) if(pr[e]>b0){b0=pr[e];e0=e;}
  int e1=-1; float b1=-1e30f;
  #pragma unroll
  for(int e=0;e<7;e++) if(e!=e0 && pr[e]>b1){b1=pr[e];e1=e;}
  if(lane==0){
    float s=b0+b1;
    idx2[2*t]=e0; idx2[2*t+1]=e1;
    w2[2*t]=b0/s; w2[2*t+1]=b1/s;
  }
}

// ---------------- split-bf16 128x128 MFMA GEMM (swizzled LDS) ----------
template<int EPI>
__global__ __launch_bounds__(256) void k_gemm2(
    const u16* __restrict__ Ahi, const u16* __restrict__ Alo, int lda, int aofs_z,
    const u16* __restrict__ Bhi, const u16* __restrict__ Blo, int ldb, long bStrideZ,
    int N, int ksteps,
    u16* __restrict__ Chi, u16* __restrict__ Clo, int ldc,
    float* __restrict__ C32, long cStrideZ, const float* __restrict__ resid)
{
  __shared__ u16 Ahs[128*32], Als[128*32], Bhs[128*32], Bls[128*32];
  int tid=threadIdx.x, wid=tid>>6, lane=tid&63;
  int m0=blockIdx.x*128, n0=blockIdx.y*128, z=blockIdx.z;
  const u16* Abh = Ahi + ((z>0)?aofs_z:0);
  const u16* Abl = Alo + ((z>0)?aofs_z:0);
  const u16* Bbh = Bhi + (long)z*bStrideZ;
  const u16* Bbl = Blo + (long)z*bStrideZ;
  int lq=lane&15, lg=lane>>4;
  int wr=wid>>1, wc=wid&1;
  f32x4 acc[4][4]={};
  for(int kt=0;kt<ksteps;kt++){
    #pragma unroll
    for(int is=0;is<2;is++){
      int ub = is*4096 + wid*1024;
      int o = ub + lane*16;
      int row = o>>6, p=(o>>4)&3;
      int sc8 = ((p ^ ((row>>1)&3)))*8;
      long aoff = (long)(m0+row)*lda + kt*32 + sc8;
      gll16(Abh+aoff, (char*)Ahs+ub);
      gll16(Abl+aoff, (char*)Als+ub);
      int rowb = n0+row; rowb = rowb<N?rowb:(N-1);
      long boff = (long)rowb*ldb + kt*32 + sc8;
      gll16(Bbh+boff, (char*)Bhs+ub);
      gll16(Bbl+boff, (char*)Bls+ub);
    }
    __syncthreads();
    bf16x8 ah[4], al[4], bh[4], bl[4];
    #pragma unroll
    for(int m=0;m<4;m++){
      int arow=wr*64+m*16+lq;
      int co = arow*32 + ((lg ^ ((arow>>1)&3)))*8;
      ah[m]=*(const bf16x8*)&Ahs[co];
      al[m]=*(const bf16x8*)&Als[co];
    }
    #pragma unroll
    for(int n=0;n<4;n++){
      int brow=wc*64+n*16+lq;
      int co = brow*32 + ((lg ^ ((brow>>1)&3)))*8;
      bh[n]=*(const bf16x8*)&Bhs[co];
      bl[n]=*(const bf16x8*)&Bls[co];
    }
    #pragma unroll
    for(int m=0;m<4;m++)
      #pragma unroll
      for(int n=0;n<4;n++){
        acc[m][n]=MFMA16(ah[m],bh[n],acc[m][n]);
        acc[m][n]=MFMA16(ah[m],bl[n],acc[m][n]);
        acc[m][n]=MFMA16(al[m],bh[n],acc[m][n]);
      }
    __syncthreads();
  }
  #pragma unroll
  for(int m=0;m<4;m++){
    #pragma unroll
    for(int n=0;n<4;n++){
      int col = n0 + wc*64 + n*16 + lq;
      if(col<N){
        #pragma unroll
        for(int r=0;r<4;r++){
          int row = m0 + wr*64 + m*16 + lg*4 + r;
          float val = acc[m][n][r];
          if(EPI==0){
            int dc = (col<144)? col : col+16;
            u16 hh=f2b(val);
            Chi[(long)row*ldc + dc] = hh;
            Clo[(long)row*ldc + dc] = f2b(val-b2f(hh));
          } else if(EPI==1){
            (C32 + (long)z*cStrideZ)[(long)row*ldc + col] = val;
          } else {
            C32[(long)row*ldc+col] = resid[(long)row*ldc+col] + val;
          }
        }
      }
    }
  }
}

// ---------------- RoPE + hi/lo split repack ----------------
__global__ void k_ropesplit(const float* __restrict__ QR, const float* __restrict__ KR,
                            const float* __restrict__ cost, const float* __restrict__ sint,
                            u16* __restrict__ QHI, u16* __restrict__ QLO,
                            u16* __restrict__ KHI, u16* __restrict__ KLO){
  int i = blockIdx.x*256+threadIdx.x;
  if(i >= NT_*H_*32) return;
  int d = i&31; int h=(i>>5)%H_; int t = i/(H_*32);
  int s = t & (S_-1); int b = t >> 10;
  float c = cost[s*32+d], sn = sint[s*32+d];
  long qi = (long)t*D_ + h*HD_ + d;
  float q1=QR[qi], q2=QR[qi+32];
  float k1=KR[qi], k2=KR[qi+32];
  long ob = ((long)(b*H_+h)*S_ + s)*HD_ + d;
  float qa=(q1*c - q2*sn)*0.125f, qb2=(q2*c + q1*sn)*0.125f;
  float ka=k1*c - k2*sn,          kb2=k2*c + k1*sn;
  u16 hh;
  hh=f2b(qa);  QHI[ob]=hh;    QLO[ob]   =f2b(qa -b2f(hh));
  hh=f2b(qb2); QHI[ob+32]=hh; QLO[ob+32]=f2b(qb2-b2f(hh));
  hh=f2b(ka);  KHI[ob]=hh;    KLO[ob]   =f2b(ka -b2f(hh));
  hh=f2b(kb2); KHI[ob+32]=hh; KLO[ob+32]=f2b(kb2-b2f(hh));
}

// ---------------- V transpose + hi/lo split: [b][s][576] -> [bh][64][S] --
__global__ __launch_bounds__(256) void k_vsplit(const float* __restrict__ VR,
                       u16* __restrict__ VHI, u16* __restrict__ VLO){
  __shared__ float ls[64][65];
  int s0 = blockIdx.x*64; int bh = blockIdx.y;
  int b = bh/H_, h = bh - b*H_;
  int tid=threadIdx.x;
  #pragma unroll
  for(int i=0;i<16;i++){
    int idx = tid + i*256;
    int si = idx>>6, dj = idx&63;
    ls[si][dj] = VR[((long)(b*S_+s0+si))*D_ + h*HD_ + dj];
  }
  __syncthreads();
  #pragma unroll
  for(int i=0;i<16;i++){
    int idx = tid + i*256;
    int di = idx>>6, sj = idx&63;
    float v = ls[sj][di];
    u16 hh = f2b(v);
    long o = ((long)bh*HD_+di)*S_ + s0+sj;
    VHI[o]=hh; VLO[o]=f2b(v-b2f(hh));
  }
}

// ---------------- split-bf16 MFMA flash attention v3 -------------------
__global__ __launch_bounds__(256) void k_attn_split(
    const u16* __restrict__ QHI, const u16* __restrict__ QLO,
    const u16* __restrict__ KHI, const u16* __restrict__ KLO,
    const u16* __restrict__ VHI, const u16* __restrict__ VLO,
    u16* __restrict__ OHI, u16* __restrict__ OLO){
  __shared__ u16 lds[2][4][64*64];   // [buf][Khi,Klo,Vhi,Vlo][row*64]
  int tid=threadIdx.x, wid=tid>>6, lane=tid&63;
  int bh=blockIdx.x; int b=bh/H_, h=bh-b*H_;
  int jb=blockIdx.y;
  int lq=lane&15, lg=lane>>4;
  int jslot=lane&7, rloc=lane>>3;

  for(int pass=0;pass<2;pass++){
    int tile = pass? (15-jb) : jb;
    int ntile = tile+1;
    int q0 = tile*64 + wid*16;
    long qoff = ((long)bh*S_ + q0+lq)*HD_;
    bf16x8 qh0 = *(const bf16x8*)(QHI+qoff+lg*8);
    bf16x8 qh1 = *(const bf16x8*)(QHI+qoff+32+lg*8);
    bf16x8 ql0 = *(const bf16x8*)(QLO+qoff+lg*8);
    bf16x8 ql1 = *(const bf16x8*)(QLO+qoff+32+lg*8);
    float m=-1e30f, l=0.f;
    f32x4 ot[4]={};
    int q_lane = q0 + lq;

    #define STAGE(bufi, kv0_) do{                                          \
      int _kv0=(kv0_);                                                     \
      _Pragma("unroll")                                                    \
      for(int c=0;c<2;c++){                                                \
        int r = wid*16 + c*8 + rloc;                                       \
        int col = 8*(jslot ^ (r&7));                                       \
        long kg = ((long)bh*S_ + _kv0 + r)*64 + col;                       \
        long vg = ((long)bh*64 + r)*S_ + _kv0 + col;                       \
        int lb = (wid*16 + c*8)*64;                                        \
        gll16(KHI+kg, &lds[bufi][0][lb]);                                  \
        gll16(KLO+kg, &lds[bufi][1][lb]);                                  \
        gll16(VHI+vg, &lds[bufi][2][lb]);                                  \
        gll16(VLO+vg, &lds[bufi][3][lb]);                                  \
      } }while(0)

    STAGE(0, 0);
    __syncthreads();
    for(int t=0;t<ntile;t++){
      if(t+1<ntile) STAGE((t+1)&1, (t+1)*64);
      int bufc = t&1;
      int kv0 = t*64;
      bool last = (t==ntile-1);
      const char* Khs=(const char*)lds[bufc][0];
      const char* Kls=(const char*)lds[bufc][1];
      const char* Vhs=(const char*)lds[bufc][2];
      const char* Vls=(const char*)lds[bufc][3];
      #pragma unroll
      for(int kvh=0;kvh<64;kvh+=32){
        float p[8];
        float tmax=-1e30f;
        #pragma unroll
        for(int sub=0;sub<2;sub++){
          int r = kvh + sub*16 + lq;
          int sw = (r&7)<<4;
          bf16x8 kh0=*(const bf16x8*)(Khs + r*128 + ((lg*16) ^ sw));
          bf16x8 kh1=*(const bf16x8*)(Khs + r*128 + ((64+lg*16) ^ sw));
          bf16x8 kl0=*(const bf16x8*)(Kls + r*128 + ((lg*16) ^ sw));
          bf16x8 kl1=*(const bf16x8*)(Kls + r*128 + ((64+lg*16) ^ sw));
          f32x4 st={0.f,0.f,0.f,0.f};
          st=MFMA16(kh0,qh0,st); st=MFMA16(kh1,qh1,st);
          st=MFMA16(kl0,qh0,st); st=MFMA16(kl1,qh1,st);
          st=MFMA16(kh0,ql0,st); st=MFMA16(kh1,ql1,st);
          #pragma unroll
          for(int r2=0;r2<4;r2++){
            int key = kv0 + kvh + sub*16 + lg*4 + r2;
            float sv = (!last || key <= q_lane)? st[r2] : -1e30f;
            p[sub*4+r2]=sv;
            tmax = fmaxf(tmax, sv);
          }
        }
        tmax = fmaxf(tmax, __shfl_xor(tmax,16,64));
        tmax = fmaxf(tmax, __shfl_xor(tmax,32,64));
        float mn = fmaxf(m, tmax);
        float sc = __expf(m - mn);
        l *= sc;
        #pragma unroll
        for(int t2=0;t2<4;t2++)
          #pragma unroll
          for(int r2=0;r2<4;r2++) ot[t2][r2]*=sc;
        float ps=0.f;
        #pragma unroll
        for(int j=0;j<8;j++){ p[j]=__expf(p[j]-mn); ps+=p[j]; }
        l+=ps; m=mn;
        bf16x8 ph, pl;
        #pragma unroll
        for(int j=0;j<8;j++){
          u16 hb2=f2b(p[j]);
          ph[j]=(short)hb2;
          pl[j]=(short)f2b(p[j]-b2f(hb2));
        }
        #pragma unroll
        for(int t2=0;t2<4;t2++){
          int d = t2*16+lq;
          int swd = (d&7)<<4;
          int b1 = (2*(kvh+4*lg)) ^ swd;
          int b2v = (2*(kvh+16+4*lg)) ^ swd;
          us4 vh0=*(const us4*)(Vhs + d*128 + b1);
          us4 vh1=*(const us4*)(Vhs + d*128 + b2v);
          us4 vl0=*(const us4*)(Vls + d*128 + b1);
          us4 vl1=*(const us4*)(Vls + d*128 + b2v);
          bf16x8 vh, vl;
          #pragma unroll
          for(int j=0;j<4;j++){
            vh[j]=(short)vh0[j]; vh[4+j]=(short)vh1[j];
            vl[j]=(short)vl0[j]; vl[4+j]=(short)vl1[j];
          }
          ot[t2]=MFMA16(vh,ph,ot[t2]);
          ot[t2]=MFMA16(vl,ph,ot[t2]);
          ot[t2]=MFMA16(vh,pl,ot[t2]);
        }
      }
      __syncthreads();
    }
    #undef STAGE
    float l1 = l + __shfl_xor(l,16,64);
    float lt = l1 + __shfl_xor(l1,32,64);
    float inv = 1.f/lt;
    long orow = ((long)b*S_ + q_lane)*D_ + h*HD_;
    #pragma unroll
    for(int t2=0;t2<4;t2++){
      us4 oh4, ol4;
      #pragma unroll
      for(int r2=0;r2<4;r2++){
        float v=ot[t2][r2]*inv;
        u16 hh=f2b(v);
        oh4[r2]=hh; ol4[r2]=f2b(v-b2f(hh));
      }
      *(us4*)(OHI + orow + t2*16 + 4*lg) = oh4;
      *(us4*)(OLO + orow + t2*16 + 4*lg) = ol4;
    }
  }
}

// ---------------- expert histogram (LDS, 7 global atomics/block) -------
__global__ __launch_bounds__(256) void k_count(const int* __restrict__ idx2, int* __restrict__ counts){
  __shared__ int hist[NE_];
  int tid=threadIdx.x;
  if(tid<NE_) hist[tid]=0;
  __syncthreads();
  int i = blockIdx.x*256+tid;
  atomicAdd(&hist[idx2[i]],1);
  __syncthreads();
  if(tid<NE_) atomicAdd(&counts[tid], hist[tid]);
}

// offsets + flattened tile table (ts[0..7]=tile start per group, ts[8]=total)
__global__ void k_offsets(const int* __restrict__ counts, int* __restrict__ ofs,
                          int* __restrict__ fill, int* __restrict__ ts){
  if(threadIdx.x==0 && blockIdx.x==0){
    int a=0;
    for(int e=0;e<NE_;e++){ ofs[e]=a; fill[e]=a; a+=counts[e]; }
    ofs[NE_]=a;
    int t=0;
    for(int e=0;e<NE_;e++){ ts[e]=t; t += (counts[e]+127)>>7; }
    ts[NE_]=t; t+=64;          // shared expert: 64 m-tiles
    ts[NE_+1]=t;
  }
}

// ---------------- ballot-scan scatter (1 atomic/expert/block) ----------
__global__ __launch_bounds__(256) void k_scatter2(const int* __restrict__ idx2, const float* __restrict__ w2,
                          int* __restrict__ fill, int* __restrict__ ltok,
                          float* __restrict__ lw, int* __restrict__ ppos){
  __shared__ int wcnt[4][8];
  __shared__ int wpre[4][8];
  __shared__ int base[8];
  int tid=threadIdx.x, wid=tid>>6, lane=tid&63;
  int slot = blockIdx.x*256 + wid*64 + lane;
  int id = idx2[slot];
  unsigned long long ltm = (1ull<<lane)-1ull;
  int myrank=0;
  #pragma unroll
  for(int e=0;e<7;e++){
    unsigned long long mask = __ballot(id==e);
    if(id==e) myrank = __popcll(mask & ltm);
    if(lane==0) wcnt[wid][e] = __popcll(mask);
  }
  __syncthreads();
  if(wid==0 && lane<7){
    int e=lane;
    int s0=wcnt[0][e], s1=wcnt[1][e], s2=wcnt[2][e], s3=wcnt[3][e];
    wpre[0][e]=0; wpre[1][e]=s0; wpre[2][e]=s0+s1; wpre[3][e]=s0+s1+s2;
    base[e] = atomicAdd(&fill[e], s0+s1+s2+s3);
  }
  __syncthreads();
  int pos = base[id] + wpre[wid][id] + myrank;
  ltok[pos] = slot>>1;
  lw[pos] = w2[slot];
  ppos[slot] = pos;
}

// ---------------- grouped gate+up+SwiGLU (fused gather, swizzled) ------
__global__ __launch_bounds__(256) void k_moe_gu(const u16* __restrict__ h2b, const u16* __restrict__ Gb,
                        const u16* __restrict__ Ub, const int* __restrict__ cnt,
                        const int* __restrict__ ofs, const int* __restrict__ ts,
                        const int* __restrict__ ltok, u16* __restrict__ act){
  int tsv[9];
  #pragma unroll
  for(int i=0;i<9;i++) tsv[i]=ts[i];
  int xt = blockIdx.x;
  if(xt >= tsv[8]) return;
  int e=0;
  #pragma unroll
  for(int i=1;i<8;i++) if(xt >= tsv[i]) e=i;
  int mt = xt - tsv[e];
  int nrows = (e<NE_)? cnt[e] : NT_;
  int base  = (e<NE_)? ofs[e] : 0;
  long arow0 = (e<NE_)? (long)base : (long)NPAIR_;
  int f0 = blockIdx.y*128;
  __shared__ u16 As[128*32], Gs[128*32], Us[128*32];
  int tid=threadIdx.x, wid=tid>>6, lane=tid&63;
  int lq=lane&15, lg=lane>>4;
  int wr=wid>>1, wc=wid&1;
  // per-thread staging rows (fixed across K) + swizzled source chunk
  int r0 = wid*16 + (lane>>2);
  int r1 = 64 + r0;
  int sc8 = ((lane&3) ^ ((r0>>1)&3))*8;      // same for r1 (r1=r0+64)
  int ri0 = mt*128+r0; if(ri0>nrows-1) ri0=nrows-1;
  int ri1 = mt*128+r1; if(ri1>nrows-1) ri1=nrows-1;
  long tok0 = (e<NE_)? (long)ltok[base+ri0] : (long)ri0;
  long tok1 = (e<NE_)? (long)ltok[base+ri1] : (long)ri1;
  const u16* a0 = h2b + tok0*D_ + sc8;
  const u16* a1 = h2b + tok1*D_ + sc8;
  const u16* g0 = Gb + ((long)e*FF_ + f0 + r0)*D_ + sc8;
  const u16* g1 = Gb + ((long)e*FF_ + f0 + r1)*D_ + sc8;
  const u16* u0 = Ub + ((long)e*FF_ + f0 + r0)*D_ + sc8;
  const u16* u1 = Ub + ((long)e*FF_ + f0 + r1)*D_ + sc8;
  int lb0 = wid*1024 + lane*16 - (lane&3)*16 + (lane&3)*16; // = wid*1024+lane*16
  f32x4 ag_[4][4]={}, au_[4][4]={};
  for(int kt=0;kt<18;kt++){
    int ko = kt*32;
    gll16(a0+ko, (char*)As + (wid*1024 + lane*16));
    gll16(a1+ko, (char*)As + (4096 + wid*1024 + lane*16));
    gll16(g0+ko, (char*)Gs + (wid*1024 + lane*16));
    gll16(g1+ko, (char*)Gs + (4096 + wid*1024 + lane*16));
    gll16(u0+ko, (char*)Us + (wid*1024 + lane*16));
    gll16(u1+ko, (char*)Us + (4096 + wid*1024 + lane*16));
    __syncthreads();
    bf16x8 af[4], gf[4], uf[4];
    #pragma unroll
    for(int m=0;m<4;m++){
      int arow=wr*64+m*16+lq;
      af[m]=*(const bf16x8*)&As[arow*32 + ((lg ^ ((arow>>1)&3)))*8];
    }
    #pragma unroll
    for(int n=0;n<4;n++){
      int grow=wc*64+n*16+lq;
      int co = grow*32 + ((lg ^ ((grow>>1)&3)))*8;
      gf[n]=*(const bf16x8*)&Gs[co];
      uf[n]=*(const bf16x8*)&Us[co];
    }
    #pragma unroll
    for(int m=0;m<4;m++)
      #pragma unroll
      for(int n=0;n<4;n++){
        ag_[m][n]=MFMA16(af[m],gf[n],ag_[m][n]);
        au_[m][n]=MFMA16(af[m],uf[n],au_[m][n]);
      }
    __syncthreads();
  }
  (void)lb0;
  #pragma unroll
  for(int m=0;m<4;m++){
    #pragma unroll
    for(int n=0;n<4;n++){
      int f = f0 + wc*64+n*16+lq;
      #pragma unroll
      for(int r=0;r<4;r++){
        int rl = wr*64+m*16+lg*4+r;
        int ridx = mt*128+rl;
        if(ridx<nrows){
          float g=ag_[m][n][r], u=au_[m][n][r];
          float sw = g/(1.f+__expf(-g))*u;
          act[(arow0+ridx)*FF_ + f] = f2b(sw);
        }
      }
    }
  }
}

// ---------------- grouped down-proj (flattened, swizzled) --------------
__global__ __launch_bounds__(256) void k_moe_down(const u16* __restrict__ act, const u16* __restrict__ Db,
                          const int* __restrict__ cnt, const int* __restrict__ ofs,
                          const int* __restrict__ ts, const float* __restrict__ lw,
                          u16* __restrict__ pd){
  int tsv[9];
  #pragma unroll
  for(int i=0;i<9;i++) tsv[i]=ts[i];
  int xt = blockIdx.x;
  if(xt >= tsv[8]) return;
  int e=0;
  #pragma unroll
  for(int i=1;i<8;i++) if(xt >= tsv[i]) e=i;
  int mt = xt - tsv[e];
  int nrows=(e<NE_)?cnt[e]:NT_;
  long arow0=(e<NE_)?(long)ofs[e]:(long)NPAIR_;
  int n0=blockIdx.y*128;
  __shared__ u16 As[128*32], Bs[128*32];
  int tid=threadIdx.x,wid=tid>>6,lane=tid&63;
  int lq=lane&15,lg=lane>>4;
  int wr=wid>>1,wc=wid&1;
  int r0 = wid*16 + (lane>>2);
  int r1 = 64 + r0;
  int sc8 = ((lane&3) ^ ((r0>>1)&3))*8;
  int ri0 = mt*128+r0; if(ri0>nrows-1) ri0=nrows-1;
  int ri1 = mt*128+r1; if(ri1>nrows-1) ri1=nrows-1;
  const u16* a0 = act + (arow0+ri0)*FF_ + sc8;
  const u16* a1 = act + (arow0+ri1)*FF_ + sc8;
  int rb0 = n0+r0; if(rb0>D_-1) rb0=D_-1;
  int rb1 = n0+r1; if(rb1>D_-1) rb1=D_-1;
  const u16* b0p = Db + ((long)e*D_ + rb0)*FF_ + sc8;
  const u16* b1p = Db + ((long)e*D_ + rb1)*FF_ + sc8;
  f32x4 acc[4][4]={};
  for(int kt=0;kt<48;kt++){
    int ko = kt*32;
    gll16(a0+ko, (char*)As + (wid*1024 + lane*16));
    gll16(a1+ko, (char*)As + (4096 + wid*1024 + lane*16));
    gll16(b0p+ko, (char*)Bs + (wid*1024 + lane*16));
    gll16(b1p+ko, (char*)Bs + (4096 + wid*1024 + lane*16));
    __syncthreads();
    bf16x8 af[4],bf2[4];
    #pragma unroll
    for(int m=0;m<4;m++){
      int arow=wr*64+m*16+lq;
      af[m]=*(const bf16x8*)&As[arow*32 + ((lg ^ ((arow>>1)&3)))*8];
    }
    #pragma unroll
    for(int n=0;n<4;n++){
      int brow=wc*64+n*16+lq;
      bf2[n]=*(const bf16x8*)&Bs[brow*32 + ((lg ^ ((brow>>1)&3)))*8];
    }
    #pragma unroll
    for(int m=0;m<4;m++)
      #pragma unroll
      for(int n=0;n<4;n++)
        acc[m][n]=MFMA16(af[m],bf2[n],acc[m][n]);
    __syncthreads();
  }
  #pragma unroll
  for(int m=0;m<4;m++){
    #pragma unroll
    for(int n=0;n<4;n++){
      int col=n0+wc*64+n*16+lq;
      if(col<D_){
        #pragma unroll
        for(int r=0;r<4;r++){
          int rl=wr*64+m*16+lg*4+r;
          int ridx=mt*128+rl;
          if(ridx<nrows){
            float w=1.f;
            if(e<NE_) w=lw[arow0+ridx];
            pd[(arow0+ridx)*D_ + col]=f2b(w*acc[m][n][r]);
          }
        }
      }
    }
  }
}

// ---------------- final combine ----------------
__global__ void k_final(const float* __restrict__ x2, const u16* __restrict__ pd,
                        const int* __restrict__ ppos, float* __restrict__ out){
  int i=blockIdx.x*256+threadIdx.x;
  int tot = NT_*(D_/4);
  if(i>=tot) return;
  int t = i/(D_/4); int c = (i - t*(D_/4))*4;
  int p0=ppos[2*t], p1=ppos[2*t+1];
  const u16* a=pd+((long)NPAIR_+t)*D_+c;
  const u16* b=pd+(long)p0*D_+c;
  const u16* d=pd+(long)p1*D_+c;
  const float* xr = x2+(long)t*D_+c;
  float* o = out+(long)t*D_+c;
  #pragma unroll
  for(int j=0;j<4;j++) o[j]=xr[j]+b2f(a[j])+b2f(b[j])+b2f(d[j]);
}

extern "C" void kernel_launch(void* const* d_in, const int* in_sizes, int n_in,
                              void* d_out, int out_size, void* d_ws, size_t ws_size,
                              hipStream_t stream){
  const float* x    =(const float*)d_in[0];
  const float* ln1  =(const float*)d_in[1];
  const float* ln2  =(const float*)d_in[2];
  const float* Wqd  =(const float*)d_in[3];
  const float* Wkvd =(const float*)d_in[4];
  const float* Wqu  =(const float*)d_in[5];
  const float* Wku  =(const float*)d_in[6];
  const float* Wvu  =(const float*)d_in[7];
  const float* Wo   =(const float*)d_in[8];
  const float* sg   =(const float*)d_in[9];
  const float* su   =(const float*)d_in[10];
  const float* sd   =(const float*)d_in[11];
  const float* rg   =(const float*)d_in[12];
  const float* ru   =(const float*)d_in[13];
  const float* rd   =(const float*)d_in[14];
  const float* Wr   =(const float*)d_in[15];
  const float* rb   =(const float*)d_in[16];
  float* out=(float*)d_out;

  char* ws=(char*)d_ws;
  size_t off=0;
  auto alloc=[&](size_t bsz){ size_t r=off; off=(off+bsz+255)&~(size_t)255; return r; };
  // fixed region
  u16* GB   =(u16*)(ws+alloc(8L*FF_*D_*2));
  u16* UB   =(u16*)(ws+alloc(8L*FF_*D_*2));
  u16* DB   =(u16*)(ws+alloc(8L*D_*FF_*2));
  float* COS=(float*)(ws+alloc(S_*32*4));
  float* SIN=(float*)(ws+alloc(S_*32*4));
  float* X2 =(float*)(ws+alloc((long)NT_*D_*4));
  u16* H2B  =(u16*)(ws+alloc((long)NT_*D_*2));
  int* IDX2 =(int*)(ws+alloc(NT_*2*4));
  float* W2 =(float*)(ws+alloc(NT_*2*4));
  int* PPOS =(int*)(ws+alloc(NT_*2*4));
  int* CNT  =(int*)(ws+alloc(64));
  int* OFS  =(int*)(ws+alloc(64));
  int* FILL =(int*)(ws+alloc(64));
  int* TS   =(int*)(ws+alloc(64));
  int* LTOK =(int*)(ws+alloc(NPAIR_*4));
  float* LW =(float*)(ws+alloc(NPAIR_*4));
  size_t scr0 = off;
  // phase A (attention)
  const long NQ = (long)B_*H_*S_*HD_;   // 4.72M elems
  u16* H1HI=(u16*)(ws+alloc((long)NT_*D_*2));
  u16* H1LO=(u16*)(ws+alloc((long)NT_*D_*2));
  u16* LATHI=(u16*)(ws+alloc((long)NT_*320*2));
  u16* LATLO=(u16*)(ws+alloc((long)NT_*320*2));
  float* QR =(float*)(ws+alloc((long)NT_*D_*4));
  float* KR =(float*)(ws+alloc((long)NT_*D_*4));
  float* VR =(float*)(ws+alloc((long)NT_*D_*4));
  u16* QHI =(u16*)(ws+alloc(NQ*2));
  u16* QLO =(u16*)(ws+alloc(NQ*2));
  u16* KHI =(u16*)(ws+alloc(NQ*2));
  u16* KLO =(u16*)(ws+alloc(NQ*2));
  u16* WDHI=(u16*)(ws+alloc(288L*D_*2));
  u16* WDLO=(u16*)(ws+alloc(288L*D_*2));
  u16* WUPHI=(u16*)(ws+alloc(3L*D_*160*2));
  u16* WUPLO=(u16*)(ws+alloc(3L*D_*160*2));
  u16* WOHI=(u16*)(ws+alloc((long)D_*D_*2));
  u16* WOLO=(u16*)(ws+alloc((long)D_*D_*2));
  u16* VHI = (u16*)QR;
  u16* VLO = (u16*)QR + NQ;
  u16* OHI = H1HI;
  u16* OLO = H1LO;
  // phase B (MoE) overlaps phase A
  off = scr0;
  u16* ACT =(u16*)(ws+alloc((long)NACT_*FF_*2));
  u16* PD  =(u16*)(ws+alloc((long)NACT_*D_*2));
  (void)ws_size;

  // MoE weight conversion (plain bf16)
  CvtSegs cs;
  {
    const float* ss[6]={rg,sg,ru,su,rd,sd};
    u16* dd[6]={GB, GB+7L*FF_*D_, UB, UB+7L*FF_*D_, DB, DB+7L*D_*FF_};
    long nn[6]={7L*FF_*D_,(long)FF_*D_,7L*FF_*D_,(long)FF_*D_,7L*D_*FF_,(long)D_*FF_};
    cs.start4[0]=0;
    for(int j=0;j<6;j++){ cs.src[j]=ss[j]; cs.dst[j]=dd[j]; cs.start4[j+1]=cs.start4[j]+(int)(nn[j]/4); }
  }
  k_cvt<<<2048,256,0,stream>>>(cs);
  // attention weight conversion (hi/lo split)
  CvtSegs2 c2;
  {
    const float* ss[3]={Wqd, Wkvd, Wo};
    u16* dh[3]={WDHI, WDHI+144L*D_, WOHI};
    u16* dl[3]={WDLO, WDLO+144L*D_, WOLO};
    long nn[3]={144L*D_, 144L*D_, (long)D_*D_};
    c2.start4[0]=0;
    for(int j=0;j<3;j++){ c2.src[j]=ss[j]; c2.dhi[j]=dh[j]; c2.dlo[j]=dl[j]; c2.start4[j+1]=c2.start4[j]+(int)(nn[j]/4); }
  }
  k_cvt_split<<<512,256,0,stream>>>(c2);
  k_cvt_pad_split<<<(3*D_*160+255)/256,256,0,stream>>>(Wqu,Wku,Wvu,WUPHI,WUPLO);
  k_rope_tab<<<(S_*32+255)/256,256,0,stream>>>(COS,SIN);

  // attention block (split-bf16 MFMA throughout)
  k_rms<<<NT_,64,0,stream>>>(x, ln1, H1HI, H1LO);
  k_gemm2<0><<<dim3(64,3,1),256,0,stream>>>(H1HI,H1LO,D_,0, WDHI,WDLO,D_,0, 288,18, LATHI,LATLO,320, nullptr,0,nullptr);
  k_gemm2<1><<<dim3(64,5,3),256,0,stream>>>(LATHI,LATLO,320,160, WUPHI,WUPLO,160,(long)D_*160, D_,5, nullptr,nullptr,D_, QR,(long)NT_*D_, nullptr);
  k_ropesplit<<<(NT_*H_*32+255)/256,256,0,stream>>>(QR,KR,COS,SIN,QHI,QLO,KHI,KLO);
  k_vsplit<<<dim3(16,72),256,0,stream>>>(VR,VHI,VLO);
  k_attn_split<<<dim3(72,8),256,0,stream>>>(QHI,QLO,KHI,KLO,VHI,VLO,OHI,OLO);
  k_gemm2<2><<<dim3(64,5,1),256,0,stream>>>(OHI,OLO,D_,0, WOHI,WOLO,D_,0, D_,18, nullptr,nullptr,D_, X2,0, x);

  // MoE block
  hipMemsetAsync(CNT,0,64,stream);
  k_rms_router<<<NT_/4,256,0,stream>>>(X2, ln2, Wr, rb, H2B, IDX2, W2);
  k_count<<<NPAIR_/256,256,0,stream>>>(IDX2,CNT);
  k_offsets<<<1,1,0,stream>>>(CNT,OFS,FILL,TS);
  k_scatter2<<<NPAIR_/256,256,0,stream>>>(IDX2,W2,FILL,LTOK,LW,PPOS);
  k_moe_gu<<<dim3(MAXT_,12),256,0,stream>>>(H2B,GB,UB,CNT,OFS,TS,LTOK,ACT);
  k_moe_down<<<dim3(MAXT_,5),256,0,stream>>>(ACT,DB,CNT,OFS,TS,LW,PD);
  k_final<<<(NT_*(D_/4)+255)/256,256,0,stream>>>(X2,PD,PPOS,out);
}

// Round 9
// 658.039 us; speedup vs baseline: 5.2995x; 1.0757x over previous
//
#include <hip/hip_runtime.h>
#include <stdint.h>
#include <math.h>

#define B_    8
#define S_    1024
#define D_    576
#define H_    9
#define HD_   64
#define LAT_  144
#define FF_   1536
#define NE_   7
#define NT_   8192
#define NPAIR_ 16384
#define NACT_  24576
#define MAXT_ 200

typedef unsigned short u16;
typedef __attribute__((ext_vector_type(8))) short bf16x8;
typedef __attribute__((ext_vector_type(4))) float f32x4;
typedef __attribute__((ext_vector_type(4))) unsigned short us4;

__device__ __forceinline__ u16 f2b(float f){
  union{float f;uint32_t u;} v; v.f=f;
  uint32_t u=v.u;
  return (u16)((u + 0x7fffu + ((u>>16)&1u))>>16);
}
__device__ __forceinline__ float b2f(u16 h){
  union{uint32_t u;float f;} v; v.u=((uint32_t)h)<<16; return v.f;
}

#define MFMA16(a,b,c) __builtin_amdgcn_mfma_f32_16x16x32_bf16((a),(b),(c),0,0,0)

typedef __attribute__((address_space(1))) const unsigned char g_u8;
typedef __attribute__((address_space(3))) unsigned char s_u8;
__device__ __forceinline__ void gll16(const void* g, void* l){
  __builtin_amdgcn_global_load_lds((g_u8*)g, (s_u8*)l, 16, 0, 0);
}

// ---------------- MoE weight conversion fp32->bf16 ----------------
struct CvtSegs {
  const float* src[6];
  u16* dst[6];
  int start4[7];
};
__global__ void k_cvt(CvtSegs cs){
  int tot = cs.start4[6];
  for(int i = blockIdx.x*blockDim.x + threadIdx.x; i < tot; i += gridDim.x*blockDim.x){
    int s=0;
    #pragma unroll
    for(int j=0;j<6;j++) if(i >= cs.start4[j+1]) s=j+1;
    int loc = i - cs.start4[s];
    float4 v = ((const float4*)cs.src[s])[loc];
    us4 o; o[0]=f2b(v.x); o[1]=f2b(v.y); o[2]=f2b(v.z); o[3]=f2b(v.w);
    ((us4*)cs.dst[s])[loc] = o;
  }
}

// ---------------- attention weight conversion fp32 -> hi/lo bf16 -------
struct CvtSegs2 {
  const float* src[3];
  u16* dhi[3]; u16* dlo[3];
  int start4[4];
};
__global__ void k_cvt_split(CvtSegs2 cs){
  int tot = cs.start4[3];
  for(int i = blockIdx.x*blockDim.x + threadIdx.x; i < tot; i += gridDim.x*blockDim.x){
    int s=0;
    #pragma unroll
    for(int j=0;j<3;j++) if(i >= cs.start4[j+1]) s=j+1;
    int loc = i - cs.start4[s];
    float4 v = ((const float4*)cs.src[s])[loc];
    us4 oh, ol;
    float vv[4]={v.x,v.y,v.z,v.w};
    #pragma unroll
    for(int j=0;j<4;j++){ u16 hh=f2b(vv[j]); oh[j]=hh; ol[j]=f2b(vv[j]-b2f(hh)); }
    ((us4*)cs.dhi[s])[loc]=oh;
    ((us4*)cs.dlo[s])[loc]=ol;
  }
}

// up-proj weights [3][576][144] -> padded [3][576][160] hi/lo
__global__ void k_cvt_pad_split(const float* __restrict__ Wqu, const float* __restrict__ Wku,
                                const float* __restrict__ Wvu,
                                u16* __restrict__ dhi, u16* __restrict__ dlo){
  int i = blockIdx.x*256 + threadIdx.x;
  if(i >= 3*D_*160) return;
  int z = i/(D_*160); int rem = i - z*D_*160;
  int row = rem/160, col = rem - row*160;
  const float* s = (z==0)?Wqu:((z==1)?Wku:Wvu);
  float v = (col<LAT_)? s[row*LAT_+col] : 0.f;
  u16 hh=f2b(v);
  dhi[i]=hh; dlo[i]=f2b(v-b2f(hh));
}

// ---------------- RoPE tables ----------------
__global__ void k_rope_tab(float* __restrict__ cost, float* __restrict__ sint){
  int i = blockIdx.x*256+threadIdx.x; if(i>=S_*32) return;
  int s=i>>5, d=i&31;
  float pw = (float)pow(10000.0, (double)d/32.0);
  float inv = 1.0f/pw;
  float ang = (float)s*inv;
  cost[i]=cosf(ang); sint[i]=sinf(ang);
}

// ---------------- fp32 rmsnorm -> hi/lo bf16 ----------------
__global__ __launch_bounds__(64) void k_rms(const float* __restrict__ x, const float* __restrict__ w,
                      u16* __restrict__ hhi, u16* __restrict__ hlo){
  int t = blockIdx.x; int lane = threadIdx.x;
  const float* xr = x + (size_t)t*D_;
  float v[9]; float ss=0.f;
  #pragma unroll
  for(int j=0;j<9;j++){ v[j]=xr[lane+64*j]; ss += v[j]*v[j]; }
  #pragma unroll
  for(int m=1;m<64;m<<=1) ss += __shfl_xor(ss,m,64);
  float sc = 1.0f/sqrtf(ss/(float)D_ + 1e-5f);
  #pragma unroll
  for(int j=0;j<9;j++){
    float y = v[j]*sc*w[lane+64*j];
    size_t o=(size_t)t*D_+lane+64*j;
    u16 hh=f2b(y); hhi[o]=hh; hlo[o]=f2b(y-b2f(hh));
  }
}

// ---------------- fused rmsnorm2 + router (fp32 exact) -----------------
__global__ __launch_bounds__(256) void k_rms_router(const float* __restrict__ x2, const float* __restrict__ w,
                        const float* __restrict__ Wr, const float* __restrict__ rb,
                        u16* __restrict__ hb, int* __restrict__ idx2, float* __restrict__ w2){
  int wid=threadIdx.x>>6, lane=threadIdx.x&63;
  int t = blockIdx.x*4 + wid;
  const float* xr = x2 + (size_t)t*D_;
  float v[9]; float ss=0.f;
  #pragma unroll
  for(int j=0;j<9;j++){ v[j]=xr[lane+64*j]; ss += v[j]*v[j]; }
  #pragma unroll
  for(int m=1;m<64;m<<=1) ss += __shfl_xor(ss,m,64);
  float sc = 1.0f/sqrtf(ss/(float)D_ + 1e-5f);
  float hv[9];
  #pragma unroll
  for(int j=0;j<9;j++){
    float y = v[j]*sc*w[lane+64*j];
    hv[j]=y;
    hb[(size_t)t*D_+lane+64*j]=f2b(y);
  }
  float pr[7];
  #pragma unroll
  for(int e=0;e<7;e++){
    float s=0.f;
    #pragma unroll
    for(int j=0;j<9;j++) s += hv[j]*Wr[e*D_+lane+64*j];
    #pragma unroll
    for(int mm=1;mm<64;mm<<=1) s+=__shfl_xor(s,mm,64);
    pr[e] = 1.f/(1.f+expf(-(s+rb[e])));
  }
  int e0=0; float b0=pr[0];
  #pragma unroll
  for(int e=1;e<7;e++) if(pr[e]>b0){b0=pr[e];e0=e;}
  int e1=-1; float b1=-1e30f;
  #pragma unroll
  for(int e=0;e<7;e++) if(e!=e0 && pr[e]>b1){b1=pr[e];e1=e;}
  if(lane==0){
    float s=b0+b1;
    idx2[2*t]=e0; idx2[2*t+1]=e1;
    w2[2*t]=b0/s; w2[2*t+1]=b1/s;
  }
}

// ---------------- split-bf16 128x128 MFMA GEMM (swizzled LDS) ----------
template<int EPI>
__global__ __launch_bounds__(256) void k_gemm2(
    const u16* __restrict__ Ahi, const u16* __restrict__ Alo, int lda, int aofs_z,
    const u16* __restrict__ Bhi, const u16* __restrict__ Blo, int ldb, long bStrideZ,
    int N, int ksteps,
    u16* __restrict__ Chi, u16* __restrict__ Clo, int ldc,
    float* __restrict__ C32, long cStrideZ, const float* __restrict__ resid)
{
  __shared__ u16 Ahs[128*32], Als[128*32], Bhs[128*32], Bls[128*32];
  int tid=threadIdx.x, wid=tid>>6, lane=tid&63;
  int m0=blockIdx.x*128, n0=blockIdx.y*128, z=blockIdx.z;
  const u16* Abh = Ahi + ((z>0)?aofs_z:0);
  const u16* Abl = Alo + ((z>0)?aofs_z:0);
  const u16* Bbh = Bhi + (long)z*bStrideZ;
  const u16* Bbl = Blo + (long)z*bStrideZ;
  int lq=lane&15, lg=lane>>4;
  int wr=wid>>1, wc=wid&1;
  f32x4 acc[4][4]={};
  for(int kt=0;kt<ksteps;kt++){
    #pragma unroll
    for(int is=0;is<2;is++){
      int ub = is*4096 + wid*1024;
      int o = ub + lane*16;
      int row = o>>6, p=(o>>4)&3;
      int sc8 = ((p ^ ((row>>1)&3)))*8;
      long aoff = (long)(m0+row)*lda + kt*32 + sc8;
      gll16(Abh+aoff, (char*)Ahs+ub);
      gll16(Abl+aoff, (char*)Als+ub);
      int rowb = n0+row; rowb = rowb<N?rowb:(N-1);
      long boff = (long)rowb*ldb + kt*32 + sc8;
      gll16(Bbh+boff, (char*)Bhs+ub);
      gll16(Bbl+boff, (char*)Bls+ub);
    }
    __syncthreads();
    bf16x8 ah[4], al[4], bh[4], bl[4];
    #pragma unroll
    for(int m=0;m<4;m++){
      int arow=wr*64+m*16+lq;
      int co = arow*32 + ((lg ^ ((arow>>1)&3)))*8;
      ah[m]=*(const bf16x8*)&Ahs[co];
      al[m]=*(const bf16x8*)&Als[co];
    }
    #pragma unroll
    for(int n=0;n<4;n++){
      int brow=wc*64+n*16+lq;
      int co = brow*32 + ((lg ^ ((brow>>1)&3)))*8;
      bh[n]=*(const bf16x8*)&Bhs[co];
      bl[n]=*(const bf16x8*)&Bls[co];
    }
    #pragma unroll
    for(int m=0;m<4;m++)
      #pragma unroll
      for(int n=0;n<4;n++){
        acc[m][n]=MFMA16(ah[m],bh[n],acc[m][n]);
        acc[m][n]=MFMA16(ah[m],bl[n],acc[m][n]);
        acc[m][n]=MFMA16(al[m],bh[n],acc[m][n]);
      }
    __syncthreads();
  }
  #pragma unroll
  for(int m=0;m<4;m++){
    #pragma unroll
    for(int n=0;n<4;n++){
      int col = n0 + wc*64 + n*16 + lq;
      if(col<N){
        #pragma unroll
        for(int r=0;r<4;r++){
          int row = m0 + wr*64 + m*16 + lg*4 + r;
          float val = acc[m][n][r];
          if(EPI==0){
            int dc = (col<144)? col : col+16;
            u16 hh=f2b(val);
            Chi[(long)row*ldc + dc] = hh;
            Clo[(long)row*ldc + dc] = f2b(val-b2f(hh));
          } else if(EPI==1){
            (C32 + (long)z*cStrideZ)[(long)row*ldc + col] = val;
          } else {
            C32[(long)row*ldc+col] = resid[(long)row*ldc+col] + val;
          }
        }
      }
    }
  }
}

// ---------------- RoPE + hi/lo split repack ----------------
__global__ void k_ropesplit(const float* __restrict__ QR, const float* __restrict__ KR,
                            const float* __restrict__ cost, const float* __restrict__ sint,
                            u16* __restrict__ QHI, u16* __restrict__ QLO,
                            u16* __restrict__ KHI, u16* __restrict__ KLO){
  int i = blockIdx.x*256+threadIdx.x;
  if(i >= NT_*H_*32) return;
  int d = i&31; int h=(i>>5)%H_; int t = i/(H_*32);
  int s = t & (S_-1); int b = t >> 10;
  float c = cost[s*32+d], sn = sint[s*32+d];
  long qi = (long)t*D_ + h*HD_ + d;
  float q1=QR[qi], q2=QR[qi+32];
  float k1=KR[qi], k2=KR[qi+32];
  long ob = ((long)(b*H_+h)*S_ + s)*HD_ + d;
  float qa=(q1*c - q2*sn)*0.125f, qb2=(q2*c + q1*sn)*0.125f;
  float ka=k1*c - k2*sn,          kb2=k2*c + k1*sn;
  u16 hh;
  hh=f2b(qa);  QHI[ob]=hh;    QLO[ob]   =f2b(qa -b2f(hh));
  hh=f2b(qb2); QHI[ob+32]=hh; QLO[ob+32]=f2b(qb2-b2f(hh));
  hh=f2b(ka);  KHI[ob]=hh;    KLO[ob]   =f2b(ka -b2f(hh));
  hh=f2b(kb2); KHI[ob+32]=hh; KLO[ob+32]=f2b(kb2-b2f(hh));
}

// ---------------- V transpose + hi/lo split: [b][s][576] -> [bh][64][S] --
__global__ __launch_bounds__(256) void k_vsplit(const float* __restrict__ VR,
                       u16* __restrict__ VHI, u16* __restrict__ VLO){
  __shared__ float ls[64][65];
  int s0 = blockIdx.x*64; int bh = blockIdx.y;
  int b = bh/H_, h = bh - b*H_;
  int tid=threadIdx.x;
  #pragma unroll
  for(int i=0;i<16;i++){
    int idx = tid + i*256;
    int si = idx>>6, dj = idx&63;
    ls[si][dj] = VR[((long)(b*S_+s0+si))*D_ + h*HD_ + dj];
  }
  __syncthreads();
  #pragma unroll
  for(int i=0;i<16;i++){
    int idx = tid + i*256;
    int di = idx>>6, sj = idx&63;
    float v = ls[sj][di];
    u16 hh = f2b(v);
    long o = ((long)bh*HD_+di)*S_ + s0+sj;
    VHI[o]=hh; VLO[o]=f2b(v-b2f(hh));
  }
}

// ---------------- split-bf16 MFMA flash attention v3 -------------------
__global__ __launch_bounds__(256) void k_attn_split(
    const u16* __restrict__ QHI, const u16* __restrict__ QLO,
    const u16* __restrict__ KHI, const u16* __restrict__ KLO,
    const u16* __restrict__ VHI, const u16* __restrict__ VLO,
    u16* __restrict__ OHI, u16* __restrict__ OLO){
  __shared__ u16 lds[2][4][64*64];   // [buf][Khi,Klo,Vhi,Vlo][row*64]
  int tid=threadIdx.x, wid=tid>>6, lane=tid&63;
  int bh=blockIdx.x; int b=bh/H_, h=bh-b*H_;
  int jb=blockIdx.y;
  int lq=lane&15, lg=lane>>4;
  int jslot=lane&7, rloc=lane>>3;

  for(int pass=0;pass<2;pass++){
    int tile = pass? (15-jb) : jb;
    int ntile = tile+1;
    int q0 = tile*64 + wid*16;
    long qoff = ((long)bh*S_ + q0+lq)*HD_;
    bf16x8 qh0 = *(const bf16x8*)(QHI+qoff+lg*8);
    bf16x8 qh1 = *(const bf16x8*)(QHI+qoff+32+lg*8);
    bf16x8 ql0 = *(const bf16x8*)(QLO+qoff+lg*8);
    bf16x8 ql1 = *(const bf16x8*)(QLO+qoff+32+lg*8);
    float m=-1e30f, l=0.f;
    f32x4 ot[4]={};
    int q_lane = q0 + lq;

    #define STAGE(bufi, kv0_) do{                                          \
      int _kv0=(kv0_);                                                     \
      _Pragma("unroll")                                                    \
      for(int c=0;c<2;c++){                                                \
        int r = wid*16 + c*8 + rloc;                                       \
        int col = 8*(jslot ^ (r&7));                                       \
        long kg = ((long)bh*S_ + _kv0 + r)*64 + col;                       \
        long vg = ((long)bh*64 + r)*S_ + _kv0 + col;                       \
        int lb = (wid*16 + c*8)*64;                                        \
        gll16(KHI+kg, &lds[bufi][0][lb]);                                  \
        gll16(KLO+kg, &lds[bufi][1][lb]);                                  \
        gll16(VHI+vg, &lds[bufi][2][lb]);                                  \
        gll16(VLO+vg, &lds[bufi][3][lb]);                                  \
      } }while(0)

    STAGE(0, 0);
    __syncthreads();
    for(int t=0;t<ntile;t++){
      if(t+1<ntile) STAGE((t+1)&1, (t+1)*64);
      int bufc = t&1;
      int kv0 = t*64;
      bool last = (t==ntile-1);
      const char* Khs=(const char*)lds[bufc][0];
      const char* Kls=(const char*)lds[bufc][1];
      const char* Vhs=(const char*)lds[bufc][2];
      const char* Vls=(const char*)lds[bufc][3];
      #pragma unroll
      for(int kvh=0;kvh<64;kvh+=32){
        float p[8];
        float tmax=-1e30f;
        #pragma unroll
        for(int sub=0;sub<2;sub++){
          int r = kvh + sub*16 + lq;
          int sw = (r&7)<<4;
          bf16x8 kh0=*(const bf16x8*)(Khs + r*128 + ((lg*16) ^ sw));
          bf16x8 kh1=*(const bf16x8*)(Khs + r*128 + ((64+lg*16) ^ sw));
          bf16x8 kl0=*(const bf16x8*)(Kls + r*128 + ((lg*16) ^ sw));
          bf16x8 kl1=*(const bf16x8*)(Kls + r*128 + ((64+lg*16) ^ sw));
          f32x4 st={0.f,0.f,0.f,0.f};
          st=MFMA16(kh0,qh0,st); st=MFMA16(kh1,qh1,st);
          st=MFMA16(kl0,qh0,st); st=MFMA16(kl1,qh1,st);
          st=MFMA16(kh0,ql0,st); st=MFMA16(kh1,ql1,st);
          #pragma unroll
          for(int r2=0;r2<4;r2++){
            int key = kv0 + kvh + sub*16 + lg*4 + r2;
            float sv = (!last || key <= q_lane)? st[r2] : -1e30f;
            p[sub*4+r2]=sv;
            tmax = fmaxf(tmax, sv);
          }
        }
        tmax = fmaxf(tmax, __shfl_xor(tmax,16,64));
        tmax = fmaxf(tmax, __shfl_xor(tmax,32,64));
        float mn = fmaxf(m, tmax);
        float sc = __expf(m - mn);
        l *= sc;
        #pragma unroll
        for(int t2=0;t2<4;t2++)
          #pragma unroll
          for(int r2=0;r2<4;r2++) ot[t2][r2]*=sc;
        float ps=0.f;
        #pragma unroll
        for(int j=0;j<8;j++){ p[j]=__expf(p[j]-mn); ps+=p[j]; }
        l+=ps; m=mn;
        bf16x8 ph, pl;
        #pragma unroll
        for(int j=0;j<8;j++){
          u16 hb2=f2b(p[j]);
          ph[j]=(short)hb2;
          pl[j]=(short)f2b(p[j]-b2f(hb2));
        }
        #pragma unroll
        for(int t2=0;t2<4;t2++){
          int d = t2*16+lq;
          int swd = (d&7)<<4;
          int b1 = (2*(kvh+4*lg)) ^ swd;
          int b2v = (2*(kvh+16+4*lg)) ^ swd;
          us4 vh0=*(const us4*)(Vhs + d*128 + b1);
          us4 vh1=*(const us4*)(Vhs + d*128 + b2v);
          us4 vl0=*(const us4*)(Vls + d*128 + b1);
          us4 vl1=*(const us4*)(Vls + d*128 + b2v);
          bf16x8 vh, vl;
          #pragma unroll
          for(int j=0;j<4;j++){
            vh[j]=(short)vh0[j]; vh[4+j]=(short)vh1[j];
            vl[j]=(short)vl0[j]; vl[4+j]=(short)vl1[j];
          }
          ot[t2]=MFMA16(vh,ph,ot[t2]);
          ot[t2]=MFMA16(vl,ph,ot[t2]);
          ot[t2]=MFMA16(vh,pl,ot[t2]);
        }
      }
      __syncthreads();
    }
    #undef STAGE
    float l1 = l + __shfl_xor(l,16,64);
    float lt = l1 + __shfl_xor(l1,32,64);
    float inv = 1.f/lt;
    long orow = ((long)b*S_ + q_lane)*D_ + h*HD_;
    #pragma unroll
    for(int t2=0;t2<4;t2++){
      us4 oh4, ol4;
      #pragma unroll
      for(int r2=0;r2<4;r2++){
        float v=ot[t2][r2]*inv;
        u16 hh=f2b(v);
        oh4[r2]=hh; ol4[r2]=f2b(v-b2f(hh));
      }
      *(us4*)(OHI + orow + t2*16 + 4*lg) = oh4;
      *(us4*)(OLO + orow + t2*16 + 4*lg) = ol4;
    }
  }
}

// ---------------- expert histogram (LDS, 7 global atomics/block) -------
__global__ __launch_bounds__(256) void k_count(const int* __restrict__ idx2, int* __restrict__ counts){
  __shared__ int hist[NE_];
  int tid=threadIdx.x;
  if(tid<NE_) hist[tid]=0;
  __syncthreads();
  int i = blockIdx.x*256+tid;
  atomicAdd(&hist[idx2[i]],1);
  __syncthreads();
  if(tid<NE_) atomicAdd(&counts[tid], hist[tid]);
}

// offsets + flattened tile table (ts[0..7]=tile start per group, ts[8]=total)
__global__ void k_offsets(const int* __restrict__ counts, int* __restrict__ ofs,
                          int* __restrict__ fill, int* __restrict__ ts){
  if(threadIdx.x==0 && blockIdx.x==0){
    int a=0;
    for(int e=0;e<NE_;e++){ ofs[e]=a; fill[e]=a; a+=counts[e]; }
    ofs[NE_]=a;
    int t=0;
    for(int e=0;e<NE_;e++){ ts[e]=t; t += (counts[e]+127)>>7; }
    ts[NE_]=t; t+=64;          // shared expert: 64 m-tiles
    ts[NE_+1]=t;
  }
}

// ---------------- ballot-scan scatter (1 atomic/expert/block) ----------
__global__ __launch_bounds__(256) void k_scatter2(const int* __restrict__ idx2, const float* __restrict__ w2,
                          int* __restrict__ fill, int* __restrict__ ltok,
                          float* __restrict__ lw, int* __restrict__ ppos){
  __shared__ int wcnt[4][8];
  __shared__ int wpre[4][8];
  __shared__ int base[8];
  int tid=threadIdx.x, wid=tid>>6, lane=tid&63;
  int slot = blockIdx.x*256 + wid*64 + lane;
  int id = idx2[slot];
  unsigned long long ltm = (1ull<<lane)-1ull;
  int myrank=0;
  #pragma unroll
  for(int e=0;e<7;e++){
    unsigned long long mask = __ballot(id==e);
    if(id==e) myrank = __popcll(mask & ltm);
    if(lane==0) wcnt[wid][e] = __popcll(mask);
  }
  __syncthreads();
  if(wid==0 && lane<7){
    int e=lane;
    int s0=wcnt[0][e], s1=wcnt[1][e], s2=wcnt[2][e], s3=wcnt[3][e];
    wpre[0][e]=0; wpre[1][e]=s0; wpre[2][e]=s0+s1; wpre[3][e]=s0+s1+s2;
    base[e] = atomicAdd(&fill[e], s0+s1+s2+s3);
  }
  __syncthreads();
  int pos = base[id] + wpre[wid][id] + myrank;
  ltok[pos] = slot>>1;
  lw[pos] = w2[slot];
  ppos[slot] = pos;
}

// ---------------- grouped gate+up+SwiGLU (dbuf prefetch, f-fast grid) --
__global__ __launch_bounds__(256) void k_moe_gu(const u16* __restrict__ h2b, const u16* __restrict__ Gb,
                        const u16* __restrict__ Ub, const int* __restrict__ cnt,
                        const int* __restrict__ ofs, const int* __restrict__ ts,
                        const int* __restrict__ ltok, u16* __restrict__ act){
  int tsv[9];
  #pragma unroll
  for(int i=0;i<9;i++) tsv[i]=ts[i];
  int xt = blockIdx.y;
  if(xt >= tsv[8]) return;
  int e=0;
  #pragma unroll
  for(int i=1;i<8;i++) if(xt >= tsv[i]) e=i;
  int mt = xt - tsv[e];
  int nrows = (e<NE_)? cnt[e] : NT_;
  int base  = (e<NE_)? ofs[e] : 0;
  long arow0 = (e<NE_)? (long)base : (long)NPAIR_;
  int f0 = blockIdx.x*128;
  __shared__ u16 As[2][128*32], Gs[2][128*32], Us[2][128*32];
  int tid=threadIdx.x, wid=tid>>6, lane=tid&63;
  int lq=lane&15, lg=lane>>4;
  int wr=wid>>1, wc=wid&1;
  // per-thread staging rows (fixed across K) + swizzled source chunk
  int r0 = wid*16 + (lane>>2);
  int r1 = 64 + r0;
  int so = wid*1024 + lane*16;               // dest byte offset (first half)
  int sc8 = ((lane&3) ^ ((r0>>1)&3))*8;      // same for r1 (r1=r0+64)
  int ri0 = mt*128+r0; if(ri0>nrows-1) ri0=nrows-1;
  int ri1 = mt*128+r1; if(ri1>nrows-1) ri1=nrows-1;
  long tok0 = (e<NE_)? (long)ltok[base+ri0] : (long)ri0;
  long tok1 = (e<NE_)? (long)ltok[base+ri1] : (long)ri1;
  const u16* a0 = h2b + tok0*D_ + sc8;
  const u16* a1 = h2b + tok1*D_ + sc8;
  const u16* g0 = Gb + ((long)e*FF_ + f0 + r0)*D_ + sc8;
  const u16* g1 = Gb + ((long)e*FF_ + f0 + r1)*D_ + sc8;
  const u16* u0 = Ub + ((long)e*FF_ + f0 + r0)*D_ + sc8;
  const u16* u1 = Ub + ((long)e*FF_ + f0 + r1)*D_ + sc8;
  #define STG(bi, kt_) do{ int ko=(kt_)*32;                       \
    gll16(a0+ko, (char*)As[bi]+so);                               \
    gll16(a1+ko, (char*)As[bi]+4096+so);                          \
    gll16(g0+ko, (char*)Gs[bi]+so);                               \
    gll16(g1+ko, (char*)Gs[bi]+4096+so);                          \
    gll16(u0+ko, (char*)Us[bi]+so);                               \
    gll16(u1+ko, (char*)Us[bi]+4096+so); }while(0)
  f32x4 ag_[4][4]={}, au_[4][4]={};
  STG(0,0);
  __syncthreads();
  for(int kt=0;kt<18;kt++){
    int cur = kt&1;
    if(kt<17) STG(cur^1, kt+1);
    bf16x8 af[4], gf[4], uf[4];
    #pragma unroll
    for(int m=0;m<4;m++){
      int arow=wr*64+m*16+lq;
      af[m]=*(const bf16x8*)&As[cur][arow*32 + ((lg ^ ((arow>>1)&3)))*8];
    }
    #pragma unroll
    for(int n=0;n<4;n++){
      int grow=wc*64+n*16+lq;
      int co = grow*32 + ((lg ^ ((grow>>1)&3)))*8;
      gf[n]=*(const bf16x8*)&Gs[cur][co];
      uf[n]=*(const bf16x8*)&Us[cur][co];
    }
    #pragma unroll
    for(int m=0;m<4;m++)
      #pragma unroll
      for(int n=0;n<4;n++){
        ag_[m][n]=MFMA16(af[m],gf[n],ag_[m][n]);
        au_[m][n]=MFMA16(af[m],uf[n],au_[m][n]);
      }
    __syncthreads();
  }
  #undef STG
  #pragma unroll
  for(int m=0;m<4;m++){
    #pragma unroll
    for(int n=0;n<4;n++){
      int f = f0 + wc*64+n*16+lq;
      #pragma unroll
      for(int r=0;r<4;r++){
        int rl = wr*64+m*16+lg*4+r;
        int ridx = mt*128+rl;
        if(ridx<nrows){
          float g=ag_[m][n][r], u=au_[m][n][r];
          float sw = g/(1.f+__expf(-g))*u;
          act[(arow0+ridx)*FF_ + f] = f2b(sw);
        }
      }
    }
  }
}

// ---------------- grouped down-proj (dbuf prefetch, f-fast grid) -------
__global__ __launch_bounds__(256) void k_moe_down(const u16* __restrict__ act, const u16* __restrict__ Db,
                          const int* __restrict__ cnt, const int* __restrict__ ofs,
                          const int* __restrict__ ts, const float* __restrict__ lw,
                          u16* __restrict__ pd){
  int tsv[9];
  #pragma unroll
  for(int i=0;i<9;i++) tsv[i]=ts[i];
  int xt = blockIdx.y;
  if(xt >= tsv[8]) return;
  int e=0;
  #pragma unroll
  for(int i=1;i<8;i++) if(xt >= tsv[i]) e=i;
  int mt = xt - tsv[e];
  int nrows=(e<NE_)?cnt[e]:NT_;
  long arow0=(e<NE_)?(long)ofs[e]:(long)NPAIR_;
  int n0=blockIdx.x*128;
  __shared__ u16 As[2][128*32], Bs[2][128*32];
  int tid=threadIdx.x,wid=tid>>6,lane=tid&63;
  int lq=lane&15,lg=lane>>4;
  int wr=wid>>1,wc=wid&1;
  int r0 = wid*16 + (lane>>2);
  int r1 = 64 + r0;
  int so = wid*1024 + lane*16;
  int sc8 = ((lane&3) ^ ((r0>>1)&3))*8;
  int ri0 = mt*128+r0; if(ri0>nrows-1) ri0=nrows-1;
  int ri1 = mt*128+r1; if(ri1>nrows-1) ri1=nrows-1;
  const u16* a0 = act + (arow0+ri0)*FF_ + sc8;
  const u16* a1 = act + (arow0+ri1)*FF_ + sc8;
  int rb0 = n0+r0; if(rb0>D_-1) rb0=D_-1;
  int rb1 = n0+r1; if(rb1>D_-1) rb1=D_-1;
  const u16* b0p = Db + ((long)e*D_ + rb0)*FF_ + sc8;
  const u16* b1p = Db + ((long)e*D_ + rb1)*FF_ + sc8;
  #define STG(bi, kt_) do{ int ko=(kt_)*32;                       \
    gll16(a0+ko, (char*)As[bi]+so);                               \
    gll16(a1+ko, (char*)As[bi]+4096+so);                          \
    gll16(b0p+ko, (char*)Bs[bi]+so);                              \
    gll16(b1p+ko, (char*)Bs[bi]+4096+so); }while(0)
  f32x4 acc[4][4]={};
  STG(0,0);
  __syncthreads();
  for(int kt=0;kt<48;kt++){
    int cur = kt&1;
    if(kt<47) STG(cur^1, kt+1);
    bf16x8 af[4],bf2[4];
    #pragma unroll
    for(int m=0;m<4;m++){
      int arow=wr*64+m*16+lq;
      af[m]=*(const bf16x8*)&As[cur][arow*32 + ((lg ^ ((arow>>1)&3)))*8];
    }
    #pragma unroll
    for(int n=0;n<4;n++){
      int brow=wc*64+n*16+lq;
      bf2[n]=*(const bf16x8*)&Bs[cur][brow*32 + ((lg ^ ((brow>>1)&3)))*8];
    }
    #pragma unroll
    for(int m=0;m<4;m++)
      #pragma unroll
      for(int n=0;n<4;n++)
        acc[m][n]=MFMA16(af[m],bf2[n],acc[m][n]);
    __syncthreads();
  }
  #undef STG
  #pragma unroll
  for(int m=0;m<4;m++){
    #pragma unroll
    for(int n=0;n<4;n++){
      int col=n0+wc*64+n*16+lq;
      if(col<D_){
        #pragma unroll
        for(int r=0;r<4;r++){
          int rl=wr*64+m*16+lg*4+r;
          int ridx=mt*128+rl;
          if(ridx<nrows){
            float w=1.f;
            if(e<NE_) w=lw[arow0+ridx];
            pd[(arow0+ridx)*D_ + col]=f2b(w*acc[m][n][r]);
          }
        }
      }
    }
  }
}

// ---------------- final combine ----------------
__global__ void k_final(const float* __restrict__ x2, const u16* __restrict__ pd,
                        const int* __restrict__ ppos, float* __restrict__ out){
  int i=blockIdx.x*256+threadIdx.x;
  int tot = NT_*(D_/4);
  if(i>=tot) return;
  int t = i/(D_/4); int c = (i - t*(D_/4))*4;
  int p0=ppos[2*t], p1=ppos[2*t+1];
  const u16* a=pd+((long)NPAIR_+t)*D_+c;
  const u16* b=pd+(long)p0*D_+c;
  const u16* d=pd+(long)p1*D_+c;
  const float* xr = x2+(long)t*D_+c;
  float* o = out+(long)t*D_+c;
  #pragma unroll
  for(int j=0;j<4;j++) o[j]=xr[j]+b2f(a[j])+b2f(b[j])+b2f(d[j]);
}

extern "C" void kernel_launch(void* const* d_in, const int* in_sizes, int n_in,
                              void* d_out, int out_size, void* d_ws, size_t ws_size,
                              hipStream_t stream){
  const float* x    =(const float*)d_in[0];
  const float* ln1  =(const float*)d_in[1];
  const float* ln2  =(const float*)d_in[2];
  const float* Wqd  =(const float*)d_in[3];
  const float* Wkvd =(const float*)d_in[4];
  const float* Wqu  =(const float*)d_in[5];
  const float* Wku  =(const float*)d_in[6];
  const float* Wvu  =(const float*)d_in[7];
  const float* Wo   =(const float*)d_in[8];
  const float* sg   =(const float*)d_in[9];
  const float* su   =(const float*)d_in[10];
  const float* sd   =(const float*)d_in[11];
  const float* rg   =(const float*)d_in[12];
  const float* ru   =(const float*)d_in[13];
  const float* rd   =(const float*)d_in[14];
  const float* Wr   =(const float*)d_in[15];
  const float* rb   =(const float*)d_in[16];
  float* out=(float*)d_out;

  char* ws=(char*)d_ws;
  size_t off=0;
  auto alloc=[&](size_t bsz){ size_t r=off; off=(off+bsz+255)&~(size_t)255; return r; };
  // fixed region
  u16* GB   =(u16*)(ws+alloc(8L*FF_*D_*2));
  u16* UB   =(u16*)(ws+alloc(8L*FF_*D_*2));
  u16* DB   =(u16*)(ws+alloc(8L*D_*FF_*2));
  float* COS=(float*)(ws+alloc(S_*32*4));
  float* SIN=(float*)(ws+alloc(S_*32*4));
  float* X2 =(float*)(ws+alloc((long)NT_*D_*4));
  u16* H2B  =(u16*)(ws+alloc((long)NT_*D_*2));
  int* IDX2 =(int*)(ws+alloc(NT_*2*4));
  float* W2 =(float*)(ws+alloc(NT_*2*4));
  int* PPOS =(int*)(ws+alloc(NT_*2*4));
  int* CNT  =(int*)(ws+alloc(64));
  int* OFS  =(int*)(ws+alloc(64));
  int* FILL =(int*)(ws+alloc(64));
  int* TS   =(int*)(ws+alloc(64));
  int* LTOK =(int*)(ws+alloc(NPAIR_*4));
  float* LW =(float*)(ws+alloc(NPAIR_*4));
  size_t scr0 = off;
  // phase A (attention)
  const long NQ = (long)B_*H_*S_*HD_;   // 4.72M elems
  u16* H1HI=(u16*)(ws+alloc((long)NT_*D_*2));
  u16* H1LO=(u16*)(ws+alloc((long)NT_*D_*2));
  u16* LATHI=(u16*)(ws+alloc((long)NT_*320*2));
  u16* LATLO=(u16*)(ws+alloc((long)NT_*320*2));
  float* QR =(float*)(ws+alloc((long)NT_*D_*4));
  float* KR =(float*)(ws+alloc((long)NT_*D_*4));
  float* VR =(float*)(ws+alloc((long)NT_*D_*4));
  u16* QHI =(u16*)(ws+alloc(NQ*2));
  u16* QLO =(u16*)(ws+alloc(NQ*2));
  u16* KHI =(u16*)(ws+alloc(NQ*2));
  u16* KLO =(u16*)(ws+alloc(NQ*2));
  u16* WDHI=(u16*)(ws+alloc(288L*D_*2));
  u16* WDLO=(u16*)(ws+alloc(288L*D_*2));
  u16* WUPHI=(u16*)(ws+alloc(3L*D_*160*2));
  u16* WUPLO=(u16*)(ws+alloc(3L*D_*160*2));
  u16* WOHI=(u16*)(ws+alloc((long)D_*D_*2));
  u16* WOLO=(u16*)(ws+alloc((long)D_*D_*2));
  u16* VHI = (u16*)QR;
  u16* VLO = (u16*)QR + NQ;
  u16* OHI = H1HI;
  u16* OLO = H1LO;
  // phase B (MoE) overlaps phase A
  off = scr0;
  u16* ACT =(u16*)(ws+alloc((long)NACT_*FF_*2));
  u16* PD  =(u16*)(ws+alloc((long)NACT_*D_*2));
  (void)ws_size;

  // MoE weight conversion (plain bf16)
  CvtSegs cs;
  {
    const float* ss[6]={rg,sg,ru,su,rd,sd};
    u16* dd[6]={GB, GB+7L*FF_*D_, UB, UB+7L*FF_*D_, DB, DB+7L*D_*FF_};
    long nn[6]={7L*FF_*D_,(long)FF_*D_,7L*FF_*D_,(long)FF_*D_,7L*D_*FF_,(long)D_*FF_};
    cs.start4[0]=0;
    for(int j=0;j<6;j++){ cs.src[j]=ss[j]; cs.dst[j]=dd[j]; cs.start4[j+1]=cs.start4[j]+(int)(nn[j]/4); }
  }
  k_cvt<<<2048,256,0,stream>>>(cs);
  // attention weight conversion (hi/lo split)
  CvtSegs2 c2;
  {
    const float* ss[3]={Wqd, Wkvd, Wo};
    u16* dh[3]={WDHI, WDHI+144L*D_, WOHI};
    u16* dl[3]={WDLO, WDLO+144L*D_, WOLO};
    long nn[3]={144L*D_, 144L*D_, (long)D_*D_};
    c2.start4[0]=0;
    for(int j=0;j<3;j++){ c2.src[j]=ss[j]; c2.dhi[j]=dh[j]; c2.dlo[j]=dl[j]; c2.start4[j+1]=c2.start4[j]+(int)(nn[j]/4); }
  }
  k_cvt_split<<<512,256,0,stream>>>(c2);
  k_cvt_pad_split<<<(3*D_*160+255)/256,256,0,stream>>>(Wqu,Wku,Wvu,WUPHI,WUPLO);
  k_rope_tab<<<(S_*32+255)/256,256,0,stream>>>(COS,SIN);

  // attention block (split-bf16 MFMA throughout)
  k_rms<<<NT_,64,0,stream>>>(x, ln1, H1HI, H1LO);
  k_gemm2<0><<<dim3(64,3,1),256,0,stream>>>(H1HI,H1LO,D_,0, WDHI,WDLO,D_,0, 288,18, LATHI,LATLO,320, nullptr,0,nullptr);
  k_gemm2<1><<<dim3(64,5,3),256,0,stream>>>(LATHI,LATLO,320,160, WUPHI,WUPLO,160,(long)D_*160, D_,5, nullptr,nullptr,D_, QR,(long)NT_*D_, nullptr);
  k_ropesplit<<<(NT_*H_*32+255)/256,256,0,stream>>>(QR,KR,COS,SIN,QHI,QLO,KHI,KLO);
  k_vsplit<<<dim3(16,72),256,0,stream>>>(VR,VHI,VLO);
  k_attn_split<<<dim3(72,8),256,0,stream>>>(QHI,QLO,KHI,KLO,VHI,VLO,OHI,OLO);
  k_gemm2<2><<<dim3(64,5,1),256,0,stream>>>(OHI,OLO,D_,0, WOHI,WOLO,D_,0, D_,18, nullptr,nullptr,D_, X2,0, x);

  // MoE block
  hipMemsetAsync(CNT,0,64,stream);
  k_rms_router<<<NT_/4,256,0,stream>>>(X2, ln2, Wr, rb, H2B, IDX2, W2);
  k_count<<<NPAIR_/256,256,0,stream>>>(IDX2,CNT);
  k_offsets<<<1,1,0,stream>>>(CNT,OFS,FILL,TS);
  k_scatter2<<<NPAIR_/256,256,0,stream>>>(IDX2,W2,FILL,LTOK,LW,PPOS);
  k_moe_gu<<<dim3(12,MAXT_),256,0,stream>>>(H2B,GB,UB,CNT,OFS,TS,LTOK,ACT);
  k_moe_down<<<dim3(5,MAXT_),256,0,stream>>>(ACT,DB,CNT,OFS,TS,LW,PD);
  k_final<<<(NT_*(D_/4)+255)/256,256,0,stream>>>(X2,PD,PPOS,out);
}